// Round 2
// baseline (25477.007 us; speedup 1.0000x reference)
//
#include <hip/hip_runtime.h>
#include <math.h>

// Problem constants (fixed by the reference: H=1024, B=16, L=4, S=512)
#define Sv   512
#define Hv   1024
#define BSZ  16
#define NLB  4
#define NITEM 64          // BSZ*NLB
#define LOv  224          // >= max option len (512-300=212)
#define LDv  464          // >= max doc len (449)
#define NEGV (-1e30f)
#define VTHR (-1e20f)

enum { A_DIRECT = 0, A_OPT = 1, A_COMP = 2, A_GATE = 3, A_SELF = 4 };
enum { B_DIR_T = 0, B_DIR_N = 1, B_OPT_T = 2, B_OPT_N = 3, B_DOC_T = 4, B_DOC_N = 5 };
enum { E_STORE = 0, E_LOGIT = 1, E_ACC = 2, E_TANH = 3, E_GATE = 4, E_RELUMAX = 5 };

struct GP {
  const float* A; long long sA; int lda;
  const float* B; long long sB; int ldb;
  float* C; long long sC; int ldc;
  const float* ll;
  const int* fp;
  const unsigned char* qmask; int ldqm;
  const unsigned char* kmask; int ldkm;
  const unsigned char* docm;
  const float* w3;
  const float* qlogv; int ldql;
  const float* klogv; int ldkl;
  const float* bias;
  const float* X; long long sX;
  const float* Y; long long sY;
  float* outmax;
  int M, N, K;
  int qi, kj;
  int amode, bmode, epi, beta, cinst;
};

// opt_enc semantics of the reference: value = ll[item, fp+t, h] if fp+t < S else 0
// (note: NOT am-masked -- reference multiplies only by `valid`)
__device__ __forceinline__ float opt_view_f(const float* ll, const int* fp, int item, int t, int h) {
  int idx = fp[item] + t;
  return (idx < Sv) ? ll[((size_t)item * Sv + idx) * Hv + h] : 0.f;
}
// doc_enc semantics: ll * doc_mask (t < fp && am>0)
__device__ __forceinline__ float doc_view_f(const float* ll, const unsigned char* dm, int item, int t, int h) {
  return dm[item * LDv + t] ? ll[((size_t)item * Sv + t) * Hv + h] : 0.f;
}

__device__ __forceinline__ float fetchA(const GP& p, int inst, int itq, int m, int k) {
  switch (p.amode) {
    default:
    case A_DIRECT: return p.A[(size_t)inst * p.sA + (size_t)m * p.lda + k];
    case A_OPT:    return opt_view_f(p.ll, p.fp, itq, m, k);
    case A_COMP: { // concat([cur, cur*a0, cur-a0, cur*a1, cur-a1, cur*a2, cur-a2])
      int blk = k >> 10, kk = k & 1023;
      float x = opt_view_f(p.ll, p.fp, itq, m, kk);
      if (blk == 0) return x;
      int s = (blk - 1) >> 1;
      float a = p.X[(size_t)(s * BSZ + inst) * p.sX + (size_t)m * Hv + kk];
      return (blk & 1) ? x * a : x - a;
    }
    case A_GATE: { // concat([opt_enc, opt_corr])
      int blk = k >> 10, kk = k & 1023;
      if (blk == 0) return opt_view_f(p.ll, p.fp, itq, m, kk);
      return p.Y[(size_t)inst * p.sY + (size_t)m * Hv + kk];
    }
    case A_SELF: { // concat([f, a, f*a, f-a])
      int blk = k >> 10, kk = k & 1023;
      float f = p.X[(size_t)inst * p.sX + (size_t)m * Hv + kk];
      if (blk == 0) return f;
      float a = p.Y[(size_t)inst * p.sY + (size_t)m * Hv + kk];
      if (blk == 1) return a;
      return (blk == 2) ? f * a : f - a;
    }
  }
}

__device__ __forceinline__ float fetchB_T(const GP& p, int inst, int itk, int c, int k) {
  switch (p.bmode) {
    default:
    case B_DIR_T: return p.B[(size_t)inst * p.sB + (size_t)c * p.ldb + k];
    case B_OPT_T: return opt_view_f(p.ll, p.fp, itk, c, k);
    case B_DOC_T: return doc_view_f(p.ll, p.docm, itk, c, k);
  }
}
__device__ __forceinline__ float fetchB_N(const GP& p, int inst, int itk, int k, int c) {
  switch (p.bmode) {
    default:
    case B_DIR_N: return p.B[(size_t)inst * p.sB + (size_t)k * p.ldb + c];
    case B_OPT_N: return opt_view_f(p.ll, p.fp, itk, k, c);
    case B_DOC_N: return doc_view_f(p.ll, p.docm, itk, k, c);
  }
}

// Generic 64x64-tile f32 GEMM, 256 threads, 4x4 microtile, KT=16.
// C[inst_or_item, m, c] (+)= sum_k Aeff(m,k) * Beff(c_or_k, k_or_c)
__global__ __launch_bounds__(256) void gemm_k(GP p) {
  __shared__ float As[16][68];
  __shared__ float Bs[16][68];
  int inst = blockIdx.z;
  int itq = (p.qi >= 0) ? inst * NLB + p.qi : inst;
  int itk = (p.kj >= 0) ? inst * NLB + p.kj : inst;
  int tid = threadIdx.x;
  int m0 = blockIdx.y * 64, c0 = blockIdx.x * 64;
  float acc[4][4] = {};
  int tx = tid & 15, ty = tid >> 4;
  int lr = tid >> 2;
  int lk4 = (tid & 3) * 4;
  bool bT = (p.bmode == B_DIR_T || p.bmode == B_OPT_T || p.bmode == B_DOC_T);
  for (int k0 = 0; k0 < p.K; k0 += 16) {  // K is always a multiple of 16 here
    {
      int m = m0 + lr;
      #pragma unroll
      for (int j = 0; j < 4; j++) {
        int k = k0 + lk4 + j;
        float v = 0.f;
        if (m < p.M) {
          v = fetchA(p, inst, itq, m, k);
          if (p.epi == E_LOGIT) v *= p.w3[k];  // trilinear: dot uses w3-weighted q
        }
        As[lk4 + j][lr] = v;
      }
    }
    if (bT) {
      int c = c0 + lr;
      #pragma unroll
      for (int j = 0; j < 4; j++) {
        int k = k0 + lk4 + j;
        Bs[lk4 + j][lr] = (c < p.N) ? fetchB_T(p, inst, itk, c, k) : 0.f;
      }
    } else {
      int kr = tid >> 4;
      int n4 = (tid & 15) * 4;
      #pragma unroll
      for (int j = 0; j < 4; j++) {
        int c = c0 + n4 + j;
        Bs[kr][n4 + j] = (c < p.N) ? fetchB_N(p, inst, itk, k0 + kr, c) : 0.f;
      }
    }
    __syncthreads();
    #pragma unroll
    for (int k = 0; k < 16; k++) {
      float a[4], b[4];
      #pragma unroll
      for (int i = 0; i < 4; i++) a[i] = As[k][ty * 4 + i];
      #pragma unroll
      for (int j = 0; j < 4; j++) b[j] = Bs[k][tx * 4 + j];
      #pragma unroll
      for (int i = 0; i < 4; i++)
        #pragma unroll
        for (int j = 0; j < 4; j++) acc[i][j] += a[i] * b[j];
    }
    __syncthreads();
  }
  int cit = p.cinst ? inst : itq;
  #pragma unroll
  for (int i = 0; i < 4; i++) {
    int m = m0 + ty * 4 + i;
    if (m >= p.M) continue;
    #pragma unroll
    for (int j = 0; j < 4; j++) {
      int c = c0 + tx * 4 + j;
      if (c >= p.N) continue;
      float v = acc[i][j];
      float* cp = p.C ? (p.C + (size_t)cit * p.sC + (size_t)m * p.ldc + c) : nullptr;
      switch (p.epi) {
        case E_STORE: *cp = v; break;
        case E_LOGIT: {
          bool qm = p.qmask[itq * p.ldqm + m] != 0;
          bool km = p.kmask[itk * p.ldkm + c] != 0;
          *cp = (qm && km) ? (v + p.qlogv[(size_t)itq * p.ldql + m] + p.klogv[(size_t)itk * p.ldkl + c]) : NEGV;
          break;
        }
        case E_ACC: {
          *cp = v + (p.bias ? p.bias[c] : 0.f) + (p.beta ? *cp : 0.f);
          break;
        }
        case E_TANH: {
          *cp = tanhf(v + (p.bias ? p.bias[c] : 0.f) + (p.beta ? *cp : 0.f));
          break;
        }
        case E_GATE: {
          float g = 1.f / (1.f + __expf(-(v + p.bias[c])));
          float xv = opt_view_f(p.ll, p.fp, cit, m, c);
          float yv = p.Y[(size_t)cit * p.sY + (size_t)m * Hv + c];
          *cp = xv * g + yv * (1.f - g);
          break;
        }
        case E_RELUMAX: {
          float r = fmaxf(v + p.bias[c], 0.f);
          if (p.qmask[cit * p.ldqm + m])
            atomicMax((unsigned int*)(p.outmax + (size_t)cit * Hv + c), __float_as_uint(r));
          break;
        }
      }
    }
  }
}

// NOTE: the harness delivers ALL integer inputs as int32 ("integer -> const int*"),
// including the reference's int64 all_doc_final_pos. Cast as const int*.
__global__ __launch_bounds__(256) void init_masks(const int* fp_in, const int* am, int* fp,
                                                  unsigned char* optm, unsigned char* docm) {
  int item = blockIdx.x;
  int f = fp_in[item];
  if (threadIdx.x == 0) fp[item] = f;
  for (int t = threadIdx.x; t < LDv; t += blockDim.x) {
    docm[item * LDv + t] = (t < f && am[item * Sv + t] > 0) ? 1 : 0;
    if (t < LOv) {
      int idx = f + t;
      optm[item * LOv + t] = (idx < Sv && am[item * Sv + idx] > 0) ? 1 : 0;
    }
  }
}

// out[item, t] = dot(row, w); mode 0: direct buffer, 1: opt view, 2: doc view
__global__ __launch_bounds__(256) void dot_rows(const float* src, long long sS,
                                                const float* ll, const int* fp, const unsigned char* docm,
                                                const float* w, float* outv, int ldo, int mode) {
  int t = blockIdx.x, item = blockIdx.y;
  int tid = threadIdx.x;
  float s = 0.f;
  for (int h = tid; h < Hv; h += 256) {
    float v;
    if (mode == 0)      v = src[(size_t)item * sS + (size_t)t * Hv + h];
    else if (mode == 1) v = opt_view_f(ll, fp, item, t, h);
    else                v = doc_view_f(ll, docm, item, t, h);
    s += v * w[h];
  }
  __shared__ float red[4];
  for (int o = 32; o > 0; o >>= 1) s += __shfl_down(s, o, 64);
  int lane = tid & 63, wv = tid >> 6;
  if (lane == 0) red[wv] = s;
  __syncthreads();
  if (tid == 0) outv[(size_t)item * ldo + t] = red[0] + red[1] + red[2] + red[3];
}

// softmax over the last axis; masked entries (logit<VTHR) -> 0. dst may equal src.
__global__ __launch_bounds__(256) void row_softmax(const float* src, float* dst, int Lk, int ldl, long long sL) {
  int m = blockIdx.x, inst = blockIdx.y;
  const float* row = src + (size_t)inst * sL + (size_t)m * ldl;
  float* orow = dst + (size_t)inst * sL + (size_t)m * ldl;
  int tid = threadIdx.x;
  float mx = -INFINITY;
  for (int t = tid; t < Lk; t += 256) mx = fmaxf(mx, row[t]);
  __shared__ float sm[4]; __shared__ float ss[4];
  for (int o = 32; o > 0; o >>= 1) mx = fmaxf(mx, __shfl_down(mx, o, 64));
  int lane = tid & 63, wv = tid >> 6;
  if (lane == 0) sm[wv] = mx;
  __syncthreads();
  mx = fmaxf(fmaxf(sm[0], sm[1]), fmaxf(sm[2], sm[3]));
  float sum = 0.f;
  for (int t = tid; t < Lk; t += 256) sum += __expf(row[t] - mx);
  for (int o = 32; o > 0; o >>= 1) sum += __shfl_down(sum, o, 64);
  if (lane == 0) ss[wv] = sum;
  __syncthreads();
  sum = ss[0] + ss[1] + ss[2] + ss[3];
  float inv = 1.f / sum;
  for (int t = tid; t < Lk; t += 256) {
    float x = row[t];
    orow[t] = (x < VTHR) ? 0.f : __expf(x - mx) * inv;
  }
}

// softmax over rows (axis=1 of [M, ld]); in place.
__global__ __launch_bounds__(256) void col_softmax(float* buf, int Mr, int ldl, long long sL) {
  int c = blockIdx.x, inst = blockIdx.y;
  float* base = buf + (size_t)inst * sL + c;
  int tid = threadIdx.x;
  float mx = -INFINITY;
  for (int t = tid; t < Mr; t += 256) mx = fmaxf(mx, base[(size_t)t * ldl]);
  __shared__ float sm[4]; __shared__ float ss[4];
  for (int o = 32; o > 0; o >>= 1) mx = fmaxf(mx, __shfl_down(mx, o, 64));
  int lane = tid & 63, wv = tid >> 6;
  if (lane == 0) sm[wv] = mx;
  __syncthreads();
  mx = fmaxf(fmaxf(sm[0], sm[1]), fmaxf(sm[2], sm[3]));
  float sum = 0.f;
  for (int t = tid; t < Mr; t += 256) sum += __expf(base[(size_t)t * ldl] - mx);
  for (int o = 32; o > 0; o >>= 1) sum += __shfl_down(sum, o, 64);
  if (lane == 0) ss[wv] = sum;
  __syncthreads();
  sum = ss[0] + ss[1] + ss[2] + ss[3];
  float inv = 1.f / sum;
  for (int t = tid; t < Mr; t += 256) {
    float x = base[(size_t)t * ldl];
    base[(size_t)t * ldl] = (x < VTHR) ? 0.f : __expf(x - mx) * inv;
  }
}

extern "C" void kernel_launch(void* const* d_in, const int* in_sizes, int n_in,
                              void* d_out, int out_size, void* d_ws, size_t ws_size,
                              hipStream_t stream) {
  const float* ll        = (const float*)d_in[0];
  const int* am          = (const int*)d_in[1];
  const int* fp_in       = (const int*)d_in[2];   // int64 in reference, delivered as int32
  // d_in[3] = num_label (ignored, ==4)
  const float* attn_w1   = (const float*)d_in[4];
  const float* attn_w2   = (const float*)d_in[5];
  const float* attn_w3   = (const float*)d_in[6];
  const float* opt_w1    = (const float*)d_in[7];
  const float* opt_w2    = (const float*)d_in[8];
  const float* opt_w3    = (const float*)d_in[9];
  const float* self_w1   = (const float*)d_in[10];
  const float* self_w2   = (const float*)d_in[11];
  const float* self_w3   = (const float*)d_in[12];
  const float* attn_fc_w = (const float*)d_in[13];
  const float* attn_fc_b = (const float*)d_in[14];
  const float* comp_fc_w = (const float*)d_in[15];
  const float* comp_fc_b = (const float*)d_in[16];
  const float* gate_fc_w = (const float*)d_in[17];
  const float* gate_fc_b = (const float*)d_in[18];
  const float* self_fc_w = (const float*)d_in[19];
  const float* self_fc_b = (const float*)d_in[20];
  float* out = (float*)d_out;

  // ---- workspace arena (floats), ~243 MB total ----
  float* wsf = (float*)d_ws;
  const size_t BIG = (size_t)NITEM * LOv * Hv;     // 14,680,064 floats
  const size_t LGT = (size_t)NITEM * LOv * LDv;    // 6,651,904
  const size_t COW = (size_t)NITEM * LOv * LOv;    // 3,211,264
  float* optcorr = wsf;               // phase1 out; later re-used as facc/fusion
  float* option  = wsf + BIG;
  float* tmp     = wsf + 2 * BIG;     // attn / coattn / attn2 / phase-1 slices
  float* logit   = wsf + 3 * BIG;
  float* awb     = logit + LGT;
  float* cow     = awb + LGT;
  float* qlog    = cow + COW;
  float* klog    = qlog + (size_t)NITEM * LOv;
  float* optq    = klog + (size_t)NITEM * LDv;
  float* optk    = optq + (size_t)NITEM * LOv;
  unsigned char* optm = (unsigned char*)(optk + (size_t)NITEM * LOv);
  unsigned char* docm = optm + (size_t)NITEM * LOv;
  int* fp = (int*)(docm + (size_t)NITEM * LDv);
  const long long sBIGi = (long long)LOv * Hv;

  (void)hipMemsetAsync(d_out, 0, (size_t)NITEM * Hv * sizeof(float), stream);
  init_masks<<<NITEM, 256, 0, stream>>>(fp_in, am, fp, optm, docm);
  // option-token q/k logits for phase 1 (opt_w1/opt_w2)
  dot_rows<<<dim3(LOv, NITEM), 256, 0, stream>>>(nullptr, 0, ll, fp, docm, opt_w1, optq, LOv, 1);
  dot_rows<<<dim3(LOv, NITEM), 256, 0, stream>>>(nullptr, 0, ll, fp, docm, opt_w2, optk, LOv, 1);

  // ================= Phase 1: pairwise option attention + comp FC =================
  for (int i = 0; i < NLB; i++) {
    int s = 0;
    for (int j = 0; j < NLB; j++) {
      if (j == i) continue;
      {
        GP p = {};
        p.ll = ll; p.fp = fp; p.docm = docm;
        p.amode = A_OPT; p.bmode = B_OPT_T; p.epi = E_LOGIT;
        p.qi = i; p.kj = j; p.w3 = opt_w3;
        p.qmask = optm; p.ldqm = LOv; p.kmask = optm; p.ldkm = LOv;
        p.qlogv = optq; p.ldql = LOv; p.klogv = optk; p.ldkl = LOv;
        p.C = logit; p.sC = (long long)LOv * LOv; p.ldc = LOv; p.cinst = 1;
        p.M = LOv; p.N = LOv; p.K = Hv;
        gemm_k<<<dim3(4, 4, BSZ), 256, 0, stream>>>(p);
      }
      row_softmax<<<dim3(LOv, BSZ), 256, 0, stream>>>(logit, logit, LOv, LOv, (long long)LOv * LOv);
      {
        GP p = {};
        p.ll = ll; p.fp = fp; p.docm = docm;
        p.amode = A_DIRECT; p.A = logit; p.sA = (long long)LOv * LOv; p.lda = LOv;
        p.bmode = B_OPT_N; p.qi = i; p.kj = j; p.epi = E_STORE;
        p.C = tmp + (size_t)s * BSZ * LOv * Hv; p.sC = sBIGi; p.ldc = Hv; p.cinst = 1;
        p.M = LOv; p.N = Hv; p.K = LOv;
        gemm_k<<<dim3(16, 4, BSZ), 256, 0, stream>>>(p);
      }
      s++;
    }
    { // comp FC: K=7168 over virtual concat, epilogue tanh, write opt_corr[:, i]
      GP p = {};
      p.ll = ll; p.fp = fp; p.docm = docm;
      p.amode = A_COMP; p.qi = i; p.kj = -1;
      p.X = tmp; p.sX = sBIGi;
      p.bmode = B_DIR_T; p.B = comp_fc_w; p.sB = 0; p.ldb = 7 * Hv;
      p.epi = E_TANH; p.bias = comp_fc_b; p.beta = 0;
      p.C = optcorr; p.sC = sBIGi; p.ldc = Hv; p.cinst = 0;
      p.M = LOv; p.N = Hv; p.K = 7 * Hv;
      gemm_k<<<dim3(16, 4, BSZ), 256, 0, stream>>>(p);
    }
  }

  // ================= Phase 2: gate FC + blend -> option =================
  {
    GP p = {};
    p.ll = ll; p.fp = fp; p.docm = docm;
    p.amode = A_GATE; p.qi = -1; p.kj = -1;
    p.Y = optcorr; p.sY = sBIGi;
    p.bmode = B_DIR_T; p.B = gate_fc_w; p.sB = 0; p.ldb = 2 * Hv;
    p.epi = E_GATE; p.bias = gate_fc_b;
    p.C = option; p.sC = sBIGi; p.ldc = Hv; p.cinst = 1;
    p.M = LOv; p.N = Hv; p.K = 2 * Hv;
    gemm_k<<<dim3(16, 4, NITEM), 256, 0, stream>>>(p);
  }

  // ================= Phase 3: doc attention + co-attention + attn FC =================
  float* facc = optcorr;  // opt_corr is dead now; reuse as fusion accumulator
  dot_rows<<<dim3(LOv, NITEM), 256, 0, stream>>>(option, sBIGi, ll, fp, docm, attn_w1, qlog, LOv, 0);
  dot_rows<<<dim3(LDv, NITEM), 256, 0, stream>>>(nullptr, 0, ll, fp, docm, attn_w2, klog, LDv, 2);
  {
    GP p = {};
    p.ll = ll; p.fp = fp; p.docm = docm;
    p.amode = A_DIRECT; p.A = option; p.sA = sBIGi; p.lda = Hv;
    p.bmode = B_DOC_T; p.qi = -1; p.kj = -1; p.epi = E_LOGIT; p.w3 = attn_w3;
    p.qmask = optm; p.ldqm = LOv; p.kmask = docm; p.ldkm = LDv;
    p.qlogv = qlog; p.ldql = LOv; p.klogv = klog; p.ldkl = LDv;
    p.C = logit; p.sC = (long long)LOv * LDv; p.ldc = LDv; p.cinst = 1;
    p.M = LOv; p.N = LDv; p.K = Hv;
    gemm_k<<<dim3(8, 4, NITEM), 256, 0, stream>>>(p);
  }
  row_softmax<<<dim3(LOv, NITEM), 256, 0, stream>>>(logit, awb, LDv, LDv, (long long)LOv * LDv);
  col_softmax<<<dim3(LDv, NITEM), 256, 0, stream>>>(logit, LOv, LDv, (long long)LOv * LDv);  // kq in place
  {  // attn = aw @ doc_enc -> tmp
    GP p = {};
    p.ll = ll; p.fp = fp; p.docm = docm;
    p.amode = A_DIRECT; p.A = awb; p.sA = (long long)LOv * LDv; p.lda = LDv;
    p.bmode = B_DOC_N; p.qi = -1; p.kj = -1; p.epi = E_STORE;
    p.C = tmp; p.sC = sBIGi; p.ldc = Hv; p.cinst = 1;
    p.M = LOv; p.N = Hv; p.K = LDv;
    gemm_k<<<dim3(16, 4, NITEM), 256, 0, stream>>>(p);
  }
  {  // facc = attn @ Wa[:,H:2H] + bias
    GP p = {};
    p.amode = A_DIRECT; p.A = tmp; p.sA = sBIGi; p.lda = Hv; p.qi = -1; p.kj = -1;
    p.bmode = B_DIR_T; p.B = attn_fc_w + Hv; p.sB = 0; p.ldb = 3 * Hv;
    p.epi = E_ACC; p.bias = attn_fc_b; p.beta = 0;
    p.C = facc; p.sC = sBIGi; p.ldc = Hv; p.cinst = 1;
    p.M = LOv; p.N = Hv; p.K = Hv;
    gemm_k<<<dim3(16, 4, NITEM), 256, 0, stream>>>(p);
  }
  {  // co_w = aw @ kq^T -> cow
    GP p = {};
    p.amode = A_DIRECT; p.A = awb; p.sA = (long long)LOv * LDv; p.lda = LDv; p.qi = -1; p.kj = -1;
    p.bmode = B_DIR_T; p.B = logit; p.sB = (long long)LOv * LDv; p.ldb = LDv;
    p.epi = E_STORE;
    p.C = cow; p.sC = (long long)LOv * LOv; p.ldc = LOv; p.cinst = 1;
    p.M = LOv; p.N = LOv; p.K = LDv;
    gemm_k<<<dim3(4, 4, NITEM), 256, 0, stream>>>(p);
  }
  {  // coattn = co_w @ option -> tmp
    GP p = {};
    p.amode = A_DIRECT; p.A = cow; p.sA = (long long)LOv * LOv; p.lda = LOv; p.qi = -1; p.kj = -1;
    p.bmode = B_DIR_N; p.B = option; p.sB = sBIGi; p.ldb = Hv;
    p.epi = E_STORE;
    p.C = tmp; p.sC = sBIGi; p.ldc = Hv; p.cinst = 1;
    p.M = LOv; p.N = Hv; p.K = LOv;
    gemm_k<<<dim3(16, 4, NITEM), 256, 0, stream>>>(p);
  }
  {  // facc += coattn @ Wa[:,2H:3H]
    GP p = {};
    p.amode = A_DIRECT; p.A = tmp; p.sA = sBIGi; p.lda = Hv; p.qi = -1; p.kj = -1;
    p.bmode = B_DIR_T; p.B = attn_fc_w + 2 * Hv; p.sB = 0; p.ldb = 3 * Hv;
    p.epi = E_ACC; p.beta = 1;
    p.C = facc; p.sC = sBIGi; p.ldc = Hv; p.cinst = 1;
    p.M = LOv; p.N = Hv; p.K = Hv;
    gemm_k<<<dim3(16, 4, NITEM), 256, 0, stream>>>(p);
  }
  {  // fusion = tanh(facc + option @ Wa[:,0:H])  (in place in facc)
    GP p = {};
    p.amode = A_DIRECT; p.A = option; p.sA = sBIGi; p.lda = Hv; p.qi = -1; p.kj = -1;
    p.bmode = B_DIR_T; p.B = attn_fc_w; p.sB = 0; p.ldb = 3 * Hv;
    p.epi = E_TANH; p.beta = 1;
    p.C = facc; p.sC = sBIGi; p.ldc = Hv; p.cinst = 1;
    p.M = LOv; p.N = Hv; p.K = Hv;
    gemm_k<<<dim3(16, 4, NITEM), 256, 0, stream>>>(p);
  }

  // ================= Phase 4: self attention + self FC + masked max =================
  float* fusion = facc;
  dot_rows<<<dim3(LOv, NITEM), 256, 0, stream>>>(fusion, sBIGi, ll, fp, docm, self_w1, qlog, LOv, 0);
  dot_rows<<<dim3(LOv, NITEM), 256, 0, stream>>>(fusion, sBIGi, ll, fp, docm, self_w2, klog, LOv, 0);
  {
    GP p = {};
    p.ll = ll; p.fp = fp; p.docm = docm;
    p.amode = A_DIRECT; p.A = fusion; p.sA = sBIGi; p.lda = Hv;
    p.bmode = B_DIR_T; p.B = fusion; p.sB = sBIGi; p.ldb = Hv;
    p.qi = -1; p.kj = -1; p.epi = E_LOGIT; p.w3 = self_w3;
    p.qmask = optm; p.ldqm = LOv; p.kmask = optm; p.ldkm = LOv;
    p.qlogv = qlog; p.ldql = LOv; p.klogv = klog; p.ldkl = LOv;
    p.C = logit; p.sC = (long long)LOv * LOv; p.ldc = LOv; p.cinst = 1;
    p.M = LOv; p.N = LOv; p.K = Hv;
    gemm_k<<<dim3(4, 4, NITEM), 256, 0, stream>>>(p);
  }
  row_softmax<<<dim3(LOv, NITEM), 256, 0, stream>>>(logit, awb, LOv, LOv, (long long)LOv * LOv);
  {  // attn2 = aw @ fusion -> tmp
    GP p = {};
    p.amode = A_DIRECT; p.A = awb; p.sA = (long long)LOv * LOv; p.lda = LOv; p.qi = -1; p.kj = -1;
    p.bmode = B_DIR_N; p.B = fusion; p.sB = sBIGi; p.ldb = Hv;
    p.epi = E_STORE;
    p.C = tmp; p.sC = sBIGi; p.ldc = Hv; p.cinst = 1;
    p.M = LOv; p.N = Hv; p.K = LOv;
    gemm_k<<<dim3(16, 4, NITEM), 256, 0, stream>>>(p);
  }
  {  // self FC (K=4096 virtual concat) + relu + masked atomic max -> d_out
    GP p = {};
    p.amode = A_SELF; p.X = fusion; p.sX = sBIGi; p.Y = tmp; p.sY = sBIGi;
    p.qi = -1; p.kj = -1;
    p.bmode = B_DIR_T; p.B = self_fc_w; p.sB = 0; p.ldb = 4 * Hv;
    p.epi = E_RELUMAX; p.bias = self_fc_b;
    p.qmask = optm; p.ldqm = LOv;
    p.outmax = out; p.C = nullptr; p.sC = 0; p.ldc = 0; p.cinst = 1;
    p.M = LOv; p.N = Hv; p.K = 4 * Hv;
    gemm_k<<<dim3(16, 4, NITEM), 256, 0, stream>>>(p);
  }
}

// Round 3
// 3907.037 us; speedup vs baseline: 6.5208x; 6.5208x over previous
//
#include <hip/hip_runtime.h>
#include <math.h>

// Problem constants (fixed by the reference: H=1024, B=16, L=4, S=512)
#define Sv   512
#define Hv   1024
#define BSZ  16
#define NLB  4
#define NITEM 64          // BSZ*NLB
#define LOv  224          // >= max option len (512-300=212), multiple of 32
#define LDv  480          // >= max doc len (449), multiple of 32
#define NEGV (-1e30f)
#define VTHR (-1e20f)

typedef unsigned short u16;
typedef __attribute__((ext_vector_type(8))) short short8;   // 8 bf16 = 4 VGPRs (MFMA A/B frag)

__device__ __forceinline__ u16 f2b(float x) {  // f32 -> bf16 RNE
  unsigned u = __float_as_uint(x);
  return (u16)((u + 0x7FFFu + ((u >> 16) & 1u)) >> 16);
}
__device__ __forceinline__ float b2f(u16 b) { return __uint_as_float(((unsigned)b) << 16); }

__device__ __forceinline__ float opt_view_f(const float* ll, const int* fp, int item, int t, int h) {
  int idx = fp[item] + t;
  return (idx < Sv) ? ll[((size_t)item * Sv + idx) * Hv + h] : 0.f;
}

// ======================= bf16 MFMA GEMM =======================
// C[ci][m][n] = sum_k A[ai][m][k] * B[bi][n][k]   (both operands bf16 row-major, B is "B^T" layout)
// 128x128 tile, BK=32, 256 threads = 4 waves in 2x2 grid, each wave 64x64 via 4x4 MFMA 16x16x32.
enum { EP_BF16 = 0, EP_LOGIT = 1, EP_TANH = 2, EP_GATE = 3, EP_RELUMAX = 4, EP_F32 = 5 };
enum { IX_INST = 0, IX_ITQ = 1, IX_ITK = 2 };

struct MG {
  const u16* A; long long sA; int lda; int aidx;
  const u16* B; long long sB; int ldb; int bidx;
  float* C; long long sC; int ldc; int cidx;
  u16* Cb;                      // bf16 output base (EP_BF16)
  const float* bias;
  const unsigned char* qmask; int ldqm;
  const unsigned char* kmask; int ldkm;
  const float* qlogv; int ldql;
  const float* klogv; int ldkl;
  const float* ll; const int* fp;           // EP_GATE xv source
  const float* Yv; long long sY;            // EP_GATE yv source (f32)
  float* outmax;
  int M, N, K, qi, kj, epi;
};

__global__ __launch_bounds__(256) void mgemm(MG p) {
  __shared__ u16 As[128][40];   // row stride 40 elems (80B) breaks power-of-2 bank stride
  __shared__ u16 Bs[128][40];
  int inst = blockIdx.z;
  int itq = (p.qi >= 0) ? inst * NLB + p.qi : inst;
  int itk = (p.kj >= 0) ? inst * NLB + p.kj : inst;
  int ai = (p.aidx == IX_ITQ) ? itq : (p.aidx == IX_ITK ? itk : inst);
  int bi = (p.bidx == IX_ITQ) ? itq : (p.bidx == IX_ITK ? itk : inst);
  int ci = (p.cidx == IX_ITQ) ? itq : (p.cidx == IX_ITK ? itk : inst);
  const u16* Ab = p.A + (size_t)ai * p.sA;
  const u16* Bb = p.B + (size_t)bi * p.sB;
  int tid = threadIdx.x;
  int m0 = blockIdx.y * 128, n0 = blockIdx.x * 128;
  int sr = tid >> 1, sk = (tid & 1) * 16;   // staging: row, k-offset (each thread 32B)
  int wave = tid >> 6, lane = tid & 63;
  int wm = (wave >> 1) * 64, wn = (wave & 1) * 64;
  int col = lane & 15, quad = lane >> 4;
  using floatx4 = __attribute__((ext_vector_type(4))) float;
  floatx4 acc[4][4] = {};

  for (int k0 = 0; k0 < p.K; k0 += 32) {
    {
      int m = m0 + sr;
      if (m < p.M) {
        const u16* src = Ab + (size_t)m * p.lda + k0 + sk;
        *(uint4*)&As[sr][sk]     = *(const uint4*)src;
        *(uint4*)&As[sr][sk + 8] = *(const uint4*)(src + 8);
      } else {
        uint4 z = {0, 0, 0, 0};
        *(uint4*)&As[sr][sk] = z; *(uint4*)&As[sr][sk + 8] = z;
      }
      int n = n0 + sr;
      if (n < p.N) {
        const u16* src = Bb + (size_t)n * p.ldb + k0 + sk;
        *(uint4*)&Bs[sr][sk]     = *(const uint4*)src;
        *(uint4*)&Bs[sr][sk + 8] = *(const uint4*)(src + 8);
      } else {
        uint4 z = {0, 0, 0, 0};
        *(uint4*)&Bs[sr][sk] = z; *(uint4*)&Bs[sr][sk + 8] = z;
      }
    }
    __syncthreads();
    short8 a[4], b[4];
    #pragma unroll
    for (int mi = 0; mi < 4; mi++) a[mi] = *(const short8*)&As[wm + mi * 16 + col][quad * 8];
    #pragma unroll
    for (int ni = 0; ni < 4; ni++) b[ni] = *(const short8*)&Bs[wn + ni * 16 + col][quad * 8];
    #pragma unroll
    for (int mi = 0; mi < 4; mi++)
      #pragma unroll
      for (int ni = 0; ni < 4; ni++)
        acc[mi][ni] = __builtin_amdgcn_mfma_f32_16x16x32_bf16(a[mi], b[ni], acc[mi][ni], 0, 0, 0);
    __syncthreads();
  }

  // epilogue: C/D layout col=lane&15, row=quad*4+reg  [verified m89/m91]
  #pragma unroll
  for (int mi = 0; mi < 4; mi++) {
    #pragma unroll
    for (int ni = 0; ni < 4; ni++) {
      int n = n0 + wn + ni * 16 + col;
      if (n >= p.N) continue;
      #pragma unroll
      for (int r = 0; r < 4; r++) {
        int m = m0 + wm + mi * 16 + quad * 4 + r;
        if (m >= p.M) continue;
        float v = acc[mi][ni][r];
        switch (p.epi) {
          case EP_BF16:
            p.Cb[(size_t)ci * p.sC + (size_t)m * p.ldc + n] = f2b(v);
            break;
          case EP_F32:
            p.C[(size_t)ci * p.sC + (size_t)m * p.ldc + n] = v;
            break;
          case EP_LOGIT: {
            bool qm = p.qmask[itq * p.ldqm + m] != 0;
            bool km = p.kmask[itk * p.ldkm + n] != 0;
            p.C[(size_t)ci * p.sC + (size_t)m * p.ldc + n] =
              (qm && km) ? (v + p.qlogv[(size_t)itq * p.ldql + m] + p.klogv[(size_t)itk * p.ldkl + n]) : NEGV;
            break;
          }
          case EP_TANH:
            p.C[(size_t)ci * p.sC + (size_t)m * p.ldc + n] = tanhf(v + p.bias[n]);
            break;
          case EP_GATE: {
            float g = 1.f / (1.f + __expf(-(v + p.bias[n])));
            float xv = opt_view_f(p.ll, p.fp, ci, m, n);
            float yv = p.Yv[(size_t)ci * p.sY + (size_t)m * Hv + n];
            p.C[(size_t)ci * p.sC + (size_t)m * p.ldc + n] = xv * g + yv * (1.f - g);
            break;
          }
          case EP_RELUMAX: {
            float rr = fmaxf(v + p.bias[n], 0.f);
            if (p.qmask[ci * p.ldqm + m])
              atomicMax((unsigned int*)(p.outmax + (size_t)ci * Hv + n), __float_as_uint(rr));
            break;
          }
        }
      }
    }
  }
}

// ======================= helpers =======================
__global__ __launch_bounds__(256) void init_masks(const int* fp_in, const int* am, int* fp,
                                                  unsigned char* optm, unsigned char* docm) {
  int item = blockIdx.x;
  int f = fp_in[item];
  if (threadIdx.x == 0) fp[item] = f;
  for (int t = threadIdx.x; t < LDv; t += blockDim.x) {
    docm[item * LDv + t] = (t < f && t < Sv && am[item * Sv + t] > 0) ? 1 : 0;
    if (t < LOv) {
      int idx = f + t;
      optm[item * LOv + t] = (idx < Sv && am[item * Sv + idx] > 0) ? 1 : 0;
    }
  }
}

__global__ __launch_bounds__(256) void convf2b(const float* src, u16* dst, int n) {
  int i = blockIdx.x * 256 + threadIdx.x;
  int stride = gridDim.x * 256;
  for (; i < n; i += stride) dst[i] = f2b(src[i]);
}

// opt view -> opt_bf + (opt*w3)_bf
__global__ __launch_bounds__(256) void build_opt(const float* ll, const int* fp, const float* w3,
                                                 u16* optB, u16* optw3B) {
  int t = blockIdx.x, item = blockIdx.y;
  int idx = fp[item] + t;
  bool v = idx < Sv;
  const float* src = ll + ((size_t)item * Sv + (v ? idx : 0)) * Hv;
  size_t o = ((size_t)item * LOv + t) * Hv;
  for (int h = threadIdx.x; h < Hv; h += 256) {
    float x = v ? src[h] : 0.f;
    optB[o + h] = f2b(x);
    optw3B[o + h] = f2b(x * w3[h]);
  }
}

// doc view -> doc_bf [64,480,1024]
__global__ __launch_bounds__(256) void build_doc(const float* ll, const unsigned char* docm, u16* docB) {
  int t = blockIdx.x, item = blockIdx.y;
  bool v = docm[item * LDv + t] != 0;
  const float* src = ll + ((size_t)item * Sv + (t < Sv ? t : 0)) * Hv;
  size_t o = ((size_t)item * LDv + t) * Hv;
  for (int h = threadIdx.x; h < Hv; h += 256) docB[o + h] = v ? f2b(src[h]) : (u16)0;
}

// transpose token-major [Lt,H] (f32 source or view) -> bf16 [H,Lt]
__global__ __launch_bounds__(256) void transpose_b(const float* src, long long sS,
                                                   const float* ll, const int* fp, const unsigned char* docm,
                                                   int mode, int Lt, u16* out) {
  __shared__ float tile[32][33];
  int t0 = blockIdx.x * 32, h0 = blockIdx.y * 32, item = blockIdx.z;
  int tx = threadIdx.x & 31, ty0 = threadIdx.x >> 5;  // 32x8
  for (int yy = ty0; yy < 32; yy += 8) {
    int t = t0 + yy, h = h0 + tx;
    float v = 0.f;
    if (t < Lt) {
      if (mode == 0)      v = src[(size_t)item * sS + (size_t)t * Hv + h];
      else if (mode == 1) { int idx = fp[item] + t; if (idx < Sv) v = ll[((size_t)item * Sv + idx) * Hv + h]; }
      else                { if (docm[item * LDv + t]) v = ll[((size_t)item * Sv + t) * Hv + h]; }
    }
    tile[yy][tx] = v;
  }
  __syncthreads();
  for (int yy = ty0; yy < 32; yy += 8) {
    int h = h0 + yy, t = t0 + tx;
    if (t < Lt) out[((size_t)item * Hv + h) * (size_t)Lt + t] = f2b(tile[tx][yy]);
  }
}

// compA[b] = concat7([cur, cur*a0, cur-a0, cur*a1, cur-a1, cur*a2, cur-a2]) bf16
__global__ __launch_bounds__(256) void build_compA(const u16* optB, const u16* asbuf, u16* compA, int i) {
  int t = blockIdx.x, b = blockIdx.y;
  int item = b * NLB + i;
  const u16* cur = optB + ((size_t)item * LOv + t) * Hv;
  u16* dst = compA + ((size_t)b * LOv + t) * (7 * Hv);
  for (int h = threadIdx.x; h < Hv; h += 256) {
    u16 cu = cur[h]; float c = b2f(cu);
    dst[h] = cu;
    #pragma unroll
    for (int s = 0; s < 3; s++) {
      float a = b2f(asbuf[(((size_t)s * BSZ + b) * LOv + t) * Hv + h]);
      dst[(size_t)(1 + 2 * s) * Hv + h] = f2b(c * a);
      dst[(size_t)(2 + 2 * s) * Hv + h] = f2b(c - a);
    }
  }
}

// gateA = concat2([opt_enc, opt_corr]) bf16
__global__ __launch_bounds__(256) void build_gateA(const float* ll, const int* fp, const float* corr, u16* gateA) {
  int t = blockIdx.x, item = blockIdx.y;
  int idx = fp[item] + t;
  bool v = idx < Sv;
  const float* src = ll + ((size_t)item * Sv + (v ? idx : 0)) * Hv;
  u16* dst = gateA + ((size_t)item * LOv + t) * (2 * Hv);
  const float* cr = corr + ((size_t)item * LOv + t) * Hv;
  for (int h = threadIdx.x; h < Hv; h += 256) {
    dst[h] = f2b(v ? src[h] : 0.f);
    dst[Hv + h] = f2b(cr[h]);
  }
}

// act f32 -> bf16 copy (strided dst1) + bf16(act*w3)
__global__ __launch_bounds__(256) void conv_act(const float* src, const float* w3,
                                                u16* dst1, int ld1, u16* dstw3) {
  int t = blockIdx.x, item = blockIdx.y;
  const float* s = src + ((size_t)item * LOv + t) * Hv;
  u16* d1 = dst1 + ((size_t)item * LOv + t) * ld1;
  u16* d2 = dstw3 + ((size_t)item * LOv + t) * Hv;
  for (int h = threadIdx.x; h < Hv; h += 256) {
    float x = s[h];
    d1[h] = f2b(x);
    d2[h] = f2b(x * w3[h]);
  }
}

// selfA blocks 2,3 = f*a, f-a from blocks 0,1
__global__ __launch_bounds__(256) void build_selfA23(u16* selfA) {
  int t = blockIdx.x, item = blockIdx.y;
  u16* row = selfA + ((size_t)item * LOv + t) * (4 * Hv);
  for (int h = threadIdx.x; h < Hv; h += 256) {
    float f = b2f(row[h]), a = b2f(row[Hv + h]);
    row[2 * Hv + h] = f2b(f * a);
    row[3 * Hv + h] = f2b(f - a);
  }
}

// out[item, t] = dot(row, w); mode 0: direct buffer, 1: opt view, 2: doc view  (f32)
__global__ __launch_bounds__(256) void dot_rows(const float* src, long long sS,
                                                const float* ll, const int* fp, const unsigned char* docm,
                                                const float* w, float* outv, int ldo, int mode) {
  int t = blockIdx.x, item = blockIdx.y;
  int tid = threadIdx.x;
  float s = 0.f;
  for (int h = tid; h < Hv; h += 256) {
    float v;
    if (mode == 0)      v = src[(size_t)item * sS + (size_t)t * Hv + h];
    else if (mode == 1) v = opt_view_f(ll, fp, item, t, h);
    else                v = docm[item * LDv + t] ? ll[((size_t)item * Sv + t) * Hv + h] : 0.f;
    s += v * w[h];
  }
  __shared__ float red[4];
  for (int o = 32; o > 0; o >>= 1) s += __shfl_down(s, o, 64);
  int lane = tid & 63, wv = tid >> 6;
  if (lane == 0) red[wv] = s;
  __syncthreads();
  if (tid == 0) outv[(size_t)item * ldo + t] = red[0] + red[1] + red[2] + red[3];
}

// softmax over last axis, f32 in -> bf16 out; masked (<VTHR) -> 0
__global__ __launch_bounds__(256) void row_softmax(const float* src, u16* dst, int Lk, int ldl, long long sL) {
  int m = blockIdx.x, inst = blockIdx.y;
  const float* row = src + (size_t)inst * sL + (size_t)m * ldl;
  u16* orow = dst + (size_t)inst * sL + (size_t)m * ldl;
  int tid = threadIdx.x;
  float mx = -INFINITY;
  for (int t = tid; t < Lk; t += 256) mx = fmaxf(mx, row[t]);
  __shared__ float sm[4]; __shared__ float ss[4];
  for (int o = 32; o > 0; o >>= 1) mx = fmaxf(mx, __shfl_down(mx, o, 64));
  int lane = tid & 63, wv = tid >> 6;
  if (lane == 0) sm[wv] = mx;
  __syncthreads();
  mx = fmaxf(fmaxf(sm[0], sm[1]), fmaxf(sm[2], sm[3]));
  float sum = 0.f;
  for (int t = tid; t < Lk; t += 256) sum += __expf(row[t] - mx);
  for (int o = 32; o > 0; o >>= 1) sum += __shfl_down(sum, o, 64);
  if (lane == 0) ss[wv] = sum;
  __syncthreads();
  sum = ss[0] + ss[1] + ss[2] + ss[3];
  float inv = 1.f / sum;
  for (int t = tid; t < Lk; t += 256) {
    float x = row[t];
    orow[t] = (x < VTHR) ? (u16)0 : f2b(__expf(x - mx) * inv);
  }
}

// softmax over axis-0 (rows) of [Mr, ldl]; f32 in -> bf16 out
__global__ __launch_bounds__(256) void col_softmax(const float* src, u16* dst, int Mr, int ldl, long long sL) {
  int c = blockIdx.x, inst = blockIdx.y;
  const float* base = src + (size_t)inst * sL + c;
  u16* ob = dst + (size_t)inst * sL + c;
  int tid = threadIdx.x;
  float mx = -INFINITY;
  for (int t = tid; t < Mr; t += 256) mx = fmaxf(mx, base[(size_t)t * ldl]);
  __shared__ float sm[4]; __shared__ float ss[4];
  for (int o = 32; o > 0; o >>= 1) mx = fmaxf(mx, __shfl_down(mx, o, 64));
  int lane = tid & 63, wv = tid >> 6;
  if (lane == 0) sm[wv] = mx;
  __syncthreads();
  mx = fmaxf(fmaxf(sm[0], sm[1]), fmaxf(sm[2], sm[3]));
  float sum = 0.f;
  for (int t = tid; t < Mr; t += 256) sum += __expf(base[(size_t)t * ldl] - mx);
  for (int o = 32; o > 0; o >>= 1) sum += __shfl_down(sum, o, 64);
  if (lane == 0) ss[wv] = sum;
  __syncthreads();
  sum = ss[0] + ss[1] + ss[2] + ss[3];
  float inv = 1.f / sum;
  for (int t = tid; t < Mr; t += 256) {
    float x = base[(size_t)t * ldl];
    ob[(size_t)t * ldl] = (x < VTHR) ? (u16)0 : f2b(__expf(x - mx) * inv);
  }
}

// ======================= launch =======================
extern "C" void kernel_launch(void* const* d_in, const int* in_sizes, int n_in,
                              void* d_out, int out_size, void* d_ws, size_t ws_size,
                              hipStream_t stream) {
  const float* ll        = (const float*)d_in[0];
  const int* am          = (const int*)d_in[1];
  const int* fp_in       = (const int*)d_in[2];   // harness delivers int64 ref input as int32
  const float* attn_w1   = (const float*)d_in[4];
  const float* attn_w2   = (const float*)d_in[5];
  const float* attn_w3   = (const float*)d_in[6];
  const float* opt_w1    = (const float*)d_in[7];
  const float* opt_w2    = (const float*)d_in[8];
  const float* opt_w3    = (const float*)d_in[9];
  const float* self_w1   = (const float*)d_in[10];
  const float* self_w2   = (const float*)d_in[11];
  const float* self_w3   = (const float*)d_in[12];
  const float* attn_fc_w = (const float*)d_in[13];
  const float* attn_fc_b = (const float*)d_in[14];
  const float* comp_fc_w = (const float*)d_in[15];
  const float* comp_fc_b = (const float*)d_in[16];
  const float* gate_fc_w = (const float*)d_in[17];
  const float* gate_fc_b = (const float*)d_in[18];
  const float* self_fc_w = (const float*)d_in[19];
  const float* self_fc_b = (const float*)d_in[20];
  float* out = (float*)d_out;

  // ---- arena ----
  const size_t BIGF = (size_t)NITEM * LOv * Hv;          // 14,680,064
  const size_t LGTF = (size_t)NITEM * LOv * LDv;         // 6,881,280
  float* optcorrF = (float*)d_ws;                        // later aliased as fusion
  float* optionF  = optcorrF + BIGF;
  float* logitF   = optionF + BIGF;
  float* qlog     = logitF + LGTF;                       // 64*224
  float* klog     = qlog + (size_t)NITEM * LOv;          // 64*480
  float* optq     = klog + (size_t)NITEM * LDv;
  float* optk     = optq + (size_t)NITEM * LOv;
  u16* wcomp = (u16*)(optk + (size_t)NITEM * LOv);       // 1024*7168
  u16* wgate = wcomp + (size_t)Hv * 7 * Hv;              // 1024*2048
  u16* wattn = wgate + (size_t)Hv * 2 * Hv;              // 1024*3072
  u16* wself = wattn + (size_t)Hv * 3 * Hv;              // 1024*4096
  u16* kqB   = wself + (size_t)Hv * 4 * Hv;              // 64*224*480
  u16* awbB  = kqB + (size_t)NITEM * LOv * LDv;          // 64*224*480
  u16* cowB  = awbB + (size_t)NITEM * LOv * LDv;         // 64*224*224
  unsigned char* optm = (unsigned char*)(cowB + (size_t)NITEM * LOv * LOv);
  unsigned char* docm = optm + (size_t)NITEM * LOv;
  int* fp = (int*)(docm + (size_t)NITEM * LDv);
  u16* U = (u16*)(fp + NITEM + 32);                      // scratch union
  const size_t E_OPT = (size_t)NITEM * LOv * Hv;         // 14,680,064
  const size_t E_DOC = (size_t)NITEM * LDv * Hv;         // 31,457,280
  // P1
  u16* optw3B = U;
  u16* optTB  = U + E_OPT;
  u16* optB   = U + 2 * E_OPT;
  u16* asbuf  = U + 3 * E_OPT;                           // 3*16*224*1024
  u16* aw1B   = asbuf + (size_t)3 * BSZ * LOv * Hv;      // 16*224*224
  u16* compA  = aw1B + (size_t)BSZ * LOv * LOv;          // 16*224*7168
  // P2
  u16* gateA  = U;                                       // 64*224*2048 (overlaps optw3B/optTB only)
  // P3
  u16* docB   = U;
  u16* docTB  = U + E_DOC;
  u16* optw3C = U + 2 * E_DOC;                           // option*attn_w3
  u16* optTC  = optw3C + E_OPT;                          // option^T
  u16* attnA  = optTC + E_OPT;                           // 64*224*3072
  // P4
  u16* selfA  = U;                                       // 64*224*4096
  u16* fusw3  = U + (size_t)NITEM * LOv * 4 * Hv;
  u16* fusTB  = fusw3 + E_OPT;
  float* fusionF = optcorrF;                             // alias (optcorr dead after phase 2)

  const long long sOH = (long long)LOv * Hv;             // 224*1024
  const long long sLL = (long long)LOv * LOv;            // 224*224
  const long long sLD = (long long)LOv * LDv;            // 224*480

  (void)hipMemsetAsync(d_out, 0, (size_t)NITEM * Hv * sizeof(float), stream);
  init_masks<<<NITEM, 256, 0, stream>>>(fp_in, am, fp, optm, docm);
  convf2b<<<1024, 256, 0, stream>>>(comp_fc_w, wcomp, Hv * 7 * Hv);
  convf2b<<<1024, 256, 0, stream>>>(gate_fc_w, wgate, Hv * 2 * Hv);
  convf2b<<<1024, 256, 0, stream>>>(attn_fc_w, wattn, Hv * 3 * Hv);
  convf2b<<<1024, 256, 0, stream>>>(self_fc_w, wself, Hv * 4 * Hv);
  build_opt<<<dim3(LOv, NITEM), 256, 0, stream>>>(ll, fp, opt_w3, optB, optw3B);
  transpose_b<<<dim3(LOv / 32, Hv / 32, NITEM), 256, 0, stream>>>(nullptr, 0, ll, fp, docm, 1, LOv, optTB);
  dot_rows<<<dim3(LOv, NITEM), 256, 0, stream>>>(nullptr, 0, ll, fp, docm, opt_w1, optq, LOv, 1);
  dot_rows<<<dim3(LOv, NITEM), 256, 0, stream>>>(nullptr, 0, ll, fp, docm, opt_w2, optk, LOv, 1);

  // ========== Phase 1: pairwise option attention + comp FC ==========
  for (int i = 0; i < NLB; i++) {
    int s = 0;
    for (int j = 0; j < NLB; j++) {
      if (j == i) continue;
      { // logit = (q*w3) . k  + q_logit + k_logit, masked
        MG p = {};
        p.A = optw3B; p.sA = sOH; p.lda = Hv; p.aidx = IX_ITQ;
        p.B = optB;   p.sB = sOH; p.ldb = Hv; p.bidx = IX_ITK;
        p.C = logitF; p.sC = sLL; p.ldc = LOv; p.cidx = IX_INST;
        p.qmask = optm; p.ldqm = LOv; p.kmask = optm; p.ldkm = LOv;
        p.qlogv = optq; p.ldql = LOv; p.klogv = optk; p.ldkl = LOv;
        p.M = LOv; p.N = LOv; p.K = Hv; p.qi = i; p.kj = j; p.epi = EP_LOGIT;
        mgemm<<<dim3(2, 2, BSZ), 256, 0, stream>>>(p);
      }
      row_softmax<<<dim3(LOv, BSZ), 256, 0, stream>>>(logitF, aw1B, LOv, LOv, sLL);
      { // a_s = aw @ opt_enc[j]   (B = opt^T)
        MG p = {};
        p.A = aw1B; p.sA = sLL; p.lda = LOv; p.aidx = IX_INST;
        p.B = optTB; p.sB = (long long)Hv * LOv; p.ldb = LOv; p.bidx = IX_ITK;
        p.Cb = asbuf + (size_t)s * BSZ * LOv * Hv; p.sC = sOH; p.ldc = Hv; p.cidx = IX_INST;
        p.M = LOv; p.N = Hv; p.K = LOv; p.qi = i; p.kj = j; p.epi = EP_BF16;
        mgemm<<<dim3(8, 2, BSZ), 256, 0, stream>>>(p);
      }
      s++;
    }
    build_compA<<<dim3(LOv, BSZ), 256, 0, stream>>>(optB, asbuf, compA, i);
    { // opt_corr[:, i] = tanh(compA @ comp_w^T + b)
      MG p = {};
      p.A = compA; p.sA = (long long)LOv * 7 * Hv; p.lda = 7 * Hv; p.aidx = IX_INST;
      p.B = wcomp; p.sB = 0; p.ldb = 7 * Hv; p.bidx = IX_INST;
      p.C = optcorrF; p.sC = sOH; p.ldc = Hv; p.cidx = IX_ITQ;
      p.bias = comp_fc_b;
      p.M = LOv; p.N = Hv; p.K = 7 * Hv; p.qi = i; p.kj = -1; p.epi = EP_TANH;
      mgemm<<<dim3(8, 2, BSZ), 256, 0, stream>>>(p);
    }
  }

  // ========== Phase 2: gate FC + blend ==========
  build_gateA<<<dim3(LOv, NITEM), 256, 0, stream>>>(ll, fp, optcorrF, gateA);
  {
    MG p = {};
    p.A = gateA; p.sA = (long long)LOv * 2 * Hv; p.lda = 2 * Hv; p.aidx = IX_INST;
    p.B = wgate; p.sB = 0; p.ldb = 2 * Hv; p.bidx = IX_INST;
    p.C = optionF; p.sC = sOH; p.ldc = Hv; p.cidx = IX_INST;
    p.bias = gate_fc_b; p.ll = ll; p.fp = fp; p.Yv = optcorrF; p.sY = sOH;
    p.M = LOv; p.N = Hv; p.K = 2 * Hv; p.qi = -1; p.kj = -1; p.epi = EP_GATE;
    mgemm<<<dim3(8, 2, NITEM), 256, 0, stream>>>(p);
  }

  // ========== Phase 3: doc attention + co-attention + attn FC ==========
  build_doc<<<dim3(LDv, NITEM), 256, 0, stream>>>(ll, docm, docB);
  transpose_b<<<dim3(LDv / 32, Hv / 32, NITEM), 256, 0, stream>>>(nullptr, 0, ll, fp, docm, 2, LDv, docTB);
  conv_act<<<dim3(LOv, NITEM), 256, 0, stream>>>(optionF, attn_w3, attnA, 3 * Hv, optw3C);
  transpose_b<<<dim3(LOv / 32, Hv / 32, NITEM), 256, 0, stream>>>(optionF, sOH, ll, fp, docm, 0, LOv, optTC);
  dot_rows<<<dim3(LOv, NITEM), 256, 0, stream>>>(optionF, sOH, ll, fp, docm, attn_w1, qlog, LOv, 0);
  dot_rows<<<dim3(LDv, NITEM), 256, 0, stream>>>(nullptr, 0, ll, fp, docm, attn_w2, klog, LDv, 2);
  { // logit [224,480]
    MG p = {};
    p.A = optw3C; p.sA = sOH; p.lda = Hv; p.aidx = IX_INST;
    p.B = docB; p.sB = (long long)LDv * Hv; p.ldb = Hv; p.bidx = IX_INST;
    p.C = logitF; p.sC = sLD; p.ldc = LDv; p.cidx = IX_INST;
    p.qmask = optm; p.ldqm = LOv; p.kmask = docm; p.ldkm = LDv;
    p.qlogv = qlog; p.ldql = LOv; p.klogv = klog; p.ldkl = LDv;
    p.M = LOv; p.N = LDv; p.K = Hv; p.qi = -1; p.kj = -1; p.epi = EP_LOGIT;
    mgemm<<<dim3(4, 2, NITEM), 256, 0, stream>>>(p);
  }
  row_softmax<<<dim3(LOv, NITEM), 256, 0, stream>>>(logitF, awbB, LDv, LDv, sLD);
  col_softmax<<<dim3(LDv, NITEM), 256, 0, stream>>>(logitF, kqB, LOv, LDv, sLD);
  { // attn = aw @ doc -> attnA block 1
    MG p = {};
    p.A = awbB; p.sA = sLD; p.lda = LDv; p.aidx = IX_INST;
    p.B = docTB; p.sB = (long long)Hv * LDv; p.ldb = LDv; p.bidx = IX_INST;
    p.Cb = attnA + Hv; p.sC = (long long)LOv * 3 * Hv; p.ldc = 3 * Hv; p.cidx = IX_INST;
    p.M = LOv; p.N = Hv; p.K = LDv; p.qi = -1; p.kj = -1; p.epi = EP_BF16;
    mgemm<<<dim3(8, 2, NITEM), 256, 0, stream>>>(p);
  }
  { // co_w = aw @ kq^T
    MG p = {};
    p.A = awbB; p.sA = sLD; p.lda = LDv; p.aidx = IX_INST;
    p.B = kqB; p.sB = sLD; p.ldb = LDv; p.bidx = IX_INST;
    p.Cb = cowB; p.sC = sLL; p.ldc = LOv; p.cidx = IX_INST;
    p.M = LOv; p.N = LOv; p.K = LDv; p.qi = -1; p.kj = -1; p.epi = EP_BF16;
    mgemm<<<dim3(2, 2, NITEM), 256, 0, stream>>>(p);
  }
  { // coattn = co_w @ option -> attnA block 2
    MG p = {};
    p.A = cowB; p.sA = sLL; p.lda = LOv; p.aidx = IX_INST;
    p.B = optTC; p.sB = (long long)Hv * LOv; p.ldb = LOv; p.bidx = IX_INST;
    p.Cb = attnA + 2 * Hv; p.sC = (long long)LOv * 3 * Hv; p.ldc = 3 * Hv; p.cidx = IX_INST;
    p.M = LOv; p.N = Hv; p.K = LOv; p.qi = -1; p.kj = -1; p.epi = EP_BF16;
    mgemm<<<dim3(8, 2, NITEM), 256, 0, stream>>>(p);
  }
  { // fusion = tanh(attnA @ attn_w^T + b)
    MG p = {};
    p.A = attnA; p.sA = (long long)LOv * 3 * Hv; p.lda = 3 * Hv; p.aidx = IX_INST;
    p.B = wattn; p.sB = 0; p.ldb = 3 * Hv; p.bidx = IX_INST;
    p.C = fusionF; p.sC = sOH; p.ldc = Hv; p.cidx = IX_INST;
    p.bias = attn_fc_b;
    p.M = LOv; p.N = Hv; p.K = 3 * Hv; p.qi = -1; p.kj = -1; p.epi = EP_TANH;
    mgemm<<<dim3(8, 2, NITEM), 256, 0, stream>>>(p);
  }

  // ========== Phase 4: self attention + self FC + masked max ==========
  conv_act<<<dim3(LOv, NITEM), 256, 0, stream>>>(fusionF, self_w3, selfA, 4 * Hv, fusw3);
  transpose_b<<<dim3(LOv / 32, Hv / 32, NITEM), 256, 0, stream>>>(fusionF, sOH, ll, fp, docm, 0, LOv, fusTB);
  dot_rows<<<dim3(LOv, NITEM), 256, 0, stream>>>(fusionF, sOH, ll, fp, docm, self_w1, qlog, LOv, 0);
  dot_rows<<<dim3(LOv, NITEM), 256, 0, stream>>>(fusionF, sOH, ll, fp, docm, self_w2, klog, LOv, 0);
  { // self logit [224,224]  (B = fusion bf16 = selfA block 0, ldb=4096)
    MG p = {};
    p.A = fusw3; p.sA = sOH; p.lda = Hv; p.aidx = IX_INST;
    p.B = selfA; p.sB = (long long)LOv * 4 * Hv; p.ldb = 4 * Hv; p.bidx = IX_INST;
    p.C = logitF; p.sC = sLL; p.ldc = LOv; p.cidx = IX_INST;
    p.qmask = optm; p.ldqm = LOv; p.kmask = optm; p.ldkm = LOv;
    p.qlogv = qlog; p.ldql = LOv; p.klogv = klog; p.ldkl = LOv;
    p.M = LOv; p.N = LOv; p.K = Hv; p.qi = -1; p.kj = -1; p.epi = EP_LOGIT;
    mgemm<<<dim3(2, 2, NITEM), 256, 0, stream>>>(p);
  }
  row_softmax<<<dim3(LOv, NITEM), 256, 0, stream>>>(logitF, awbB, LOv, LOv, sLL);
  { // attn2 = aw @ fusion -> selfA block 1
    MG p = {};
    p.A = awbB; p.sA = sLL; p.lda = LOv; p.aidx = IX_INST;
    p.B = fusTB; p.sB = (long long)Hv * LOv; p.ldb = LOv; p.bidx = IX_INST;
    p.Cb = selfA + Hv; p.sC = (long long)LOv * 4 * Hv; p.ldc = 4 * Hv; p.cidx = IX_INST;
    p.M = LOv; p.N = Hv; p.K = LOv; p.qi = -1; p.kj = -1; p.epi = EP_BF16;
    mgemm<<<dim3(8, 2, NITEM), 256, 0, stream>>>(p);
  }
  build_selfA23<<<dim3(LOv, NITEM), 256, 0, stream>>>(selfA);
  { // out = maskmax(relu(selfA @ self_w^T + b))
    MG p = {};
    p.A = selfA; p.sA = (long long)LOv * 4 * Hv; p.lda = 4 * Hv; p.aidx = IX_INST;
    p.B = wself; p.sB = 0; p.ldb = 4 * Hv; p.bidx = IX_INST;
    p.cidx = IX_INST; p.bias = self_fc_b;
    p.qmask = optm; p.ldqm = LOv; p.outmax = out;
    p.M = LOv; p.N = Hv; p.K = 4 * Hv; p.qi = -1; p.kj = -1; p.epi = EP_RELUMAX;
    mgemm<<<dim3(8, 2, NITEM), 256, 0, stream>>>(p);
  }
}

// Round 4
// 2950.956 us; speedup vs baseline: 8.6335x; 1.3240x over previous
//
#include <hip/hip_runtime.h>
#include <math.h>

// Problem constants (fixed by the reference: H=1024, B=16, L=4, S=512)
#define Sv   512
#define Hv   1024
#define BSZ  16
#define NLB  4
#define NITEM 64          // BSZ*NLB
#define LOv  224          // >= max option len (512-300=212), multiple of 32
#define LDv  480          // >= max doc len (449), multiple of 32
#define NEGV (-1e30f)
#define VTHR (-1e20f)

typedef unsigned short u16;
typedef __attribute__((ext_vector_type(8))) short short8;   // 8 bf16 = 4 VGPRs (MFMA A/B frag)
using floatx4 = __attribute__((ext_vector_type(4))) float;

__device__ __forceinline__ u16 f2b(float x) {  // f32 -> bf16 RNE
  unsigned u = __float_as_uint(x);
  return (u16)((u + 0x7FFFu + ((u >> 16) & 1u)) >> 16);
}
__device__ __forceinline__ float b2f(u16 b) { return __uint_as_float(((unsigned)b) << 16); }

__device__ __forceinline__ float opt_view_f(const float* ll, const int* fp, int item, int t, int h) {
  int idx = fp[item] + t;
  return (idx < Sv) ? ll[((size_t)item * Sv + idx) * Hv + h] : 0.f;
}

// ======================= bf16 MFMA GEMM (non-split) =======================
enum { EP_BF16 = 0, EP_LOGIT = 1 };
enum { IX_INST = 0, IX_ITQ = 1, IX_ITK = 2 };

struct MG {
  const u16* A; long long sA; int lda; int aidx;
  const u16* B; long long sB; int ldb; int bidx;
  float* C; long long sC; int ldc; int cidx;
  u16* Cb;
  const unsigned char* qmask; int ldqm;
  const unsigned char* kmask; int ldkm;
  const float* qlogv; int ldql;
  const float* klogv; int ldkl;
  int M, N, K, qi, kj, epi, pm;   // pm: pairmode (z = pair*BSZ + b, pair=i*3+jj)
};

__global__ __launch_bounds__(256) void mgemm(MG p) {
  __shared__ u16 As[128][40];
  __shared__ u16 Bs[128][40];
  int inst = blockIdx.z;
  int itq, itk;
  if (p.pm) {
    int b = inst % BSZ, pair = inst / BSZ;
    int i = pair / 3, jj = pair % 3;
    int j = jj + (jj >= i ? 1 : 0);
    itq = b * NLB + i; itk = b * NLB + j;
  } else {
    itq = (p.qi >= 0) ? inst * NLB + p.qi : inst;
    itk = (p.kj >= 0) ? inst * NLB + p.kj : inst;
  }
  int ai = (p.aidx == IX_ITQ) ? itq : (p.aidx == IX_ITK ? itk : inst);
  int bi = (p.bidx == IX_ITQ) ? itq : (p.bidx == IX_ITK ? itk : inst);
  int ci = (p.cidx == IX_ITQ) ? itq : (p.cidx == IX_ITK ? itk : inst);
  const u16* Ab = p.A + (size_t)ai * p.sA;
  const u16* Bb = p.B + (size_t)bi * p.sB;
  int tid = threadIdx.x;
  int m0 = blockIdx.y * 128, n0 = blockIdx.x * 128;
  int sr = tid >> 1, sk = (tid & 1) * 16;
  int wave = tid >> 6, lane = tid & 63;
  int wm = (wave >> 1) * 64, wn = (wave & 1) * 64;
  int col = lane & 15, quad = lane >> 4;
  floatx4 acc[4][4] = {};

  for (int k0 = 0; k0 < p.K; k0 += 32) {
    {
      int m = m0 + sr;
      if (m < p.M) {
        const u16* src = Ab + (size_t)m * p.lda + k0 + sk;
        *(uint4*)&As[sr][sk]     = *(const uint4*)src;
        *(uint4*)&As[sr][sk + 8] = *(const uint4*)(src + 8);
      } else {
        uint4 z = {0, 0, 0, 0};
        *(uint4*)&As[sr][sk] = z; *(uint4*)&As[sr][sk + 8] = z;
      }
      int n = n0 + sr;
      if (n < p.N) {
        const u16* src = Bb + (size_t)n * p.ldb + k0 + sk;
        *(uint4*)&Bs[sr][sk]     = *(const uint4*)src;
        *(uint4*)&Bs[sr][sk + 8] = *(const uint4*)(src + 8);
      } else {
        uint4 z = {0, 0, 0, 0};
        *(uint4*)&Bs[sr][sk] = z; *(uint4*)&Bs[sr][sk + 8] = z;
      }
    }
    __syncthreads();
    short8 a[4], b[4];
    #pragma unroll
    for (int mi = 0; mi < 4; mi++) a[mi] = *(const short8*)&As[wm + mi * 16 + col][quad * 8];
    #pragma unroll
    for (int ni = 0; ni < 4; ni++) b[ni] = *(const short8*)&Bs[wn + ni * 16 + col][quad * 8];
    #pragma unroll
    for (int mi = 0; mi < 4; mi++)
      #pragma unroll
      for (int ni = 0; ni < 4; ni++)
        acc[mi][ni] = __builtin_amdgcn_mfma_f32_16x16x32_bf16(a[mi], b[ni], acc[mi][ni], 0, 0, 0);
    __syncthreads();
  }

  #pragma unroll
  for (int mi = 0; mi < 4; mi++) {
    #pragma unroll
    for (int ni = 0; ni < 4; ni++) {
      int n = n0 + wn + ni * 16 + col;
      if (n >= p.N) continue;
      #pragma unroll
      for (int r = 0; r < 4; r++) {
        int m = m0 + wm + mi * 16 + quad * 4 + r;
        if (m >= p.M) continue;
        float v = acc[mi][ni][r];
        if (p.epi == EP_BF16) {
          p.Cb[(size_t)ci * p.sC + (size_t)m * p.ldc + n] = f2b(v);
        } else {  // EP_LOGIT
          bool qm = p.qmask[itq * p.ldqm + m] != 0;
          bool km = p.kmask[itk * p.ldkm + n] != 0;
          p.C[(size_t)ci * p.sC + (size_t)m * p.ldc + n] =
            (qm && km) ? (v + p.qlogv[(size_t)itq * p.ldql + m] + p.klogv[(size_t)itk * p.ldkl + n]) : NEGV;
        }
      }
    }
  }
}

// ======================= split-K FC GEMM (weights B [N=1024][K]) =======================
// Flat grid; XCD-grouping swizzle: id = nt*8 + (g%8) + 64*(g/8). All 8 N-tiles of one
// (inst, mtile, kchunk) group land on the same XCD (round-robin dispatch) so the shared
// A-stripe (128x1024x2B = 0.25 MB) is fetched from HBM ~once per group, served by XCD-L2.
struct MGS {
  const u16* A; long long sA; int lda;
  const u16* B;                     // [1024][K] bf16
  float* Cacc;                      // [insts][M][1024] f32, pre-zeroed; atomicAdd
  int M, KS;                        // K chunks of 1024
};

__global__ __launch_bounds__(256) void mgemm_sk(MGS p) {
  __shared__ u16 As[128][40];
  __shared__ u16 Bs[128][40];
  int id = blockIdx.x;
  int hi = id >> 6, rem = id & 63;
  int nt = rem >> 3, low = rem & 7;
  int g = (hi << 3) | low;
  int ks = g % p.KS;
  int mt = (g / p.KS) & 1;
  int inst = g / (p.KS * 2);
  const u16* Ab = p.A + (size_t)inst * p.sA;
  int tid = threadIdx.x;
  int m0 = mt * 128, n0 = nt * 128;
  int sr = tid >> 1, sk = (tid & 1) * 16;
  int wave = tid >> 6, lane = tid & 63;
  int wm = (wave >> 1) * 64, wn = (wave & 1) * 64;
  int col = lane & 15, quad = lane >> 4;
  floatx4 acc[4][4] = {};

  int kb = ks * 1024;
  for (int k0 = kb; k0 < kb + 1024; k0 += 32) {
    {
      int m = m0 + sr;
      if (m < p.M) {
        const u16* src = Ab + (size_t)m * p.lda + k0 + sk;
        *(uint4*)&As[sr][sk]     = *(const uint4*)src;
        *(uint4*)&As[sr][sk + 8] = *(const uint4*)(src + 8);
      } else {
        uint4 z = {0, 0, 0, 0};
        *(uint4*)&As[sr][sk] = z; *(uint4*)&As[sr][sk + 8] = z;
      }
      int n = n0 + sr;
      const u16* src = p.B + (size_t)n * (p.KS * 1024) + k0 + sk;
      *(uint4*)&Bs[sr][sk]     = *(const uint4*)src;
      *(uint4*)&Bs[sr][sk + 8] = *(const uint4*)(src + 8);
    }
    __syncthreads();
    short8 a[4], b[4];
    #pragma unroll
    for (int mi = 0; mi < 4; mi++) a[mi] = *(const short8*)&As[wm + mi * 16 + col][quad * 8];
    #pragma unroll
    for (int ni = 0; ni < 4; ni++) b[ni] = *(const short8*)&Bs[wn + ni * 16 + col][quad * 8];
    #pragma unroll
    for (int mi = 0; mi < 4; mi++)
      #pragma unroll
      for (int ni = 0; ni < 4; ni++)
        acc[mi][ni] = __builtin_amdgcn_mfma_f32_16x16x32_bf16(a[mi], b[ni], acc[mi][ni], 0, 0, 0);
    __syncthreads();
  }

  float* Cb = p.Cacc + (size_t)inst * p.M * Hv;
  #pragma unroll
  for (int mi = 0; mi < 4; mi++) {
    #pragma unroll
    for (int ni = 0; ni < 4; ni++) {
      int n = n0 + wn + ni * 16 + col;
      #pragma unroll
      for (int r = 0; r < 4; r++) {
        int m = m0 + wm + mi * 16 + quad * 4 + r;
        if (m < p.M) atomicAdd(Cb + (size_t)m * Hv + n, acc[mi][ni][r]);
      }
    }
  }
}

// ======================= FC epilogues =======================
__global__ __launch_bounds__(256) void ep_comp(const float* Cacc, const float* bias,
                                               float* optcorr, int i) {
  int t = blockIdx.x, b = blockIdx.y;
  const float* s = Cacc + ((size_t)b * LOv + t) * Hv;
  float* d = optcorr + (((size_t)(b * NLB + i)) * LOv + t) * Hv;
  for (int h = threadIdx.x; h < Hv; h += 256) d[h] = tanhf(s[h] + bias[h]);
}

__global__ __launch_bounds__(256) void ep_gate(const float* Cacc, const float* bias,
                                               const float* ll, const int* fp,
                                               const float* corr, float* option) {
  int t = blockIdx.x, item = blockIdx.y;
  const float* s = Cacc + ((size_t)item * LOv + t) * Hv;
  const float* cr = corr + ((size_t)item * LOv + t) * Hv;
  float* d = option + ((size_t)item * LOv + t) * Hv;
  int idx = fp[item] + t;
  bool v = idx < Sv;
  const float* src = ll + ((size_t)item * Sv + (v ? idx : 0)) * Hv;
  for (int h = threadIdx.x; h < Hv; h += 256) {
    float g = 1.f / (1.f + __expf(-(s[h] + bias[h])));
    float xv = v ? src[h] : 0.f;
    d[h] = xv * g + cr[h] * (1.f - g);
  }
}

__global__ __launch_bounds__(256) void ep_tanh(const float* Cacc, const float* bias, float* dst) {
  int t = blockIdx.x, item = blockIdx.y;
  const float* s = Cacc + ((size_t)item * LOv + t) * Hv;
  float* d = dst + ((size_t)item * LOv + t) * Hv;
  for (int h = threadIdx.x; h < Hv; h += 256) d[h] = tanhf(s[h] + bias[h]);
}

// final: out[item,h] = max over valid t of relu(Cacc + bias)
__global__ __launch_bounds__(256) void ep_selfmax(const float* Cacc, const float* bias,
                                                  const unsigned char* optm, float* out) {
  int item = blockIdx.x;
  int h0 = threadIdx.x;
  float mx[4] = {-INFINITY, -INFINITY, -INFINITY, -INFINITY};
  for (int t = 0; t < LOv; t++) {
    if (!optm[item * LOv + t]) continue;
    const float* s = Cacc + ((size_t)item * LOv + t) * Hv;
    #pragma unroll
    for (int q = 0; q < 4; q++) {
      int h = h0 + q * 256;
      mx[q] = fmaxf(mx[q], fmaxf(s[h] + bias[h], 0.f));
    }
  }
  #pragma unroll
  for (int q = 0; q < 4; q++) out[(size_t)item * Hv + h0 + q * 256] = mx[q];
}

// ======================= helpers =======================
__global__ __launch_bounds__(256) void init_masks(const int* fp_in, const int* am, int* fp,
                                                  unsigned char* optm, unsigned char* docm) {
  int item = blockIdx.x;
  int f = fp_in[item];
  if (threadIdx.x == 0) fp[item] = f;
  for (int t = threadIdx.x; t < LDv; t += blockDim.x) {
    docm[item * LDv + t] = (t < f && t < Sv && am[item * Sv + t] > 0) ? 1 : 0;
    if (t < LOv) {
      int idx = f + t;
      optm[item * LOv + t] = (idx < Sv && am[item * Sv + idx] > 0) ? 1 : 0;
    }
  }
}

__global__ __launch_bounds__(256) void convf2b(const float* src, u16* dst, int n) {
  int i = blockIdx.x * 256 + threadIdx.x;
  int stride = gridDim.x * 256;
  for (; i < n; i += stride) dst[i] = f2b(src[i]);
}

__global__ __launch_bounds__(256) void build_opt(const float* ll, const int* fp, const float* w3,
                                                 u16* optB, u16* optw3B) {
  int t = blockIdx.x, item = blockIdx.y;
  int idx = fp[item] + t;
  bool v = idx < Sv;
  const float* src = ll + ((size_t)item * Sv + (v ? idx : 0)) * Hv;
  size_t o = ((size_t)item * LOv + t) * Hv;
  for (int h = threadIdx.x; h < Hv; h += 256) {
    float x = v ? src[h] : 0.f;
    optB[o + h] = f2b(x);
    optw3B[o + h] = f2b(x * w3[h]);
  }
}

__global__ __launch_bounds__(256) void build_doc(const float* ll, const unsigned char* docm, u16* docB) {
  int t = blockIdx.x, item = blockIdx.y;
  bool v = docm[item * LDv + t] != 0;
  const float* src = ll + ((size_t)item * Sv + (t < Sv ? t : 0)) * Hv;
  size_t o = ((size_t)item * LDv + t) * Hv;
  for (int h = threadIdx.x; h < Hv; h += 256) docB[o + h] = v ? f2b(src[h]) : (u16)0;
}

__global__ __launch_bounds__(256) void transpose_b(const float* src, long long sS,
                                                   const float* ll, const int* fp, const unsigned char* docm,
                                                   int mode, int Lt, u16* out) {
  __shared__ float tile[32][33];
  int t0 = blockIdx.x * 32, h0 = blockIdx.y * 32, item = blockIdx.z;
  int tx = threadIdx.x & 31, ty0 = threadIdx.x >> 5;
  for (int yy = ty0; yy < 32; yy += 8) {
    int t = t0 + yy, h = h0 + tx;
    float v = 0.f;
    if (t < Lt) {
      if (mode == 0)      v = src[(size_t)item * sS + (size_t)t * Hv + h];
      else if (mode == 1) { int idx = fp[item] + t; if (idx < Sv) v = ll[((size_t)item * Sv + idx) * Hv + h]; }
      else                { if (docm[item * LDv + t]) v = ll[((size_t)item * Sv + t) * Hv + h]; }
    }
    tile[yy][tx] = v;
  }
  __syncthreads();
  for (int yy = ty0; yy < 32; yy += 8) {
    int h = h0 + yy, t = t0 + tx;
    if (t < Lt) out[((size_t)item * Hv + h) * (size_t)Lt + t] = f2b(tile[tx][yy]);
  }
}

// compA = concat7([cur, cur*a0, cur-a0, cur*a1, cur-a1, cur*a2, cur-a2]); asbuf [12*BSZ] pair-major
__global__ __launch_bounds__(256) void build_compA(const u16* optB, const u16* asbuf, u16* compA, int i) {
  int t = blockIdx.x, b = blockIdx.y;
  int item = b * NLB + i;
  const u16* cur = optB + ((size_t)item * LOv + t) * Hv;
  u16* dst = compA + ((size_t)b * LOv + t) * (7 * Hv);
  for (int h = threadIdx.x; h < Hv; h += 256) {
    u16 cu = cur[h]; float c = b2f(cu);
    dst[h] = cu;
    #pragma unroll
    for (int s = 0; s < 3; s++) {
      float a = b2f(asbuf[(((size_t)(i * 3 + s) * BSZ + b) * LOv + t) * Hv + h]);
      dst[(size_t)(1 + 2 * s) * Hv + h] = f2b(c * a);
      dst[(size_t)(2 + 2 * s) * Hv + h] = f2b(c - a);
    }
  }
}

__global__ __launch_bounds__(256) void build_gateA(const float* ll, const int* fp, const float* corr, u16* gateA) {
  int t = blockIdx.x, item = blockIdx.y;
  int idx = fp[item] + t;
  bool v = idx < Sv;
  const float* src = ll + ((size_t)item * Sv + (v ? idx : 0)) * Hv;
  u16* dst = gateA + ((size_t)item * LOv + t) * (2 * Hv);
  const float* cr = corr + ((size_t)item * LOv + t) * Hv;
  for (int h = threadIdx.x; h < Hv; h += 256) {
    dst[h] = f2b(v ? src[h] : 0.f);
    dst[Hv + h] = f2b(cr[h]);
  }
}

__global__ __launch_bounds__(256) void conv_act(const float* src, const float* w3,
                                                u16* dst1, int ld1, u16* dstw3) {
  int t = blockIdx.x, item = blockIdx.y;
  const float* s = src + ((size_t)item * LOv + t) * Hv;
  u16* d1 = dst1 + ((size_t)item * LOv + t) * ld1;
  u16* d2 = dstw3 + ((size_t)item * LOv + t) * Hv;
  for (int h = threadIdx.x; h < Hv; h += 256) {
    float x = s[h];
    d1[h] = f2b(x);
    d2[h] = f2b(x * w3[h]);
  }
}

__global__ __launch_bounds__(256) void build_selfA23(u16* selfA) {
  int t = blockIdx.x, item = blockIdx.y;
  u16* row = selfA + ((size_t)item * LOv + t) * (4 * Hv);
  for (int h = threadIdx.x; h < Hv; h += 256) {
    float f = b2f(row[h]), a = b2f(row[Hv + h]);
    row[2 * Hv + h] = f2b(f * a);
    row[3 * Hv + h] = f2b(f - a);
  }
}

__global__ __launch_bounds__(256) void dot_rows(const float* src, long long sS,
                                                const float* ll, const int* fp, const unsigned char* docm,
                                                const float* w, float* outv, int ldo, int mode) {
  int t = blockIdx.x, item = blockIdx.y;
  int tid = threadIdx.x;
  float s = 0.f;
  for (int h = tid; h < Hv; h += 256) {
    float v;
    if (mode == 0)      v = src[(size_t)item * sS + (size_t)t * Hv + h];
    else if (mode == 1) v = opt_view_f(ll, fp, item, t, h);
    else                v = docm[item * LDv + t] ? ll[((size_t)item * Sv + t) * Hv + h] : 0.f;
    s += v * w[h];
  }
  __shared__ float red[4];
  for (int o = 32; o > 0; o >>= 1) s += __shfl_down(s, o, 64);
  int lane = tid & 63, wv = tid >> 6;
  if (lane == 0) red[wv] = s;
  __syncthreads();
  if (tid == 0) outv[(size_t)item * ldo + t] = red[0] + red[1] + red[2] + red[3];
}

__global__ __launch_bounds__(256) void row_softmax(const float* src, u16* dst, int Lk, int ldl, long long sL) {
  int m = blockIdx.x, inst = blockIdx.y;
  const float* row = src + (size_t)inst * sL + (size_t)m * ldl;
  u16* orow = dst + (size_t)inst * sL + (size_t)m * ldl;
  int tid = threadIdx.x;
  float mx = -INFINITY;
  for (int t = tid; t < Lk; t += 256) mx = fmaxf(mx, row[t]);
  __shared__ float sm[4]; __shared__ float ss[4];
  for (int o = 32; o > 0; o >>= 1) mx = fmaxf(mx, __shfl_down(mx, o, 64));
  int lane = tid & 63, wv = tid >> 6;
  if (lane == 0) sm[wv] = mx;
  __syncthreads();
  mx = fmaxf(fmaxf(sm[0], sm[1]), fmaxf(sm[2], sm[3]));
  float sum = 0.f;
  for (int t = tid; t < Lk; t += 256) sum += __expf(row[t] - mx);
  for (int o = 32; o > 0; o >>= 1) sum += __shfl_down(sum, o, 64);
  if (lane == 0) ss[wv] = sum;
  __syncthreads();
  sum = ss[0] + ss[1] + ss[2] + ss[3];
  float inv = 1.f / sum;
  for (int t = tid; t < Lk; t += 256) {
    float x = row[t];
    orow[t] = (x < VTHR) ? (u16)0 : f2b(__expf(x - mx) * inv);
  }
}

__global__ __launch_bounds__(256) void col_softmax(const float* src, u16* dst, int Mr, int ldl, long long sL) {
  int c = blockIdx.x, inst = blockIdx.y;
  const float* base = src + (size_t)inst * sL + c;
  u16* ob = dst + (size_t)inst * sL + c;
  int tid = threadIdx.x;
  float mx = -INFINITY;
  for (int t = tid; t < Mr; t += 256) mx = fmaxf(mx, base[(size_t)t * ldl]);
  __shared__ float sm[4]; __shared__ float ss[4];
  for (int o = 32; o > 0; o >>= 1) mx = fmaxf(mx, __shfl_down(mx, o, 64));
  int lane = tid & 63, wv = tid >> 6;
  if (lane == 0) sm[wv] = mx;
  __syncthreads();
  mx = fmaxf(fmaxf(sm[0], sm[1]), fmaxf(sm[2], sm[3]));
  float sum = 0.f;
  for (int t = tid; t < Mr; t += 256) sum += __expf(base[(size_t)t * ldl] - mx);
  for (int o = 32; o > 0; o >>= 1) sum += __shfl_down(sum, o, 64);
  if (lane == 0) ss[wv] = sum;
  __syncthreads();
  sum = ss[0] + ss[1] + ss[2] + ss[3];
  float inv = 1.f / sum;
  for (int t = tid; t < Mr; t += 256) {
    float x = base[(size_t)t * ldl];
    ob[(size_t)t * ldl] = (x < VTHR) ? (u16)0 : f2b(__expf(x - mx) * inv);
  }
}

// ======================= launch =======================
extern "C" void kernel_launch(void* const* d_in, const int* in_sizes, int n_in,
                              void* d_out, int out_size, void* d_ws, size_t ws_size,
                              hipStream_t stream) {
  const float* ll        = (const float*)d_in[0];
  const int* am          = (const int*)d_in[1];
  const int* fp_in       = (const int*)d_in[2];   // harness delivers int64 ref input as int32
  const float* attn_w1   = (const float*)d_in[4];
  const float* attn_w2   = (const float*)d_in[5];
  const float* attn_w3   = (const float*)d_in[6];
  const float* opt_w1    = (const float*)d_in[7];
  const float* opt_w2    = (const float*)d_in[8];
  const float* opt_w3    = (const float*)d_in[9];
  const float* self_w1   = (const float*)d_in[10];
  const float* self_w2   = (const float*)d_in[11];
  const float* self_w3   = (const float*)d_in[12];
  const float* attn_fc_w = (const float*)d_in[13];
  const float* attn_fc_b = (const float*)d_in[14];
  const float* comp_fc_w = (const float*)d_in[15];
  const float* comp_fc_b = (const float*)d_in[16];
  const float* gate_fc_w = (const float*)d_in[17];
  const float* gate_fc_b = (const float*)d_in[18];
  const float* self_fc_w = (const float*)d_in[19];
  const float* self_fc_b = (const float*)d_in[20];
  float* out = (float*)d_out;

  // ---- arena ----
  const size_t BIGF = (size_t)NITEM * LOv * Hv;          // 14,680,064
  float* optcorrF = (float*)d_ws;                        // later aliased as fusion
  float* optionF  = optcorrF + BIGF;
  float* logitF   = optionF + BIGF;                      // 14.68M floats; also split-K Cacc
  float* Cacc     = logitF;
  float* qlog     = logitF + BIGF;
  float* klog     = qlog + (size_t)NITEM * LOv;
  float* optq     = klog + (size_t)NITEM * LDv;
  float* optk     = optq + (size_t)NITEM * LOv;
  u16* wcomp = (u16*)(optk + (size_t)NITEM * LOv);       // 1024*7168
  u16* wgate = wcomp + (size_t)Hv * 7 * Hv;
  u16* wattn = wgate + (size_t)Hv * 2 * Hv;
  u16* wself = wattn + (size_t)Hv * 3 * Hv;
  u16* kqB   = wself + (size_t)Hv * 4 * Hv;              // 64*224*480
  u16* awbB  = kqB + (size_t)NITEM * LOv * LDv;
  u16* cowB  = awbB + (size_t)NITEM * LOv * LDv;
  unsigned char* optm = (unsigned char*)(cowB + (size_t)NITEM * LOv * LOv);
  unsigned char* docm = optm + (size_t)NITEM * LOv;
  int* fp = (int*)(docm + (size_t)NITEM * LDv);
  u16* U = (u16*)(fp + NITEM + 32);
  const size_t E_OPT = (size_t)NITEM * LOv * Hv;
  const size_t E_DOC = (size_t)NITEM * LDv * Hv;
  // P1
  u16* optw3B = U;
  u16* optTB  = U + E_OPT;
  u16* optB   = U + 2 * E_OPT;
  u16* asbuf  = U + 3 * E_OPT;                           // 12*16*224*1024
  u16* aw1B   = asbuf + (size_t)12 * BSZ * LOv * Hv;     // 192*224*224
  u16* compA  = aw1B + (size_t)12 * BSZ * LOv * LOv;     // 16*224*7168
  // P2
  u16* gateA  = U;
  // P3
  u16* docB   = U;
  u16* docTB  = U + E_DOC;
  u16* optw3C = U + 2 * E_DOC;
  u16* optTC  = optw3C + E_OPT;
  u16* attnA  = optTC + E_OPT;                           // 64*224*3072
  // P4
  u16* selfA  = U;                                       // 64*224*4096
  u16* fusw3  = U + (size_t)NITEM * LOv * 4 * Hv;
  u16* fusTB  = fusw3 + E_OPT;
  float* fusionF = optcorrF;

  const long long sOH = (long long)LOv * Hv;
  const long long sLL = (long long)LOv * LOv;
  const long long sLD = (long long)LOv * LDv;
  const size_t CB16 = (size_t)BSZ * LOv * Hv * sizeof(float);    // comp Cacc bytes
  const size_t CB64 = (size_t)NITEM * LOv * Hv * sizeof(float);

  init_masks<<<NITEM, 256, 0, stream>>>(fp_in, am, fp, optm, docm);
  convf2b<<<1024, 256, 0, stream>>>(comp_fc_w, wcomp, Hv * 7 * Hv);
  convf2b<<<1024, 256, 0, stream>>>(gate_fc_w, wgate, Hv * 2 * Hv);
  convf2b<<<1024, 256, 0, stream>>>(attn_fc_w, wattn, Hv * 3 * Hv);
  convf2b<<<1024, 256, 0, stream>>>(self_fc_w, wself, Hv * 4 * Hv);
  build_opt<<<dim3(LOv, NITEM), 256, 0, stream>>>(ll, fp, opt_w3, optB, optw3B);
  transpose_b<<<dim3(LOv / 32, Hv / 32, NITEM), 256, 0, stream>>>(nullptr, 0, ll, fp, docm, 1, LOv, optTB);
  dot_rows<<<dim3(LOv, NITEM), 256, 0, stream>>>(nullptr, 0, ll, fp, docm, opt_w1, optq, LOv, 1);
  dot_rows<<<dim3(LOv, NITEM), 256, 0, stream>>>(nullptr, 0, ll, fp, docm, opt_w2, optk, LOv, 1);

  // ========== Phase 1: all 12 pairwise logits -> softmax -> a_s, batched ==========
  { // logits for all (i,j) pairs: z = pair*16 + b
    MG p = {};
    p.A = optw3B; p.sA = sOH; p.lda = Hv; p.aidx = IX_ITQ;
    p.B = optB;   p.sB = sOH; p.ldb = Hv; p.bidx = IX_ITK;
    p.C = logitF; p.sC = sLL; p.ldc = LOv; p.cidx = IX_INST;
    p.qmask = optm; p.ldqm = LOv; p.kmask = optm; p.ldkm = LOv;
    p.qlogv = optq; p.ldql = LOv; p.klogv = optk; p.ldkl = LOv;
    p.M = LOv; p.N = LOv; p.K = Hv; p.epi = EP_LOGIT; p.pm = 1;
    mgemm<<<dim3(2, 2, 12 * BSZ), 256, 0, stream>>>(p);
  }
  row_softmax<<<dim3(LOv, 12 * BSZ), 256, 0, stream>>>(logitF, aw1B, LOv, LOv, sLL);
  { // a_s = aw @ opt_enc[j] for all pairs -> asbuf[pair][b]
    MG p = {};
    p.A = aw1B; p.sA = sLL; p.lda = LOv; p.aidx = IX_INST;
    p.B = optTB; p.sB = (long long)Hv * LOv; p.ldb = LOv; p.bidx = IX_ITK;
    p.Cb = asbuf; p.sC = sOH; p.ldc = Hv; p.cidx = IX_INST;
    p.M = LOv; p.N = Hv; p.K = LOv; p.epi = EP_BF16; p.pm = 1;
    mgemm<<<dim3(8, 2, 12 * BSZ), 256, 0, stream>>>(p);
  }
  for (int i = 0; i < NLB; i++) {
    build_compA<<<dim3(LOv, BSZ), 256, 0, stream>>>(optB, asbuf, compA, i);
    (void)hipMemsetAsync(Cacc, 0, CB16, stream);
    MGS p = {compA, (long long)LOv * 7 * Hv, 7 * Hv, wcomp, Cacc, LOv, 7};
    mgemm_sk<<<16 * BSZ * 7, 256, 0, stream>>>(p);
    ep_comp<<<dim3(LOv, BSZ), 256, 0, stream>>>(Cacc, comp_fc_b, optcorrF, i);
  }

  // ========== Phase 2: gate FC + blend ==========
  build_gateA<<<dim3(LOv, NITEM), 256, 0, stream>>>(ll, fp, optcorrF, gateA);
  (void)hipMemsetAsync(Cacc, 0, CB64, stream);
  {
    MGS p = {gateA, (long long)LOv * 2 * Hv, 2 * Hv, wgate, Cacc, LOv, 2};
    mgemm_sk<<<16 * NITEM * 2, 256, 0, stream>>>(p);
  }
  ep_gate<<<dim3(LOv, NITEM), 256, 0, stream>>>(Cacc, gate_fc_b, ll, fp, optcorrF, optionF);

  // ========== Phase 3: doc attention + co-attention + attn FC ==========
  build_doc<<<dim3(LDv, NITEM), 256, 0, stream>>>(ll, docm, docB);
  transpose_b<<<dim3(LDv / 32, Hv / 32, NITEM), 256, 0, stream>>>(nullptr, 0, ll, fp, docm, 2, LDv, docTB);
  conv_act<<<dim3(LOv, NITEM), 256, 0, stream>>>(optionF, attn_w3, attnA, 3 * Hv, optw3C);
  transpose_b<<<dim3(LOv / 32, Hv / 32, NITEM), 256, 0, stream>>>(optionF, sOH, ll, fp, docm, 0, LOv, optTC);
  dot_rows<<<dim3(LOv, NITEM), 256, 0, stream>>>(optionF, sOH, ll, fp, docm, attn_w1, qlog, LOv, 0);
  dot_rows<<<dim3(LDv, NITEM), 256, 0, stream>>>(nullptr, 0, ll, fp, docm, attn_w2, klog, LDv, 2);
  { // logit [224,480]
    MG p = {};
    p.A = optw3C; p.sA = sOH; p.lda = Hv; p.aidx = IX_INST;
    p.B = docB; p.sB = (long long)LDv * Hv; p.ldb = Hv; p.bidx = IX_INST;
    p.C = logitF; p.sC = sLD; p.ldc = LDv; p.cidx = IX_INST;
    p.qmask = optm; p.ldqm = LOv; p.kmask = docm; p.ldkm = LDv;
    p.qlogv = qlog; p.ldql = LOv; p.klogv = klog; p.ldkl = LDv;
    p.M = LOv; p.N = LDv; p.K = Hv; p.qi = -1; p.kj = -1; p.epi = EP_LOGIT;
    mgemm<<<dim3(4, 2, NITEM), 256, 0, stream>>>(p);
  }
  row_softmax<<<dim3(LOv, NITEM), 256, 0, stream>>>(logitF, awbB, LDv, LDv, sLD);
  col_softmax<<<dim3(LDv, NITEM), 256, 0, stream>>>(logitF, kqB, LOv, LDv, sLD);
  { // attn = aw @ doc -> attnA block 1
    MG p = {};
    p.A = awbB; p.sA = sLD; p.lda = LDv; p.aidx = IX_INST;
    p.B = docTB; p.sB = (long long)Hv * LDv; p.ldb = LDv; p.bidx = IX_INST;
    p.Cb = attnA + Hv; p.sC = (long long)LOv * 3 * Hv; p.ldc = 3 * Hv; p.cidx = IX_INST;
    p.M = LOv; p.N = Hv; p.K = LDv; p.qi = -1; p.kj = -1; p.epi = EP_BF16;
    mgemm<<<dim3(8, 2, NITEM), 256, 0, stream>>>(p);
  }
  { // co_w = aw @ kq^T
    MG p = {};
    p.A = awbB; p.sA = sLD; p.lda = LDv; p.aidx = IX_INST;
    p.B = kqB; p.sB = sLD; p.ldb = LDv; p.bidx = IX_INST;
    p.Cb = cowB; p.sC = sLL; p.ldc = LOv; p.cidx = IX_INST;
    p.M = LOv; p.N = LOv; p.K = LDv; p.qi = -1; p.kj = -1; p.epi = EP_BF16;
    mgemm<<<dim3(2, 2, NITEM), 256, 0, stream>>>(p);
  }
  { // coattn = co_w @ option -> attnA block 2
    MG p = {};
    p.A = cowB; p.sA = sLL; p.lda = LOv; p.aidx = IX_INST;
    p.B = optTC; p.sB = (long long)Hv * LOv; p.ldb = LOv; p.bidx = IX_INST;
    p.Cb = attnA + 2 * Hv; p.sC = (long long)LOv * 3 * Hv; p.ldc = 3 * Hv; p.cidx = IX_INST;
    p.M = LOv; p.N = Hv; p.K = LOv; p.qi = -1; p.kj = -1; p.epi = EP_BF16;
    mgemm<<<dim3(8, 2, NITEM), 256, 0, stream>>>(p);
  }
  (void)hipMemsetAsync(Cacc, 0, CB64, stream);
  {
    MGS p = {attnA, (long long)LOv * 3 * Hv, 3 * Hv, wattn, Cacc, LOv, 3};
    mgemm_sk<<<16 * NITEM * 3, 256, 0, stream>>>(p);
  }
  ep_tanh<<<dim3(LOv, NITEM), 256, 0, stream>>>(Cacc, attn_fc_b, fusionF);

  // ========== Phase 4: self attention + self FC + masked max ==========
  conv_act<<<dim3(LOv, NITEM), 256, 0, stream>>>(fusionF, self_w3, selfA, 4 * Hv, fusw3);
  transpose_b<<<dim3(LOv / 32, Hv / 32, NITEM), 256, 0, stream>>>(fusionF, sOH, ll, fp, docm, 0, LOv, fusTB);
  dot_rows<<<dim3(LOv, NITEM), 256, 0, stream>>>(fusionF, sOH, ll, fp, docm, self_w1, qlog, LOv, 0);
  dot_rows<<<dim3(LOv, NITEM), 256, 0, stream>>>(fusionF, sOH, ll, fp, docm, self_w2, klog, LOv, 0);
  { // self logit (B = fusion bf16 = selfA block 0, ldb=4096)
    MG p = {};
    p.A = fusw3; p.sA = sOH; p.lda = Hv; p.aidx = IX_INST;
    p.B = selfA; p.sB = (long long)LOv * 4 * Hv; p.ldb = 4 * Hv; p.bidx = IX_INST;
    p.C = logitF; p.sC = sLL; p.ldc = LOv; p.cidx = IX_INST;
    p.qmask = optm; p.ldqm = LOv; p.kmask = optm; p.ldkm = LOv;
    p.qlogv = qlog; p.ldql = LOv; p.klogv = klog; p.ldkl = LOv;
    p.M = LOv; p.N = LOv; p.K = Hv; p.qi = -1; p.kj = -1; p.epi = EP_LOGIT;
    mgemm<<<dim3(2, 2, NITEM), 256, 0, stream>>>(p);
  }
  row_softmax<<<dim3(LOv, NITEM), 256, 0, stream>>>(logitF, awbB, LOv, LOv, sLL);
  { // attn2 = aw @ fusion -> selfA block 1
    MG p = {};
    p.A = awbB; p.sA = sLL; p.lda = LOv; p.aidx = IX_INST;
    p.B = fusTB; p.sB = (long long)Hv * LOv; p.ldb = LOv; p.bidx = IX_INST;
    p.Cb = selfA + Hv; p.sC = (long long)LOv * 4 * Hv; p.ldc = 4 * Hv; p.cidx = IX_INST;
    p.M = LOv; p.N = Hv; p.K = LOv; p.qi = -1; p.kj = -1; p.epi = EP_BF16;
    mgemm<<<dim3(8, 2, NITEM), 256, 0, stream>>>(p);
  }
  build_selfA23<<<dim3(LOv, NITEM), 256, 0, stream>>>(selfA);
  (void)hipMemsetAsync(Cacc, 0, CB64, stream);
  {
    MGS p = {selfA, (long long)LOv * 4 * Hv, 4 * Hv, wself, Cacc, LOv, 4};
    mgemm_sk<<<16 * NITEM * 4, 256, 0, stream>>>(p);
  }
  ep_selfmax<<<NITEM, 256, 0, stream>>>(Cacc, self_fc_b, optm, out);
}

// Round 5
// 2317.941 us; speedup vs baseline: 10.9912x; 1.2731x over previous
//
#include <hip/hip_runtime.h>
#include <math.h>

// Problem constants (fixed by the reference: H=1024, B=16, L=4, S=512)
#define Sv   512
#define Hv   1024
#define BSZ  16
#define NLB  4
#define NITEM 64          // BSZ*NLB
#define LOv  224          // >= max option len (512-300=212), multiple of 32
#define LDv  480          // >= max doc len (449), multiple of 32
#define NEGV (-1e30f)
#define VTHR (-1e20f)

typedef unsigned short u16;
typedef __attribute__((ext_vector_type(8))) short short8;   // 8 bf16 = 4 VGPRs (MFMA A/B frag)
using floatx4 = __attribute__((ext_vector_type(4))) float;

__device__ __forceinline__ u16 f2b(float x) {  // f32 -> bf16 RNE
  unsigned u = __float_as_uint(x);
  return (u16)((u + 0x7FFFu + ((u >> 16) & 1u)) >> 16);
}
__device__ __forceinline__ float b2f(u16 b) { return __uint_as_float(((unsigned)b) << 16); }

__device__ __forceinline__ float opt_view_f(const float* ll, const int* fp, int item, int t, int h) {
  int idx = fp[item] + t;
  return (idx < Sv) ? ll[((size_t)item * Sv + idx) * Hv + h] : 0.f;
}

// async global->LDS, 16B per lane; LDS dest = wave-uniform base + lane*16
__device__ __forceinline__ void gll16(const u16* g, u16* l) {
  __builtin_amdgcn_global_load_lds(
      (const __attribute__((address_space(1))) unsigned int*)(const void*)g,
      (__attribute__((address_space(3))) unsigned int*)(void*)l, 16, 0, 0);
}

// ======================= bf16 MFMA GEMM (attention-shaped) =======================
enum { EP_BF16 = 0, EP_LOGIT = 1, EP_AS = 2 };
enum { IX_INST = 0, IX_ITQ = 1, IX_ITK = 2 };

struct MG {
  const u16* A; long long sA; int lda; int aidx;
  const u16* B; long long sB; int ldb; int bidx;
  float* C; long long sC; int ldc; int cidx;
  u16* Cb;
  const unsigned char* qmask; int ldqm;
  const unsigned char* kmask; int ldkm;
  const float* qlogv; int ldql;
  const float* klogv; int ldkl;
  int M, N, K, qi, kj, epi, pm;   // pm: pairmode (z = pair*BSZ + b, pair=i*3+jj)
};

__global__ __launch_bounds__(256) void mgemm(MG p) {
  __shared__ u16 As[128][32];
  __shared__ u16 Bs[128][32];
  int inst = blockIdx.z;
  int itq, itk;
  if (p.pm) {
    int b = inst % BSZ, pair = inst / BSZ;
    int i = pair / 3, jj = pair % 3;
    int j = jj + (jj >= i ? 1 : 0);
    itq = b * NLB + i; itk = b * NLB + j;
  } else {
    itq = (p.qi >= 0) ? inst * NLB + p.qi : inst;
    itk = (p.kj >= 0) ? inst * NLB + p.kj : inst;
  }
  int ai = (p.aidx == IX_ITQ) ? itq : (p.aidx == IX_ITK ? itk : inst);
  int bi = (p.bidx == IX_ITQ) ? itq : (p.bidx == IX_ITK ? itk : inst);
  int ci = (p.cidx == IX_ITQ) ? itq : (p.cidx == IX_ITK ? itk : inst);
  const u16* Ab = p.A + (size_t)ai * p.sA;
  const u16* Bb = p.B + (size_t)bi * p.sB;
  int tid = threadIdx.x;
  int m0 = blockIdx.y * 128, n0 = blockIdx.x * 128;
  int wave = tid >> 6, lane = tid & 63;
  int wm = (wave >> 1) * 64, wn = (wave & 1) * 64;
  int col = lane & 15, quad = lane >> 4;
  int rl = lane >> 2, chunk = (lane & 3) * 8;
  floatx4 acc[4][4] = {};

  { // zero-init LDS so exec-masked boundary rows read as 0
    uint4 z4 = {0, 0, 0, 0};
    uint4* a4 = (uint4*)&As[0][0];
    uint4* b4 = (uint4*)&Bs[0][0];
    for (int z = tid; z < 512; z += 256) { a4[z] = z4; b4[z] = z4; }
  }
  __syncthreads();

  for (int k0 = 0; k0 < p.K; k0 += 32) {
    int rb = wave * 32;
    #pragma unroll
    for (int c = 0; c < 2; c++) {
      int r = rb + c * 16 + rl;
      if (m0 + r < p.M) gll16(Ab + (size_t)(m0 + r) * p.lda + k0 + chunk, &As[rb + c * 16][0]);
      if (n0 + r < p.N) gll16(Bb + (size_t)(n0 + r) * p.ldb + k0 + chunk, &Bs[rb + c * 16][0]);
    }
    __syncthreads();
    short8 a[4], b[4];
    #pragma unroll
    for (int mi = 0; mi < 4; mi++) a[mi] = *(const short8*)&As[wm + mi * 16 + col][quad * 8];
    #pragma unroll
    for (int ni = 0; ni < 4; ni++) b[ni] = *(const short8*)&Bs[wn + ni * 16 + col][quad * 8];
    #pragma unroll
    for (int mi = 0; mi < 4; mi++)
      #pragma unroll
      for (int ni = 0; ni < 4; ni++)
        acc[mi][ni] = __builtin_amdgcn_mfma_f32_16x16x32_bf16(a[mi], b[ni], acc[mi][ni], 0, 0, 0);
    __syncthreads();
  }

  int sblk = (inst / BSZ) % 3;  // EP_AS: which a_s slot
  #pragma unroll
  for (int mi = 0; mi < 4; mi++) {
    #pragma unroll
    for (int ni = 0; ni < 4; ni++) {
      int n = n0 + wn + ni * 16 + col;
      if (n >= p.N) continue;
      #pragma unroll
      for (int r = 0; r < 4; r++) {
        int m = m0 + wm + mi * 16 + quad * 4 + r;
        if (m >= p.M) continue;
        float v = acc[mi][ni][r];
        if (p.epi == EP_BF16) {
          p.Cb[(size_t)ci * p.sC + (size_t)m * p.ldc + n] = f2b(v);
        } else if (p.epi == EP_AS) {
          u16* base = p.Cb + (size_t)itq * p.sC + (size_t)m * p.ldc;
          float cur = b2f(base[n]);  // compA block 0 = opt_enc
          base[(size_t)(1 + 2 * sblk) * Hv + n] = f2b(cur * v);
          base[(size_t)(2 + 2 * sblk) * Hv + n] = f2b(cur - v);
        } else {  // EP_LOGIT
          bool qm = p.qmask[itq * p.ldqm + m] != 0;
          bool km = p.kmask[itk * p.ldkm + n] != 0;
          p.C[(size_t)ci * p.sC + (size_t)m * p.ldc + n] =
            (qm && km) ? (v + p.qlogv[(size_t)itq * p.ldql + m] + p.klogv[(size_t)itk * p.ldkl + n]) : NEGV;
        }
      }
    }
  }
}

// ======================= FC GEMM: A [64][224][K] bf16 x weights [1024][K] =======================
// Flat grid 1024 = 128 g x 8 nt, XCD-swizzled: id = g%8 + 8*(nt + 8*(g/8)) so all 8 n-tiles
// of one (inst, mtile) share an XCD (A-stripe served from that XCD's L2).
enum { FCE_TANH = 0, FCE_GATE = 1, FCE_SELFMAX = 2 };

struct MF {
  const u16* A; long long sA;   // lda = K
  const u16* B;                 // [1024][K]
  float* C; long long sC;       // f32 out [inst][224][1024]
  const float* bias;
  const float* ll; const int* fp; const float* Yv;   // gate
  const unsigned char* optm; float* outmax;          // selfmax
  int M, K, epi;
};

__global__ __launch_bounds__(256) void mgemm_fc(MF p) {
  __shared__ u16 As[128][32];
  __shared__ u16 Bs[128][32];
  int id = blockIdx.x;
  int low = id & 7, nt = (id >> 3) & 7, hi = id >> 6;
  int g = (hi << 3) | low;
  int inst = g >> 1, mt = g & 1;
  const u16* Ab = p.A + (size_t)inst * p.sA;
  int tid = threadIdx.x;
  int m0 = mt * 128, n0 = nt * 128;
  int wave = tid >> 6, lane = tid & 63;
  int wm = (wave >> 1) * 64, wn = (wave & 1) * 64;
  int col = lane & 15, quad = lane >> 4;
  int rl = lane >> 2, chunk = (lane & 3) * 8;
  floatx4 acc[4][4] = {};

  {
    uint4 z4 = {0, 0, 0, 0};
    uint4* a4 = (uint4*)&As[0][0];
    uint4* b4 = (uint4*)&Bs[0][0];
    for (int z = tid; z < 512; z += 256) { a4[z] = z4; b4[z] = z4; }
  }
  __syncthreads();

  for (int k0 = 0; k0 < p.K; k0 += 32) {
    int rb = wave * 32;
    #pragma unroll
    for (int c = 0; c < 2; c++) {
      int r = rb + c * 16 + rl;
      if (m0 + r < p.M) gll16(Ab + (size_t)(m0 + r) * p.K + k0 + chunk, &As[rb + c * 16][0]);
      gll16(p.B + (size_t)(n0 + r) * p.K + k0 + chunk, &Bs[rb + c * 16][0]);  // N=1024 always full
    }
    __syncthreads();
    short8 a[4], b[4];
    #pragma unroll
    for (int mi = 0; mi < 4; mi++) a[mi] = *(const short8*)&As[wm + mi * 16 + col][quad * 8];
    #pragma unroll
    for (int ni = 0; ni < 4; ni++) b[ni] = *(const short8*)&Bs[wn + ni * 16 + col][quad * 8];
    #pragma unroll
    for (int mi = 0; mi < 4; mi++)
      #pragma unroll
      for (int ni = 0; ni < 4; ni++)
        acc[mi][ni] = __builtin_amdgcn_mfma_f32_16x16x32_bf16(a[mi], b[ni], acc[mi][ni], 0, 0, 0);
    __syncthreads();
  }

  if (p.epi == FCE_SELFMAX) {
    // masked rows contribute 0 (safe: final max >= 0 since relu >= 0 and >=1 valid row/item)
    #pragma unroll
    for (int ni = 0; ni < 4; ni++) {
      int n = n0 + wn + ni * 16 + col;
      float bn = p.bias[n];
      float mloc = 0.f;
      #pragma unroll
      for (int mi = 0; mi < 4; mi++)
        #pragma unroll
        for (int r = 0; r < 4; r++) {
          int m = m0 + wm + mi * 16 + quad * 4 + r;
          float vv = fmaxf(acc[mi][ni][r] + bn, 0.f);
          if (m < p.M && p.optm[inst * LOv + m]) mloc = fmaxf(mloc, vv);
        }
      mloc = fmaxf(mloc, __shfl_xor(mloc, 16, 64));
      mloc = fmaxf(mloc, __shfl_xor(mloc, 32, 64));
      if (quad == 0)
        atomicMax((unsigned int*)(p.outmax + (size_t)inst * Hv + n), __float_as_uint(mloc));
    }
    return;
  }
  #pragma unroll
  for (int mi = 0; mi < 4; mi++) {
    #pragma unroll
    for (int ni = 0; ni < 4; ni++) {
      int n = n0 + wn + ni * 16 + col;
      #pragma unroll
      for (int r = 0; r < 4; r++) {
        int m = m0 + wm + mi * 16 + quad * 4 + r;
        if (m >= p.M) continue;
        float v = acc[mi][ni][r] + p.bias[n];
        float* cp = p.C + (size_t)inst * p.sC + (size_t)m * Hv + n;
        if (p.epi == FCE_TANH) {
          *cp = tanhf(v);
        } else {  // FCE_GATE
          float gg = 1.f / (1.f + __expf(-v));
          float xv = opt_view_f(p.ll, p.fp, inst, m, n);
          float yv = p.Yv[(size_t)inst * p.sC + (size_t)m * Hv + n];
          *cp = xv * gg + yv * (1.f - gg);
        }
      }
    }
  }
}

// ======================= helpers =======================
__global__ __launch_bounds__(256) void init_masks(const int* fp_in, const int* am, int* fp,
                                                  unsigned char* optm, unsigned char* docm) {
  int item = blockIdx.x;
  int f = fp_in[item];
  if (threadIdx.x == 0) fp[item] = f;
  for (int t = threadIdx.x; t < LDv; t += blockDim.x) {
    docm[item * LDv + t] = (t < f && t < Sv && am[item * Sv + t] > 0) ? 1 : 0;
    if (t < LOv) {
      int idx = f + t;
      optm[item * LOv + t] = (idx < Sv && am[item * Sv + idx] > 0) ? 1 : 0;
    }
  }
}

__global__ __launch_bounds__(256) void convf2b(const float* src, u16* dst, int n) {
  int i = blockIdx.x * 256 + threadIdx.x;
  int stride = gridDim.x * 256;
  for (; i < n; i += stride) dst[i] = f2b(src[i]);
}

// opt view -> compA block0 (ld 7H) + (opt*w3)
__global__ __launch_bounds__(256) void build_opt(const float* ll, const int* fp, const float* w3,
                                                 u16* compA0, u16* optw3B) {
  int t = blockIdx.x, item = blockIdx.y;
  int idx = fp[item] + t;
  bool v = idx < Sv;
  const float* src = ll + ((size_t)item * Sv + (v ? idx : 0)) * Hv;
  u16* d0 = compA0 + ((size_t)item * LOv + t) * (7 * Hv);
  u16* d1 = optw3B + ((size_t)item * LOv + t) * Hv;
  for (int h = threadIdx.x; h < Hv; h += 256) {
    float x = v ? src[h] : 0.f;
    d0[h] = f2b(x);
    d1[h] = f2b(x * w3[h]);
  }
}

__global__ __launch_bounds__(256) void build_doc(const float* ll, const unsigned char* docm, u16* docB) {
  int t = blockIdx.x, item = blockIdx.y;
  bool v = docm[item * LDv + t] != 0;
  const float* src = ll + ((size_t)item * Sv + (t < Sv ? t : 0)) * Hv;
  size_t o = ((size_t)item * LDv + t) * Hv;
  for (int h = threadIdx.x; h < Hv; h += 256) docB[o + h] = v ? f2b(src[h]) : (u16)0;
}

__global__ __launch_bounds__(256) void transpose_b(const float* src, long long sS,
                                                   const float* ll, const int* fp, const unsigned char* docm,
                                                   int mode, int Lt, u16* out) {
  __shared__ float tile[32][33];
  int t0 = blockIdx.x * 32, h0 = blockIdx.y * 32, item = blockIdx.z;
  int tx = threadIdx.x & 31, ty0 = threadIdx.x >> 5;
  for (int yy = ty0; yy < 32; yy += 8) {
    int t = t0 + yy, h = h0 + tx;
    float v = 0.f;
    if (t < Lt) {
      if (mode == 0)      v = src[(size_t)item * sS + (size_t)t * Hv + h];
      else if (mode == 1) { int idx = fp[item] + t; if (idx < Sv) v = ll[((size_t)item * Sv + idx) * Hv + h]; }
      else                { if (docm[item * LDv + t]) v = ll[((size_t)item * Sv + t) * Hv + h]; }
    }
    tile[yy][tx] = v;
  }
  __syncthreads();
  for (int yy = ty0; yy < 32; yy += 8) {
    int h = h0 + yy, t = t0 + tx;
    if (t < Lt) out[((size_t)item * Hv + h) * (size_t)Lt + t] = f2b(tile[tx][yy]);
  }
}

__global__ __launch_bounds__(256) void build_gateA(const float* ll, const int* fp, const float* corr, u16* gateA) {
  int t = blockIdx.x, item = blockIdx.y;
  int idx = fp[item] + t;
  bool v = idx < Sv;
  const float* src = ll + ((size_t)item * Sv + (v ? idx : 0)) * Hv;
  u16* dst = gateA + ((size_t)item * LOv + t) * (2 * Hv);
  const float* cr = corr + ((size_t)item * LOv + t) * Hv;
  for (int h = threadIdx.x; h < Hv; h += 256) {
    dst[h] = f2b(v ? src[h] : 0.f);
    dst[Hv + h] = f2b(cr[h]);
  }
}

__global__ __launch_bounds__(256) void conv_act(const float* src, const float* w3,
                                                u16* dst1, int ld1, u16* dstw3) {
  int t = blockIdx.x, item = blockIdx.y;
  const float* s = src + ((size_t)item * LOv + t) * Hv;
  u16* d1 = dst1 + ((size_t)item * LOv + t) * ld1;
  u16* d2 = dstw3 + ((size_t)item * LOv + t) * Hv;
  for (int h = threadIdx.x; h < Hv; h += 256) {
    float x = s[h];
    d1[h] = f2b(x);
    d2[h] = f2b(x * w3[h]);
  }
}

__global__ __launch_bounds__(256) void build_selfA23(u16* selfA) {
  int t = blockIdx.x, item = blockIdx.y;
  u16* row = selfA + ((size_t)item * LOv + t) * (4 * Hv);
  for (int h = threadIdx.x; h < Hv; h += 256) {
    float f = b2f(row[h]), a = b2f(row[Hv + h]);
    row[2 * Hv + h] = f2b(f * a);
    row[3 * Hv + h] = f2b(f - a);
  }
}

__global__ __launch_bounds__(256) void dot_rows(const float* src, long long sS,
                                                const float* ll, const int* fp, const unsigned char* docm,
                                                const float* w, float* outv, int ldo, int mode) {
  int t = blockIdx.x, item = blockIdx.y;
  int tid = threadIdx.x;
  float s = 0.f;
  for (int h = tid; h < Hv; h += 256) {
    float v;
    if (mode == 0)      v = src[(size_t)item * sS + (size_t)t * Hv + h];
    else if (mode == 1) v = opt_view_f(ll, fp, item, t, h);
    else                v = docm[item * LDv + t] ? ll[((size_t)item * Sv + t) * Hv + h] : 0.f;
    s += v * w[h];
  }
  __shared__ float red[4];
  for (int o = 32; o > 0; o >>= 1) s += __shfl_down(s, o, 64);
  int lane = tid & 63, wv = tid >> 6;
  if (lane == 0) red[wv] = s;
  __syncthreads();
  if (tid == 0) outv[(size_t)item * ldo + t] = red[0] + red[1] + red[2] + red[3];
}

__global__ __launch_bounds__(256) void row_softmax(const float* src, u16* dst, int Lk, int ldl, long long sL) {
  int m = blockIdx.x, inst = blockIdx.y;
  const float* row = src + (size_t)inst * sL + (size_t)m * ldl;
  u16* orow = dst + (size_t)inst * sL + (size_t)m * ldl;
  int tid = threadIdx.x;
  float mx = -INFINITY;
  for (int t = tid; t < Lk; t += 256) mx = fmaxf(mx, row[t]);
  __shared__ float sm[4]; __shared__ float ss[4];
  for (int o = 32; o > 0; o >>= 1) mx = fmaxf(mx, __shfl_down(mx, o, 64));
  int lane = tid & 63, wv = tid >> 6;
  if (lane == 0) sm[wv] = mx;
  __syncthreads();
  mx = fmaxf(fmaxf(sm[0], sm[1]), fmaxf(sm[2], sm[3]));
  float sum = 0.f;
  for (int t = tid; t < Lk; t += 256) sum += __expf(row[t] - mx);
  for (int o = 32; o > 0; o >>= 1) sum += __shfl_down(sum, o, 64);
  if (lane == 0) ss[wv] = sum;
  __syncthreads();
  sum = ss[0] + ss[1] + ss[2] + ss[3];
  float inv = 1.f / sum;
  for (int t = tid; t < Lk; t += 256) {
    float x = row[t];
    orow[t] = (x < VTHR) ? (u16)0 : f2b(__expf(x - mx) * inv);
  }
}

__global__ __launch_bounds__(256) void col_softmax(const float* src, u16* dst, int Mr, int ldl, long long sL) {
  int c = blockIdx.x, inst = blockIdx.y;
  const float* base = src + (size_t)inst * sL + c;
  u16* ob = dst + (size_t)inst * sL + c;
  int tid = threadIdx.x;
  float mx = -INFINITY;
  for (int t = tid; t < Mr; t += 256) mx = fmaxf(mx, base[(size_t)t * ldl]);
  __shared__ float sm[4]; __shared__ float ss[4];
  for (int o = 32; o > 0; o >>= 1) mx = fmaxf(mx, __shfl_down(mx, o, 64));
  int lane = tid & 63, wv = tid >> 6;
  if (lane == 0) sm[wv] = mx;
  __syncthreads();
  mx = fmaxf(fmaxf(sm[0], sm[1]), fmaxf(sm[2], sm[3]));
  float sum = 0.f;
  for (int t = tid; t < Mr; t += 256) sum += __expf(base[(size_t)t * ldl] - mx);
  for (int o = 32; o > 0; o >>= 1) sum += __shfl_down(sum, o, 64);
  if (lane == 0) ss[wv] = sum;
  __syncthreads();
  sum = ss[0] + ss[1] + ss[2] + ss[3];
  float inv = 1.f / sum;
  for (int t = tid; t < Mr; t += 256) {
    float x = base[(size_t)t * ldl];
    ob[(size_t)t * ldl] = (x < VTHR) ? (u16)0 : f2b(__expf(x - mx) * inv);
  }
}

// ======================= launch =======================
extern "C" void kernel_launch(void* const* d_in, const int* in_sizes, int n_in,
                              void* d_out, int out_size, void* d_ws, size_t ws_size,
                              hipStream_t stream) {
  const float* ll        = (const float*)d_in[0];
  const int* am          = (const int*)d_in[1];
  const int* fp_in       = (const int*)d_in[2];   // harness delivers int64 ref input as int32
  const float* attn_w1   = (const float*)d_in[4];
  const float* attn_w2   = (const float*)d_in[5];
  const float* attn_w3   = (const float*)d_in[6];
  const float* opt_w1    = (const float*)d_in[7];
  const float* opt_w2    = (const float*)d_in[8];
  const float* opt_w3    = (const float*)d_in[9];
  const float* self_w1   = (const float*)d_in[10];
  const float* self_w2   = (const float*)d_in[11];
  const float* self_w3   = (const float*)d_in[12];
  const float* attn_fc_w = (const float*)d_in[13];
  const float* attn_fc_b = (const float*)d_in[14];
  const float* comp_fc_w = (const float*)d_in[15];
  const float* comp_fc_b = (const float*)d_in[16];
  const float* gate_fc_w = (const float*)d_in[17];
  const float* gate_fc_b = (const float*)d_in[18];
  const float* self_fc_w = (const float*)d_in[19];
  const float* self_fc_b = (const float*)d_in[20];
  float* out = (float*)d_out;

  // ---- arena ----
  const size_t BIGF = (size_t)NITEM * LOv * Hv;          // 14,680,064
  float* optcorrF = (float*)d_ws;                        // later aliased as fusion
  float* optionF  = optcorrF + BIGF;
  float* logitF   = optionF + BIGF;
  float* qlog     = logitF + BIGF;
  float* klog     = qlog + (size_t)NITEM * LOv;
  float* optq     = klog + (size_t)NITEM * LDv;
  float* optk     = optq + (size_t)NITEM * LOv;
  u16* wcomp = (u16*)(optk + (size_t)NITEM * LOv);       // 1024*7168
  u16* wgate = wcomp + (size_t)Hv * 7 * Hv;
  u16* wattn = wgate + (size_t)Hv * 2 * Hv;
  u16* wself = wattn + (size_t)Hv * 3 * Hv;
  u16* kqB   = wself + (size_t)Hv * 4 * Hv;              // 64*224*480
  u16* awbB  = kqB + (size_t)NITEM * LOv * LDv;
  u16* cowB  = awbB + (size_t)NITEM * LOv * LDv;
  unsigned char* optm = (unsigned char*)(cowB + (size_t)NITEM * LOv * LOv);
  unsigned char* docm = optm + (size_t)NITEM * LOv;
  int* fp = (int*)(docm + (size_t)NITEM * LDv);
  u16* U = (u16*)(fp + NITEM + 32);
  const size_t E_OPT = (size_t)NITEM * LOv * Hv;
  const size_t E_DOC = (size_t)NITEM * LDv * Hv;
  // P1: compA [64][224][7168]; block0 doubles as opt_enc bf16
  u16* optw3B = U;
  u16* optTB  = U + E_OPT;
  u16* aw1B   = U + 2 * E_OPT;                           // 192*224*224
  u16* compA  = aw1B + (size_t)12 * BSZ * LOv * LOv;     // 64*224*7168
  // P2
  u16* gateA  = U;                                       // 64*224*2048
  // P3
  u16* docB   = U;
  u16* docTB  = U + E_DOC;
  u16* optw3C = U + 2 * E_DOC;
  u16* optTC  = optw3C + E_OPT;
  u16* attnA  = optTC + E_OPT;                           // 64*224*3072
  // P4
  u16* selfA  = U;                                       // 64*224*4096
  u16* fusw3  = U + (size_t)NITEM * LOv * 4 * Hv;
  u16* fusTB  = fusw3 + E_OPT;
  float* fusionF = optcorrF;

  const long long sOH = (long long)LOv * Hv;
  const long long sLL = (long long)LOv * LOv;
  const long long sLD = (long long)LOv * LDv;
  const long long sC7 = (long long)LOv * 7 * Hv;

  (void)hipMemsetAsync(d_out, 0, (size_t)NITEM * Hv * sizeof(float), stream);
  init_masks<<<NITEM, 256, 0, stream>>>(fp_in, am, fp, optm, docm);
  convf2b<<<1024, 256, 0, stream>>>(comp_fc_w, wcomp, Hv * 7 * Hv);
  convf2b<<<1024, 256, 0, stream>>>(gate_fc_w, wgate, Hv * 2 * Hv);
  convf2b<<<1024, 256, 0, stream>>>(attn_fc_w, wattn, Hv * 3 * Hv);
  convf2b<<<1024, 256, 0, stream>>>(self_fc_w, wself, Hv * 4 * Hv);
  build_opt<<<dim3(LOv, NITEM), 256, 0, stream>>>(ll, fp, opt_w3, compA, optw3B);
  transpose_b<<<dim3(LOv / 32, Hv / 32, NITEM), 256, 0, stream>>>(nullptr, 0, ll, fp, docm, 1, LOv, optTB);
  dot_rows<<<dim3(LOv, NITEM), 256, 0, stream>>>(nullptr, 0, ll, fp, docm, opt_w1, optq, LOv, 1);
  dot_rows<<<dim3(LOv, NITEM), 256, 0, stream>>>(nullptr, 0, ll, fp, docm, opt_w2, optk, LOv, 1);

  // ========== Phase 1: all 12 pairwise logits -> softmax -> a_s (fused into compA) ==========
  { // logits for all (i,j) pairs: z = pair*16 + b ; B = compA block0 (opt_enc)
    MG p = {};
    p.A = optw3B; p.sA = sOH; p.lda = Hv; p.aidx = IX_ITQ;
    p.B = compA;  p.sB = sC7; p.ldb = 7 * Hv; p.bidx = IX_ITK;
    p.C = logitF; p.sC = sLL; p.ldc = LOv; p.cidx = IX_INST;
    p.qmask = optm; p.ldqm = LOv; p.kmask = optm; p.ldkm = LOv;
    p.qlogv = optq; p.ldql = LOv; p.klogv = optk; p.ldkl = LOv;
    p.M = LOv; p.N = LOv; p.K = Hv; p.epi = EP_LOGIT; p.pm = 1;
    mgemm<<<dim3(2, 2, 12 * BSZ), 256, 0, stream>>>(p);
  }
  row_softmax<<<dim3(LOv, 12 * BSZ), 256, 0, stream>>>(logitF, aw1B, LOv, LOv, sLL);
  { // a_s = aw @ opt_enc[j]; epilogue writes cur*a, cur-a into compA blocks (1+2s, 2+2s)
    MG p = {};
    p.A = aw1B; p.sA = sLL; p.lda = LOv; p.aidx = IX_INST;
    p.B = optTB; p.sB = (long long)Hv * LOv; p.ldb = LOv; p.bidx = IX_ITK;
    p.Cb = compA; p.sC = sC7; p.ldc = 7 * Hv; p.cidx = IX_ITQ;
    p.M = LOv; p.N = Hv; p.K = LOv; p.epi = EP_AS; p.pm = 1;
    mgemm<<<dim3(8, 2, 12 * BSZ), 256, 0, stream>>>(p);
  }
  { // opt_corr = tanh(compA @ comp_w^T + b), all 64 insts in one launch
    MF p = {};
    p.A = compA; p.sA = sC7; p.B = wcomp;
    p.C = optcorrF; p.sC = sOH; p.bias = comp_fc_b;
    p.M = LOv; p.K = 7 * Hv; p.epi = FCE_TANH;
    mgemm_fc<<<1024, 256, 0, stream>>>(p);
  }

  // ========== Phase 2: gate FC + blend ==========
  build_gateA<<<dim3(LOv, NITEM), 256, 0, stream>>>(ll, fp, optcorrF, gateA);
  {
    MF p = {};
    p.A = gateA; p.sA = (long long)LOv * 2 * Hv; p.B = wgate;
    p.C = optionF; p.sC = sOH; p.bias = gate_fc_b;
    p.ll = ll; p.fp = fp; p.Yv = optcorrF;
    p.M = LOv; p.K = 2 * Hv; p.epi = FCE_GATE;
    mgemm_fc<<<1024, 256, 0, stream>>>(p);
  }

  // ========== Phase 3: doc attention + co-attention + attn FC ==========
  build_doc<<<dim3(LDv, NITEM), 256, 0, stream>>>(ll, docm, docB);
  transpose_b<<<dim3(LDv / 32, Hv / 32, NITEM), 256, 0, stream>>>(nullptr, 0, ll, fp, docm, 2, LDv, docTB);
  conv_act<<<dim3(LOv, NITEM), 256, 0, stream>>>(optionF, attn_w3, attnA, 3 * Hv, optw3C);
  transpose_b<<<dim3(LOv / 32, Hv / 32, NITEM), 256, 0, stream>>>(optionF, sOH, ll, fp, docm, 0, LOv, optTC);
  dot_rows<<<dim3(LOv, NITEM), 256, 0, stream>>>(optionF, sOH, ll, fp, docm, attn_w1, qlog, LOv, 0);
  dot_rows<<<dim3(LDv, NITEM), 256, 0, stream>>>(nullptr, 0, ll, fp, docm, attn_w2, klog, LDv, 2);
  { // logit [224,480]
    MG p = {};
    p.A = optw3C; p.sA = sOH; p.lda = Hv; p.aidx = IX_INST;
    p.B = docB; p.sB = (long long)LDv * Hv; p.ldb = Hv; p.bidx = IX_INST;
    p.C = logitF; p.sC = sLD; p.ldc = LDv; p.cidx = IX_INST;
    p.qmask = optm; p.ldqm = LOv; p.kmask = docm; p.ldkm = LDv;
    p.qlogv = qlog; p.ldql = LOv; p.klogv = klog; p.ldkl = LDv;
    p.M = LOv; p.N = LDv; p.K = Hv; p.qi = -1; p.kj = -1; p.epi = EP_LOGIT;
    mgemm<<<dim3(4, 2, NITEM), 256, 0, stream>>>(p);
  }
  row_softmax<<<dim3(LOv, NITEM), 256, 0, stream>>>(logitF, awbB, LDv, LDv, sLD);
  col_softmax<<<dim3(LDv, NITEM), 256, 0, stream>>>(logitF, kqB, LOv, LDv, sLD);
  { // attn = aw @ doc -> attnA block 1
    MG p = {};
    p.A = awbB; p.sA = sLD; p.lda = LDv; p.aidx = IX_INST;
    p.B = docTB; p.sB = (long long)Hv * LDv; p.ldb = LDv; p.bidx = IX_INST;
    p.Cb = attnA + Hv; p.sC = (long long)LOv * 3 * Hv; p.ldc = 3 * Hv; p.cidx = IX_INST;
    p.M = LOv; p.N = Hv; p.K = LDv; p.qi = -1; p.kj = -1; p.epi = EP_BF16;
    mgemm<<<dim3(8, 2, NITEM), 256, 0, stream>>>(p);
  }
  { // co_w = aw @ kq^T
    MG p = {};
    p.A = awbB; p.sA = sLD; p.lda = LDv; p.aidx = IX_INST;
    p.B = kqB; p.sB = sLD; p.ldb = LDv; p.bidx = IX_INST;
    p.Cb = cowB; p.sC = sLL; p.ldc = LOv; p.cidx = IX_INST;
    p.M = LOv; p.N = LOv; p.K = LDv; p.qi = -1; p.kj = -1; p.epi = EP_BF16;
    mgemm<<<dim3(2, 2, NITEM), 256, 0, stream>>>(p);
  }
  { // coattn = co_w @ option -> attnA block 2
    MG p = {};
    p.A = cowB; p.sA = sLL; p.lda = LOv; p.aidx = IX_INST;
    p.B = optTC; p.sB = (long long)Hv * LOv; p.ldb = LOv; p.bidx = IX_INST;
    p.Cb = attnA + 2 * Hv; p.sC = (long long)LOv * 3 * Hv; p.ldc = 3 * Hv; p.cidx = IX_INST;
    p.M = LOv; p.N = Hv; p.K = LOv; p.qi = -1; p.kj = -1; p.epi = EP_BF16;
    mgemm<<<dim3(8, 2, NITEM), 256, 0, stream>>>(p);
  }
  { // fusion = tanh(attnA @ attn_w^T + b)
    MF p = {};
    p.A = attnA; p.sA = (long long)LOv * 3 * Hv; p.B = wattn;
    p.C = fusionF; p.sC = sOH; p.bias = attn_fc_b;
    p.M = LOv; p.K = 3 * Hv; p.epi = FCE_TANH;
    mgemm_fc<<<1024, 256, 0, stream>>>(p);
  }

  // ========== Phase 4: self attention + self FC + masked max ==========
  conv_act<<<dim3(LOv, NITEM), 256, 0, stream>>>(fusionF, self_w3, selfA, 4 * Hv, fusw3);
  transpose_b<<<dim3(LOv / 32, Hv / 32, NITEM), 256, 0, stream>>>(fusionF, sOH, ll, fp, docm, 0, LOv, fusTB);
  dot_rows<<<dim3(LOv, NITEM), 256, 0, stream>>>(fusionF, sOH, ll, fp, docm, self_w1, qlog, LOv, 0);
  dot_rows<<<dim3(LOv, NITEM), 256, 0, stream>>>(fusionF, sOH, ll, fp, docm, self_w2, klog, LOv, 0);
  { // self logit (B = selfA block 0 = fusion bf16, ldb=4096)
    MG p = {};
    p.A = fusw3; p.sA = sOH; p.lda = Hv; p.aidx = IX_INST;
    p.B = selfA; p.sB = (long long)LOv * 4 * Hv; p.ldb = 4 * Hv; p.bidx = IX_INST;
    p.C = logitF; p.sC = sLL; p.ldc = LOv; p.cidx = IX_INST;
    p.qmask = optm; p.ldqm = LOv; p.kmask = optm; p.ldkm = LOv;
    p.qlogv = qlog; p.ldql = LOv; p.klogv = klog; p.ldkl = LOv;
    p.M = LOv; p.N = LOv; p.K = Hv; p.qi = -1; p.kj = -1; p.epi = EP_LOGIT;
    mgemm<<<dim3(2, 2, NITEM), 256, 0, stream>>>(p);
  }
  row_softmax<<<dim3(LOv, NITEM), 256, 0, stream>>>(logitF, awbB, LOv, LOv, sLL);
  { // attn2 = aw @ fusion -> selfA block 1
    MG p = {};
    p.A = awbB; p.sA = sLL; p.lda = LOv; p.aidx = IX_INST;
    p.B = fusTB; p.sB = (long long)Hv * LOv; p.ldb = LOv; p.bidx = IX_INST;
    p.Cb = selfA + Hv; p.sC = (long long)LOv * 4 * Hv; p.ldc = 4 * Hv; p.cidx = IX_INST;
    p.M = LOv; p.N = Hv; p.K = LOv; p.qi = -1; p.kj = -1; p.epi = EP_BF16;
    mgemm<<<dim3(8, 2, NITEM), 256, 0, stream>>>(p);
  }
  build_selfA23<<<dim3(LOv, NITEM), 256, 0, stream>>>(selfA);
  { // out[item,h] = max over valid t of relu(selfA @ self_w^T + b)
    MF p = {};
    p.A = selfA; p.sA = (long long)LOv * 4 * Hv; p.B = wself;
    p.bias = self_fc_b; p.optm = optm; p.outmax = out;
    p.M = LOv; p.K = 4 * Hv; p.epi = FCE_SELFMAX;
    mgemm_fc<<<1024, 256, 0, stream>>>(p);
  }
}

// Round 6
// 2297.927 us; speedup vs baseline: 11.0870x; 1.0087x over previous
//
#include <hip/hip_runtime.h>
#include <math.h>

// Problem constants (fixed by the reference: H=1024, B=16, L=4, S=512)
#define Sv   512
#define Hv   1024
#define BSZ  16
#define NLB  4
#define NITEM 64          // BSZ*NLB
#define LOv  224          // >= max option len (512-300=212), multiple of 32
#define LDv  480          // >= max doc len (449), multiple of 32
#define NEGV (-1e30f)
#define VTHR (-1e20f)

typedef unsigned short u16;
typedef __attribute__((ext_vector_type(8))) short short8;   // 8 bf16 = 4 VGPRs (MFMA A/B frag)
using floatx4 = __attribute__((ext_vector_type(4))) float;

__device__ __forceinline__ u16 f2b(float x) {  // f32 -> bf16 RNE
  unsigned u = __float_as_uint(x);
  return (u16)((u + 0x7FFFu + ((u >> 16) & 1u)) >> 16);
}
__device__ __forceinline__ float b2f(u16 b) { return __uint_as_float(((unsigned)b) << 16); }

__device__ __forceinline__ float opt_view_f(const float* ll, const int* fp, int item, int t, int h) {
  int idx = fp[item] + t;
  return (idx < Sv) ? ll[((size_t)item * Sv + idx) * Hv + h] : 0.f;
}

// async global->LDS, 16B per lane; LDS dest = wave-uniform base + lane*16
__device__ __forceinline__ void gll16(const u16* g, u16* l) {
  __builtin_amdgcn_global_load_lds(
      (const __attribute__((address_space(1))) unsigned int*)(const void*)g,
      (__attribute__((address_space(3))) unsigned int*)(void*)l, 16, 0, 0);
}

// LDS chunk swizzle: row r's 16B chunk q lives at slot q ^ sw(r).
// Read bank group = (r%2)*16 + ((q^sw(r))*4): 16 lanes -> 8 groups = 2-way (free, m136).
__device__ __forceinline__ int swz(int r) { return (r >> 1) & 3; }

// ======================= bf16 MFMA GEMM (attention-shaped) =======================
enum { EP_BF16 = 0, EP_LOGIT = 1, EP_AS = 2 };
enum { IX_INST = 0, IX_ITQ = 1, IX_ITK = 2 };

struct MG {
  const u16* A; long long sA; int lda; int aidx;
  const u16* B; long long sB; int ldb; int bidx;
  float* C; long long sC; int ldc; int cidx;
  u16* Cb;
  const unsigned char* qmask; int ldqm;
  const unsigned char* kmask; int ldkm;
  const float* qlogv; int ldql;
  const float* klogv; int ldkl;
  int M, N, K, qi, kj, epi, pm;   // pm: pairmode (z = pair*BSZ + b, pair=i*3+jj)
};

__global__ __launch_bounds__(256) void mgemm(MG p) {
  __shared__ u16 As[128][32];
  __shared__ u16 Bs[128][32];
  int inst = blockIdx.z;
  int itq, itk;
  if (p.pm) {
    int b = inst % BSZ, pair = inst / BSZ;
    int i = pair / 3, jj = pair % 3;
    int j = jj + (jj >= i ? 1 : 0);
    itq = b * NLB + i; itk = b * NLB + j;
  } else {
    itq = (p.qi >= 0) ? inst * NLB + p.qi : inst;
    itk = (p.kj >= 0) ? inst * NLB + p.kj : inst;
  }
  int ai = (p.aidx == IX_ITQ) ? itq : (p.aidx == IX_ITK ? itk : inst);
  int bi = (p.bidx == IX_ITQ) ? itq : (p.bidx == IX_ITK ? itk : inst);
  int ci = (p.cidx == IX_ITQ) ? itq : (p.cidx == IX_ITK ? itk : inst);
  const u16* Ab = p.A + (size_t)ai * p.sA;
  const u16* Bb = p.B + (size_t)bi * p.sB;
  int tid = threadIdx.x;
  int m0 = blockIdx.y * 128, n0 = blockIdx.x * 128;
  int wave = tid >> 6, lane = tid & 63;
  int wm = (wave >> 1) * 64, wn = (wave & 1) * 64;
  int col = lane & 15, quad = lane >> 4;
  int rl = lane >> 2, cslot = lane & 3;
  floatx4 acc[4][4] = {};

  { // zero-init LDS so exec-masked boundary rows read as 0
    uint4 z4 = {0, 0, 0, 0};
    uint4* a4 = (uint4*)&As[0][0];
    uint4* b4 = (uint4*)&Bs[0][0];
    for (int z = tid; z < 512; z += 256) { a4[z] = z4; b4[z] = z4; }
  }
  __syncthreads();

  for (int k0 = 0; k0 < p.K; k0 += 32) {
    int rb = wave * 32;
    #pragma unroll
    for (int c = 0; c < 2; c++) {
      int r = rb + c * 16 + rl;
      int gk = k0 + ((cslot ^ swz(r)) * 8);   // swizzled source chunk
      if (m0 + r < p.M) gll16(Ab + (size_t)(m0 + r) * p.lda + gk, &As[rb + c * 16][0]);
      if (n0 + r < p.N) gll16(Bb + (size_t)(n0 + r) * p.ldb + gk, &Bs[rb + c * 16][0]);
    }
    __syncthreads();
    short8 a[4], b[4];
    #pragma unroll
    for (int mi = 0; mi < 4; mi++) {
      int r = wm + mi * 16 + col;
      a[mi] = *(const short8*)&As[r][(quad ^ swz(r)) * 8];
    }
    #pragma unroll
    for (int ni = 0; ni < 4; ni++) {
      int r = wn + ni * 16 + col;
      b[ni] = *(const short8*)&Bs[r][(quad ^ swz(r)) * 8];
    }
    #pragma unroll
    for (int mi = 0; mi < 4; mi++)
      #pragma unroll
      for (int ni = 0; ni < 4; ni++)
        acc[mi][ni] = __builtin_amdgcn_mfma_f32_16x16x32_bf16(a[mi], b[ni], acc[mi][ni], 0, 0, 0);
    __syncthreads();
  }

  int sblk = (inst / BSZ) % 3;  // EP_AS: which a_s slot
  #pragma unroll
  for (int mi = 0; mi < 4; mi++) {
    #pragma unroll
    for (int ni = 0; ni < 4; ni++) {
      int n = n0 + wn + ni * 16 + col;
      if (n >= p.N) continue;
      #pragma unroll
      for (int r = 0; r < 4; r++) {
        int m = m0 + wm + mi * 16 + quad * 4 + r;
        if (m >= p.M) continue;
        float v = acc[mi][ni][r];
        if (p.epi == EP_BF16) {
          p.Cb[(size_t)ci * p.sC + (size_t)m * p.ldc + n] = f2b(v);
        } else if (p.epi == EP_AS) {
          u16* base = p.Cb + (size_t)itq * p.sC + (size_t)m * p.ldc;
          float cur = b2f(base[n]);  // compA block 0 = opt_enc
          base[(size_t)(1 + 2 * sblk) * Hv + n] = f2b(cur * v);
          base[(size_t)(2 + 2 * sblk) * Hv + n] = f2b(cur - v);
        } else {  // EP_LOGIT
          bool qm = p.qmask[itq * p.ldqm + m] != 0;
          bool km = p.kmask[itk * p.ldkm + n] != 0;
          p.C[(size_t)ci * p.sC + (size_t)m * p.ldc + n] =
            (qm && km) ? (v + p.qlogv[(size_t)itq * p.ldql + m] + p.klogv[(size_t)itk * p.ldkl + n]) : NEGV;
        }
      }
    }
  }
}

// ======================= FC GEMM: A [64][224][K] bf16 x weights [1024][K] =======================
// Flat grid 1024 = 128 g x 8 nt, XCD-swizzled: id = g%8 + 8*(nt + 8*(g/8)) so all 8 n-tiles
// of one (inst, mtile) share an XCD (A-stripe served from that XCD's L2).
enum { FCE_TANH = 0, FCE_GATE = 1, FCE_SELFMAX = 2 };

struct MF {
  const u16* A; long long sA;   // lda = K
  const u16* B;                 // [1024][K]
  float* C; long long sC;       // f32 out [inst][224][1024]
  const float* bias;
  const float* ll; const int* fp; const float* Yv;   // gate
  const unsigned char* optm; float* outmax;          // selfmax
  int M, K, epi;
};

__global__ __launch_bounds__(256) void mgemm_fc(MF p) {
  __shared__ u16 As[128][32];
  __shared__ u16 Bs[128][32];
  int id = blockIdx.x;
  int low = id & 7, nt = (id >> 3) & 7, hi = id >> 6;
  int g = (hi << 3) | low;
  int inst = g >> 1, mt = g & 1;
  const u16* Ab = p.A + (size_t)inst * p.sA;
  int tid = threadIdx.x;
  int m0 = mt * 128, n0 = nt * 128;
  int wave = tid >> 6, lane = tid & 63;
  int wm = (wave >> 1) * 64, wn = (wave & 1) * 64;
  int col = lane & 15, quad = lane >> 4;
  int rl = lane >> 2, cslot = lane & 3;
  floatx4 acc[4][4] = {};

  {
    uint4 z4 = {0, 0, 0, 0};
    uint4* a4 = (uint4*)&As[0][0];
    uint4* b4 = (uint4*)&Bs[0][0];
    for (int z = tid; z < 512; z += 256) { a4[z] = z4; b4[z] = z4; }
  }
  __syncthreads();

  for (int k0 = 0; k0 < p.K; k0 += 32) {
    int rb = wave * 32;
    #pragma unroll
    for (int c = 0; c < 2; c++) {
      int r = rb + c * 16 + rl;
      int gk = k0 + ((cslot ^ swz(r)) * 8);
      if (m0 + r < p.M) gll16(Ab + (size_t)(m0 + r) * p.K + gk, &As[rb + c * 16][0]);
      gll16(p.B + (size_t)(n0 + r) * p.K + gk, &Bs[rb + c * 16][0]);  // N=1024 always full
    }
    __syncthreads();
    short8 a[4], b[4];
    #pragma unroll
    for (int mi = 0; mi < 4; mi++) {
      int r = wm + mi * 16 + col;
      a[mi] = *(const short8*)&As[r][(quad ^ swz(r)) * 8];
    }
    #pragma unroll
    for (int ni = 0; ni < 4; ni++) {
      int r = wn + ni * 16 + col;
      b[ni] = *(const short8*)&Bs[r][(quad ^ swz(r)) * 8];
    }
    #pragma unroll
    for (int mi = 0; mi < 4; mi++)
      #pragma unroll
      for (int ni = 0; ni < 4; ni++)
        acc[mi][ni] = __builtin_amdgcn_mfma_f32_16x16x32_bf16(a[mi], b[ni], acc[mi][ni], 0, 0, 0);
    __syncthreads();
  }

  if (p.epi == FCE_SELFMAX) {
    // masked rows contribute 0 (safe: final max >= 0 since relu >= 0 and >=1 valid row/item)
    #pragma unroll
    for (int ni = 0; ni < 4; ni++) {
      int n = n0 + wn + ni * 16 + col;
      float bn = p.bias[n];
      float mloc = 0.f;
      #pragma unroll
      for (int mi = 0; mi < 4; mi++)
        #pragma unroll
        for (int r = 0; r < 4; r++) {
          int m = m0 + wm + mi * 16 + quad * 4 + r;
          float vv = fmaxf(acc[mi][ni][r] + bn, 0.f);
          if (m < p.M && p.optm[inst * LOv + m]) mloc = fmaxf(mloc, vv);
        }
      mloc = fmaxf(mloc, __shfl_xor(mloc, 16, 64));
      mloc = fmaxf(mloc, __shfl_xor(mloc, 32, 64));
      if (quad == 0)
        atomicMax((unsigned int*)(p.outmax + (size_t)inst * Hv + n), __float_as_uint(mloc));
    }
    return;
  }
  #pragma unroll
  for (int mi = 0; mi < 4; mi++) {
    #pragma unroll
    for (int ni = 0; ni < 4; ni++) {
      int n = n0 + wn + ni * 16 + col;
      #pragma unroll
      for (int r = 0; r < 4; r++) {
        int m = m0 + wm + mi * 16 + quad * 4 + r;
        if (m >= p.M) continue;
        float v = acc[mi][ni][r] + p.bias[n];
        float* cp = p.C + (size_t)inst * p.sC + (size_t)m * Hv + n;
        if (p.epi == FCE_TANH) {
          *cp = tanhf(v);
        } else {  // FCE_GATE
          float gg = 1.f / (1.f + __expf(-v));
          float xv = opt_view_f(p.ll, p.fp, inst, m, n);
          float yv = p.Yv[(size_t)inst * p.sC + (size_t)m * Hv + n];
          *cp = xv * gg + yv * (1.f - gg);
        }
      }
    }
  }
}

// ======================= helpers =======================
__global__ __launch_bounds__(256) void init_masks(const int* fp_in, const int* am, int* fp,
                                                  unsigned char* optm, unsigned char* docm) {
  int item = blockIdx.x;
  int f = fp_in[item];
  if (threadIdx.x == 0) fp[item] = f;
  for (int t = threadIdx.x; t < LDv; t += blockDim.x) {
    docm[item * LDv + t] = (t < f && t < Sv && am[item * Sv + t] > 0) ? 1 : 0;
    if (t < LOv) {
      int idx = f + t;
      optm[item * LOv + t] = (idx < Sv && am[item * Sv + idx] > 0) ? 1 : 0;
    }
  }
}

__global__ __launch_bounds__(256) void convf2b(const float* src, u16* dst, int n) {
  int i = blockIdx.x * 256 + threadIdx.x;
  int stride = gridDim.x * 256;
  for (; i < n; i += stride) dst[i] = f2b(src[i]);
}

// opt view -> compA block0 (ld 7H) + (opt*w3)
__global__ __launch_bounds__(256) void build_opt(const float* ll, const int* fp, const float* w3,
                                                 u16* compA0, u16* optw3B) {
  int t = blockIdx.x, item = blockIdx.y;
  int idx = fp[item] + t;
  bool v = idx < Sv;
  const float* src = ll + ((size_t)item * Sv + (v ? idx : 0)) * Hv;
  u16* d0 = compA0 + ((size_t)item * LOv + t) * (7 * Hv);
  u16* d1 = optw3B + ((size_t)item * LOv + t) * Hv;
  for (int h = threadIdx.x; h < Hv; h += 256) {
    float x = v ? src[h] : 0.f;
    d0[h] = f2b(x);
    d1[h] = f2b(x * w3[h]);
  }
}

__global__ __launch_bounds__(256) void build_doc(const float* ll, const unsigned char* docm, u16* docB) {
  int t = blockIdx.x, item = blockIdx.y;
  bool v = docm[item * LDv + t] != 0;
  const float* src = ll + ((size_t)item * Sv + (t < Sv ? t : 0)) * Hv;
  size_t o = ((size_t)item * LDv + t) * Hv;
  for (int h = threadIdx.x; h < Hv; h += 256) docB[o + h] = v ? f2b(src[h]) : (u16)0;
}

__global__ __launch_bounds__(256) void transpose_b(const float* src, long long sS,
                                                   const float* ll, const int* fp, const unsigned char* docm,
                                                   int mode, int Lt, u16* out) {
  __shared__ float tile[32][33];
  int t0 = blockIdx.x * 32, h0 = blockIdx.y * 32, item = blockIdx.z;
  int tx = threadIdx.x & 31, ty0 = threadIdx.x >> 5;
  for (int yy = ty0; yy < 32; yy += 8) {
    int t = t0 + yy, h = h0 + tx;
    float v = 0.f;
    if (t < Lt) {
      if (mode == 0)      v = src[(size_t)item * sS + (size_t)t * Hv + h];
      else if (mode == 1) { int idx = fp[item] + t; if (idx < Sv) v = ll[((size_t)item * Sv + idx) * Hv + h]; }
      else                { if (docm[item * LDv + t]) v = ll[((size_t)item * Sv + t) * Hv + h]; }
    }
    tile[yy][tx] = v;
  }
  __syncthreads();
  for (int yy = ty0; yy < 32; yy += 8) {
    int h = h0 + yy, t = t0 + tx;
    if (t < Lt) out[((size_t)item * Hv + h) * (size_t)Lt + t] = f2b(tile[tx][yy]);
  }
}

__global__ __launch_bounds__(256) void build_gateA(const float* ll, const int* fp, const float* corr, u16* gateA) {
  int t = blockIdx.x, item = blockIdx.y;
  int idx = fp[item] + t;
  bool v = idx < Sv;
  const float* src = ll + ((size_t)item * Sv + (v ? idx : 0)) * Hv;
  u16* dst = gateA + ((size_t)item * LOv + t) * (2 * Hv);
  const float* cr = corr + ((size_t)item * LOv + t) * Hv;
  for (int h = threadIdx.x; h < Hv; h += 256) {
    dst[h] = f2b(v ? src[h] : 0.f);
    dst[Hv + h] = f2b(cr[h]);
  }
}

__global__ __launch_bounds__(256) void conv_act(const float* src, const float* w3,
                                                u16* dst1, int ld1, u16* dstw3) {
  int t = blockIdx.x, item = blockIdx.y;
  const float* s = src + ((size_t)item * LOv + t) * Hv;
  u16* d1 = dst1 + ((size_t)item * LOv + t) * ld1;
  u16* d2 = dstw3 + ((size_t)item * LOv + t) * Hv;
  for (int h = threadIdx.x; h < Hv; h += 256) {
    float x = s[h];
    d1[h] = f2b(x);
    d2[h] = f2b(x * w3[h]);
  }
}

__global__ __launch_bounds__(256) void build_selfA23(u16* selfA) {
  int t = blockIdx.x, item = blockIdx.y;
  u16* row = selfA + ((size_t)item * LOv + t) * (4 * Hv);
  for (int h = threadIdx.x; h < Hv; h += 256) {
    float f = b2f(row[h]), a = b2f(row[Hv + h]);
    row[2 * Hv + h] = f2b(f * a);
    row[3 * Hv + h] = f2b(f - a);
  }
}

__global__ __launch_bounds__(256) void dot_rows(const float* src, long long sS,
                                                const float* ll, const int* fp, const unsigned char* docm,
                                                const float* w, float* outv, int ldo, int mode) {
  int t = blockIdx.x, item = blockIdx.y;
  int tid = threadIdx.x;
  float s = 0.f;
  for (int h = tid; h < Hv; h += 256) {
    float v;
    if (mode == 0)      v = src[(size_t)item * sS + (size_t)t * Hv + h];
    else if (mode == 1) v = opt_view_f(ll, fp, item, t, h);
    else                v = docm[item * LDv + t] ? ll[((size_t)item * Sv + t) * Hv + h] : 0.f;
    s += v * w[h];
  }
  __shared__ float red[4];
  for (int o = 32; o > 0; o >>= 1) s += __shfl_down(s, o, 64);
  int lane = tid & 63, wv = tid >> 6;
  if (lane == 0) red[wv] = s;
  __syncthreads();
  if (tid == 0) outv[(size_t)item * ldo + t] = red[0] + red[1] + red[2] + red[3];
}

__global__ __launch_bounds__(256) void row_softmax(const float* src, u16* dst, int Lk, int ldl, long long sL) {
  int m = blockIdx.x, inst = blockIdx.y;
  const float* row = src + (size_t)inst * sL + (size_t)m * ldl;
  u16* orow = dst + (size_t)inst * sL + (size_t)m * ldl;
  int tid = threadIdx.x;
  float mx = -INFINITY;
  for (int t = tid; t < Lk; t += 256) mx = fmaxf(mx, row[t]);
  __shared__ float sm[4]; __shared__ float ss[4];
  for (int o = 32; o > 0; o >>= 1) mx = fmaxf(mx, __shfl_down(mx, o, 64));
  int lane = tid & 63, wv = tid >> 6;
  if (lane == 0) sm[wv] = mx;
  __syncthreads();
  mx = fmaxf(fmaxf(sm[0], sm[1]), fmaxf(sm[2], sm[3]));
  float sum = 0.f;
  for (int t = tid; t < Lk; t += 256) sum += __expf(row[t] - mx);
  for (int o = 32; o > 0; o >>= 1) sum += __shfl_down(sum, o, 64);
  if (lane == 0) ss[wv] = sum;
  __syncthreads();
  sum = ss[0] + ss[1] + ss[2] + ss[3];
  float inv = 1.f / sum;
  for (int t = tid; t < Lk; t += 256) {
    float x = row[t];
    orow[t] = (x < VTHR) ? (u16)0 : f2b(__expf(x - mx) * inv);
  }
}

__global__ __launch_bounds__(256) void col_softmax(const float* src, u16* dst, int Mr, int ldl, long long sL) {
  int c = blockIdx.x, inst = blockIdx.y;
  const float* base = src + (size_t)inst * sL + c;
  u16* ob = dst + (size_t)inst * sL + c;
  int tid = threadIdx.x;
  float mx = -INFINITY;
  for (int t = tid; t < Mr; t += 256) mx = fmaxf(mx, base[(size_t)t * ldl]);
  __shared__ float sm[4]; __shared__ float ss[4];
  for (int o = 32; o > 0; o >>= 1) mx = fmaxf(mx, __shfl_down(mx, o, 64));
  int lane = tid & 63, wv = tid >> 6;
  if (lane == 0) sm[wv] = mx;
  __syncthreads();
  mx = fmaxf(fmaxf(sm[0], sm[1]), fmaxf(sm[2], sm[3]));
  float sum = 0.f;
  for (int t = tid; t < Mr; t += 256) sum += __expf(base[(size_t)t * ldl] - mx);
  for (int o = 32; o > 0; o >>= 1) sum += __shfl_down(sum, o, 64);
  if (lane == 0) ss[wv] = sum;
  __syncthreads();
  sum = ss[0] + ss[1] + ss[2] + ss[3];
  float inv = 1.f / sum;
  for (int t = tid; t < Mr; t += 256) {
    float x = base[(size_t)t * ldl];
    ob[(size_t)t * ldl] = (x < VTHR) ? (u16)0 : f2b(__expf(x - mx) * inv);
  }
}

// ======================= launch =======================
extern "C" void kernel_launch(void* const* d_in, const int* in_sizes, int n_in,
                              void* d_out, int out_size, void* d_ws, size_t ws_size,
                              hipStream_t stream) {
  const float* ll        = (const float*)d_in[0];
  const int* am          = (const int*)d_in[1];
  const int* fp_in       = (const int*)d_in[2];   // harness delivers int64 ref input as int32
  const float* attn_w1   = (const float*)d_in[4];
  const float* attn_w2   = (const float*)d_in[5];
  const float* attn_w3   = (const float*)d_in[6];
  const float* opt_w1    = (const float*)d_in[7];
  const float* opt_w2    = (const float*)d_in[8];
  const float* opt_w3    = (const float*)d_in[9];
  const float* self_w1   = (const float*)d_in[10];
  const float* self_w2   = (const float*)d_in[11];
  const float* self_w3   = (const float*)d_in[12];
  const float* attn_fc_w = (const float*)d_in[13];
  const float* attn_fc_b = (const float*)d_in[14];
  const float* comp_fc_w = (const float*)d_in[15];
  const float* comp_fc_b = (const float*)d_in[16];
  const float* gate_fc_w = (const float*)d_in[17];
  const float* gate_fc_b = (const float*)d_in[18];
  const float* self_fc_w = (const float*)d_in[19];
  const float* self_fc_b = (const float*)d_in[20];
  float* out = (float*)d_out;

  // ---- arena ----
  const size_t BIGF = (size_t)NITEM * LOv * Hv;          // 14,680,064
  float* optcorrF = (float*)d_ws;                        // later aliased as fusion
  float* optionF  = optcorrF + BIGF;
  float* logitF   = optionF + BIGF;
  float* qlog     = logitF + BIGF;
  float* klog     = qlog + (size_t)NITEM * LOv;
  float* optq     = klog + (size_t)NITEM * LDv;
  float* optk     = optq + (size_t)NITEM * LOv;
  u16* wcomp = (u16*)(optk + (size_t)NITEM * LOv);       // 1024*7168
  u16* wgate = wcomp + (size_t)Hv * 7 * Hv;
  u16* wattn = wgate + (size_t)Hv * 2 * Hv;
  u16* wself = wattn + (size_t)Hv * 3 * Hv;
  u16* kqB   = wself + (size_t)Hv * 4 * Hv;              // 64*224*480
  u16* awbB  = kqB + (size_t)NITEM * LOv * LDv;
  u16* cowB  = awbB + (size_t)NITEM * LOv * LDv;
  unsigned char* optm = (unsigned char*)(cowB + (size_t)NITEM * LOv * LOv);
  unsigned char* docm = optm + (size_t)NITEM * LOv;
  int* fp = (int*)(docm + (size_t)NITEM * LDv);
  u16* U = (u16*)(fp + NITEM + 32);
  const size_t E_OPT = (size_t)NITEM * LOv * Hv;
  const size_t E_DOC = (size_t)NITEM * LDv * Hv;
  // P1: compA [64][224][7168]; block0 doubles as opt_enc bf16
  u16* optw3B = U;
  u16* optTB  = U + E_OPT;
  u16* aw1B   = U + 2 * E_OPT;                           // 192*224*224
  u16* compA  = aw1B + (size_t)12 * BSZ * LOv * LOv;     // 64*224*7168
  // P2
  u16* gateA  = U;                                       // 64*224*2048
  // P3
  u16* docB   = U;
  u16* docTB  = U + E_DOC;
  u16* optw3C = U + 2 * E_DOC;
  u16* optTC  = optw3C + E_OPT;
  u16* attnA  = optTC + E_OPT;                           // 64*224*3072
  // P4
  u16* selfA  = U;                                       // 64*224*4096
  u16* fusw3  = U + (size_t)NITEM * LOv * 4 * Hv;
  u16* fusTB  = fusw3 + E_OPT;
  float* fusionF = optcorrF;

  const long long sOH = (long long)LOv * Hv;
  const long long sLL = (long long)LOv * LOv;
  const long long sLD = (long long)LOv * LDv;
  const long long sC7 = (long long)LOv * 7 * Hv;

  (void)hipMemsetAsync(d_out, 0, (size_t)NITEM * Hv * sizeof(float), stream);
  init_masks<<<NITEM, 256, 0, stream>>>(fp_in, am, fp, optm, docm);
  convf2b<<<1024, 256, 0, stream>>>(comp_fc_w, wcomp, Hv * 7 * Hv);
  convf2b<<<1024, 256, 0, stream>>>(gate_fc_w, wgate, Hv * 2 * Hv);
  convf2b<<<1024, 256, 0, stream>>>(attn_fc_w, wattn, Hv * 3 * Hv);
  convf2b<<<1024, 256, 0, stream>>>(self_fc_w, wself, Hv * 4 * Hv);
  build_opt<<<dim3(LOv, NITEM), 256, 0, stream>>>(ll, fp, opt_w3, compA, optw3B);
  transpose_b<<<dim3(LOv / 32, Hv / 32, NITEM), 256, 0, stream>>>(nullptr, 0, ll, fp, docm, 1, LOv, optTB);
  dot_rows<<<dim3(LOv, NITEM), 256, 0, stream>>>(nullptr, 0, ll, fp, docm, opt_w1, optq, LOv, 1);
  dot_rows<<<dim3(LOv, NITEM), 256, 0, stream>>>(nullptr, 0, ll, fp, docm, opt_w2, optk, LOv, 1);

  // ========== Phase 1: all 12 pairwise logits -> softmax -> a_s (fused into compA) ==========
  { // logits for all (i,j) pairs: z = pair*16 + b ; B = compA block0 (opt_enc)
    MG p = {};
    p.A = optw3B; p.sA = sOH; p.lda = Hv; p.aidx = IX_ITQ;
    p.B = compA;  p.sB = sC7; p.ldb = 7 * Hv; p.bidx = IX_ITK;
    p.C = logitF; p.sC = sLL; p.ldc = LOv; p.cidx = IX_INST;
    p.qmask = optm; p.ldqm = LOv; p.kmask = optm; p.ldkm = LOv;
    p.qlogv = optq; p.ldql = LOv; p.klogv = optk; p.ldkl = LOv;
    p.M = LOv; p.N = LOv; p.K = Hv; p.epi = EP_LOGIT; p.pm = 1;
    mgemm<<<dim3(2, 2, 12 * BSZ), 256, 0, stream>>>(p);
  }
  row_softmax<<<dim3(LOv, 12 * BSZ), 256, 0, stream>>>(logitF, aw1B, LOv, LOv, sLL);
  { // a_s = aw @ opt_enc[j]; epilogue writes cur*a, cur-a into compA blocks (1+2s, 2+2s)
    MG p = {};
    p.A = aw1B; p.sA = sLL; p.lda = LOv; p.aidx = IX_INST;
    p.B = optTB; p.sB = (long long)Hv * LOv; p.ldb = LOv; p.bidx = IX_ITK;
    p.Cb = compA; p.sC = sC7; p.ldc = 7 * Hv; p.cidx = IX_ITQ;
    p.M = LOv; p.N = Hv; p.K = LOv; p.epi = EP_AS; p.pm = 1;
    mgemm<<<dim3(8, 2, 12 * BSZ), 256, 0, stream>>>(p);
  }
  { // opt_corr = tanh(compA @ comp_w^T + b), all 64 insts in one launch
    MF p = {};
    p.A = compA; p.sA = sC7; p.B = wcomp;
    p.C = optcorrF; p.sC = sOH; p.bias = comp_fc_b;
    p.M = LOv; p.K = 7 * Hv; p.epi = FCE_TANH;
    mgemm_fc<<<1024, 256, 0, stream>>>(p);
  }

  // ========== Phase 2: gate FC + blend ==========
  build_gateA<<<dim3(LOv, NITEM), 256, 0, stream>>>(ll, fp, optcorrF, gateA);
  {
    MF p = {};
    p.A = gateA; p.sA = (long long)LOv * 2 * Hv; p.B = wgate;
    p.C = optionF; p.sC = sOH; p.bias = gate_fc_b;
    p.ll = ll; p.fp = fp; p.Yv = optcorrF;
    p.M = LOv; p.K = 2 * Hv; p.epi = FCE_GATE;
    mgemm_fc<<<1024, 256, 0, stream>>>(p);
  }

  // ========== Phase 3: doc attention + co-attention + attn FC ==========
  build_doc<<<dim3(LDv, NITEM), 256, 0, stream>>>(ll, docm, docB);
  transpose_b<<<dim3(LDv / 32, Hv / 32, NITEM), 256, 0, stream>>>(nullptr, 0, ll, fp, docm, 2, LDv, docTB);
  conv_act<<<dim3(LOv, NITEM), 256, 0, stream>>>(optionF, attn_w3, attnA, 3 * Hv, optw3C);
  transpose_b<<<dim3(LOv / 32, Hv / 32, NITEM), 256, 0, stream>>>(optionF, sOH, ll, fp, docm, 0, LOv, optTC);
  dot_rows<<<dim3(LOv, NITEM), 256, 0, stream>>>(optionF, sOH, ll, fp, docm, attn_w1, qlog, LOv, 0);
  dot_rows<<<dim3(LDv, NITEM), 256, 0, stream>>>(nullptr, 0, ll, fp, docm, attn_w2, klog, LDv, 2);
  { // logit [224,480]
    MG p = {};
    p.A = optw3C; p.sA = sOH; p.lda = Hv; p.aidx = IX_INST;
    p.B = docB; p.sB = (long long)LDv * Hv; p.ldb = Hv; p.bidx = IX_INST;
    p.C = logitF; p.sC = sLD; p.ldc = LDv; p.cidx = IX_INST;
    p.qmask = optm; p.ldqm = LOv; p.kmask = docm; p.ldkm = LDv;
    p.qlogv = qlog; p.ldql = LOv; p.klogv = klog; p.ldkl = LDv;
    p.M = LOv; p.N = LDv; p.K = Hv; p.qi = -1; p.kj = -1; p.epi = EP_LOGIT;
    mgemm<<<dim3(4, 2, NITEM), 256, 0, stream>>>(p);
  }
  row_softmax<<<dim3(LOv, NITEM), 256, 0, stream>>>(logitF, awbB, LDv, LDv, sLD);
  col_softmax<<<dim3(LDv, NITEM), 256, 0, stream>>>(logitF, kqB, LOv, LDv, sLD);
  { // attn = aw @ doc -> attnA block 1
    MG p = {};
    p.A = awbB; p.sA = sLD; p.lda = LDv; p.aidx = IX_INST;
    p.B = docTB; p.sB = (long long)Hv * LDv; p.ldb = LDv; p.bidx = IX_INST;
    p.Cb = attnA + Hv; p.sC = (long long)LOv * 3 * Hv; p.ldc = 3 * Hv; p.cidx = IX_INST;
    p.M = LOv; p.N = Hv; p.K = LDv; p.qi = -1; p.kj = -1; p.epi = EP_BF16;
    mgemm<<<dim3(8, 2, NITEM), 256, 0, stream>>>(p);
  }
  { // co_w = aw @ kq^T
    MG p = {};
    p.A = awbB; p.sA = sLD; p.lda = LDv; p.aidx = IX_INST;
    p.B = kqB; p.sB = sLD; p.ldb = LDv; p.bidx = IX_INST;
    p.Cb = cowB; p.sC = sLL; p.ldc = LOv; p.cidx = IX_INST;
    p.M = LOv; p.N = LOv; p.K = LDv; p.qi = -1; p.kj = -1; p.epi = EP_BF16;
    mgemm<<<dim3(2, 2, NITEM), 256, 0, stream>>>(p);
  }
  { // coattn = co_w @ option -> attnA block 2
    MG p = {};
    p.A = cowB; p.sA = sLL; p.lda = LOv; p.aidx = IX_INST;
    p.B = optTC; p.sB = (long long)Hv * LOv; p.ldb = LOv; p.bidx = IX_INST;
    p.Cb = attnA + 2 * Hv; p.sC = (long long)LOv * 3 * Hv; p.ldc = 3 * Hv; p.cidx = IX_INST;
    p.M = LOv; p.N = Hv; p.K = LOv; p.qi = -1; p.kj = -1; p.epi = EP_BF16;
    mgemm<<<dim3(8, 2, NITEM), 256, 0, stream>>>(p);
  }
  { // fusion = tanh(attnA @ attn_w^T + b)
    MF p = {};
    p.A = attnA; p.sA = (long long)LOv * 3 * Hv; p.B = wattn;
    p.C = fusionF; p.sC = sOH; p.bias = attn_fc_b;
    p.M = LOv; p.K = 3 * Hv; p.epi = FCE_TANH;
    mgemm_fc<<<1024, 256, 0, stream>>>(p);
  }

  // ========== Phase 4: self attention + self FC + masked max ==========
  conv_act<<<dim3(LOv, NITEM), 256, 0, stream>>>(fusionF, self_w3, selfA, 4 * Hv, fusw3);
  transpose_b<<<dim3(LOv / 32, Hv / 32, NITEM), 256, 0, stream>>>(fusionF, sOH, ll, fp, docm, 0, LOv, fusTB);
  dot_rows<<<dim3(LOv, NITEM), 256, 0, stream>>>(fusionF, sOH, ll, fp, docm, self_w1, qlog, LOv, 0);
  dot_rows<<<dim3(LOv, NITEM), 256, 0, stream>>>(fusionF, sOH, ll, fp, docm, self_w2, klog, LOv, 0);
  { // self logit (B = selfA block 0 = fusion bf16, ldb=4096)
    MG p = {};
    p.A = fusw3; p.sA = sOH; p.lda = Hv; p.aidx = IX_INST;
    p.B = selfA; p.sB = (long long)LOv * 4 * Hv; p.ldb = 4 * Hv; p.bidx = IX_INST;
    p.C = logitF; p.sC = sLL; p.ldc = LOv; p.cidx = IX_INST;
    p.qmask = optm; p.ldqm = LOv; p.kmask = optm; p.ldkm = LOv;
    p.qlogv = qlog; p.ldql = LOv; p.klogv = klog; p.ldkl = LOv;
    p.M = LOv; p.N = LOv; p.K = Hv; p.qi = -1; p.kj = -1; p.epi = EP_LOGIT;
    mgemm<<<dim3(2, 2, NITEM), 256, 0, stream>>>(p);
  }
  row_softmax<<<dim3(LOv, NITEM), 256, 0, stream>>>(logitF, awbB, LOv, LOv, sLL);
  { // attn2 = aw @ fusion -> selfA block 1
    MG p = {};
    p.A = awbB; p.sA = sLL; p.lda = LOv; p.aidx = IX_INST;
    p.B = fusTB; p.sB = (long long)Hv * LOv; p.ldb = LOv; p.bidx = IX_INST;
    p.Cb = selfA + Hv; p.sC = (long long)LOv * 4 * Hv; p.ldc = 4 * Hv; p.cidx = IX_INST;
    p.M = LOv; p.N = Hv; p.K = LOv; p.qi = -1; p.kj = -1; p.epi = EP_BF16;
    mgemm<<<dim3(8, 2, NITEM), 256, 0, stream>>>(p);
  }
  build_selfA23<<<dim3(LOv, NITEM), 256, 0, stream>>>(selfA);
  { // out[item,h] = max over valid t of relu(selfA @ self_w^T + b)
    MF p = {};
    p.A = selfA; p.sA = (long long)LOv * 4 * Hv; p.B = wself;
    p.bias = self_fc_b; p.optm = optm; p.outmax = out;
    p.M = LOv; p.K = 4 * Hv; p.epi = FCE_SELFMAX;
    mgemm_fc<<<1024, 256, 0, stream>>>(p);
  }
}

// Round 7
// 2193.682 us; speedup vs baseline: 11.6138x; 1.0475x over previous
//
#include <hip/hip_runtime.h>
#include <math.h>

// Problem constants (fixed by the reference: H=1024, B=16, L=4, S=512)
#define Sv   512
#define Hv   1024
#define BSZ  16
#define NLB  4
#define NITEM 64          // BSZ*NLB
#define LOv  224          // >= max option len (512-300=212), multiple of 32
#define LDv  480          // >= max doc len (449), multiple of 32
#define NEGV (-1e30f)
#define VTHR (-1e20f)

typedef unsigned short u16;
typedef __attribute__((ext_vector_type(8))) short short8;   // 8 bf16 = 4 VGPRs (MFMA A/B frag)
using floatx4 = __attribute__((ext_vector_type(4))) float;

__device__ __forceinline__ u16 f2b(float x) {  // f32 -> bf16 RNE
  unsigned u = __float_as_uint(x);
  return (u16)((u + 0x7FFFu + ((u >> 16) & 1u)) >> 16);
}
__device__ __forceinline__ float b2f(u16 b) { return __uint_as_float(((unsigned)b) << 16); }

__device__ __forceinline__ float opt_view_f(const float* ll, const int* fp, int item, int t, int h) {
  int idx = fp[item] + t;
  return (idx < Sv) ? ll[((size_t)item * Sv + idx) * Hv + h] : 0.f;
}

// async global->LDS, 16B per lane; LDS dest = wave-uniform base + lane*16
__device__ __forceinline__ void gll16(const u16* g, u16* l) {
  __builtin_amdgcn_global_load_lds(
      (const __attribute__((address_space(1))) unsigned int*)(const void*)g,
      (__attribute__((address_space(3))) unsigned int*)(void*)l, 16, 0, 0);
}

// LDS chunk swizzle (BK=32 layout): row r's 16B chunk q lives at slot q ^ sw(r).
__device__ __forceinline__ int swz(int r) { return (r >> 1) & 3; }

// ======================= bf16 MFMA GEMM (attention-shaped, BK=32) =======================
enum { EP_BF16 = 0, EP_LOGIT = 1, EP_AS = 2 };
enum { IX_INST = 0, IX_ITQ = 1, IX_ITK = 2 };

struct MG {
  const u16* A; long long sA; int lda; int aidx;
  const u16* B; long long sB; int ldb; int bidx;
  float* C; long long sC; int ldc; int cidx;
  u16* Cb;
  const unsigned char* qmask; int ldqm;
  const unsigned char* kmask; int ldkm;
  const float* qlogv; int ldql;
  const float* klogv; int ldkl;
  int M, N, K, qi, kj, epi, pm;   // pm: pairmode (z = pair*BSZ + b, pair=i*3+jj)
};

__global__ __launch_bounds__(256) void mgemm(MG p) {
  __shared__ u16 As[128][32];
  __shared__ u16 Bs[128][32];
  int inst = blockIdx.z;
  int itq, itk;
  if (p.pm) {
    int b = inst % BSZ, pair = inst / BSZ;
    int i = pair / 3, jj = pair % 3;
    int j = jj + (jj >= i ? 1 : 0);
    itq = b * NLB + i; itk = b * NLB + j;
  } else {
    itq = (p.qi >= 0) ? inst * NLB + p.qi : inst;
    itk = (p.kj >= 0) ? inst * NLB + p.kj : inst;
  }
  int ai = (p.aidx == IX_ITQ) ? itq : (p.aidx == IX_ITK ? itk : inst);
  int bi = (p.bidx == IX_ITQ) ? itq : (p.bidx == IX_ITK ? itk : inst);
  int ci = (p.cidx == IX_ITQ) ? itq : (p.cidx == IX_ITK ? itk : inst);
  const u16* Ab = p.A + (size_t)ai * p.sA;
  const u16* Bb = p.B + (size_t)bi * p.sB;
  int tid = threadIdx.x;
  int m0 = blockIdx.y * 128, n0 = blockIdx.x * 128;
  int wave = tid >> 6, lane = tid & 63;
  int wm = (wave >> 1) * 64, wn = (wave & 1) * 64;
  int col = lane & 15, quad = lane >> 4;
  int rl = lane >> 2, cslot = lane & 3;
  floatx4 acc[4][4] = {};

  { // zero-init LDS so exec-masked boundary rows read as 0
    uint4 z4 = {0, 0, 0, 0};
    uint4* a4 = (uint4*)&As[0][0];
    uint4* b4 = (uint4*)&Bs[0][0];
    for (int z = tid; z < 512; z += 256) { a4[z] = z4; b4[z] = z4; }
  }
  __syncthreads();

  for (int k0 = 0; k0 < p.K; k0 += 32) {
    int rb = wave * 32;
    #pragma unroll
    for (int c = 0; c < 2; c++) {
      int r = rb + c * 16 + rl;
      int gk = k0 + ((cslot ^ swz(r)) * 8);   // swizzled source chunk
      if (m0 + r < p.M) gll16(Ab + (size_t)(m0 + r) * p.lda + gk, &As[rb + c * 16][0]);
      if (n0 + r < p.N) gll16(Bb + (size_t)(n0 + r) * p.ldb + gk, &Bs[rb + c * 16][0]);
    }
    __syncthreads();
    short8 a[4], b[4];
    #pragma unroll
    for (int mi = 0; mi < 4; mi++) {
      int r = wm + mi * 16 + col;
      a[mi] = *(const short8*)&As[r][(quad ^ swz(r)) * 8];
    }
    #pragma unroll
    for (int ni = 0; ni < 4; ni++) {
      int r = wn + ni * 16 + col;
      b[ni] = *(const short8*)&Bs[r][(quad ^ swz(r)) * 8];
    }
    #pragma unroll
    for (int mi = 0; mi < 4; mi++)
      #pragma unroll
      for (int ni = 0; ni < 4; ni++)
        acc[mi][ni] = __builtin_amdgcn_mfma_f32_16x16x32_bf16(a[mi], b[ni], acc[mi][ni], 0, 0, 0);
    __syncthreads();
  }

  int sblk = (inst / BSZ) % 3;  // EP_AS: which a_s slot
  #pragma unroll
  for (int mi = 0; mi < 4; mi++) {
    #pragma unroll
    for (int ni = 0; ni < 4; ni++) {
      int n = n0 + wn + ni * 16 + col;
      if (n >= p.N) continue;
      #pragma unroll
      for (int r = 0; r < 4; r++) {
        int m = m0 + wm + mi * 16 + quad * 4 + r;
        if (m >= p.M) continue;
        float v = acc[mi][ni][r];
        if (p.epi == EP_BF16) {
          p.Cb[(size_t)ci * p.sC + (size_t)m * p.ldc + n] = f2b(v);
        } else if (p.epi == EP_AS) {
          u16* base = p.Cb + (size_t)itq * p.sC + (size_t)m * p.ldc;
          float cur = b2f(base[n]);  // compA block 0 = opt_enc
          base[(size_t)(1 + 2 * sblk) * Hv + n] = f2b(cur * v);
          base[(size_t)(2 + 2 * sblk) * Hv + n] = f2b(cur - v);
        } else {  // EP_LOGIT
          bool qm = p.qmask[itq * p.ldqm + m] != 0;
          bool km = p.kmask[itk * p.ldkm + n] != 0;
          p.C[(size_t)ci * p.sC + (size_t)m * p.ldc + n] =
            (qm && km) ? (v + p.qlogv[(size_t)itq * p.ldql + m] + p.klogv[(size_t)itk * p.ldkl + n]) : NEGV;
        }
      }
    }
  }
}

// ======================= FC GEMM (BK=64): A [64][224][K] bf16 x weights [1024][K] =======================
// Flat grid 1024 = 128 g x 8 nt, XCD-swizzled: id = g%8 + 8*(nt + 8*(g/8)) so all 8 n-tiles
// of one (inst, mtile) share an XCD (A-stripe served from that XCD's L2).
// BK=64 halves the barrier count vs BK=32: 32 MFMA per vmcnt(0) drain instead of 16
// (drain ~900cyc is the bottleneck; amortize it).
enum { FCE_TANH = 0, FCE_GATE = 1, FCE_SELFMAX = 2 };

struct MF {
  const u16* A; long long sA;   // lda = K
  const u16* B;                 // [1024][K]
  float* C; long long sC;       // f32 out [inst][224][1024]
  const float* bias;
  const float* ll; const int* fp; const float* Yv;   // gate
  const unsigned char* optm; float* outmax;          // selfmax
  int M, K, epi;
};

__global__ __launch_bounds__(256) void mgemm_fc(MF p) {
  __shared__ u16 As[128][64];
  __shared__ u16 Bs[128][64];
  int id = blockIdx.x;
  int low = id & 7, nt = (id >> 3) & 7, hi = id >> 6;
  int g = (hi << 3) | low;
  int inst = g >> 1, mt = g & 1;
  const u16* Ab = p.A + (size_t)inst * p.sA;
  int tid = threadIdx.x;
  int m0 = mt * 128, n0 = nt * 128;
  int wave = tid >> 6, lane = tid & 63;
  int wm = (wave >> 1) * 64, wn = (wave & 1) * 64;
  int col = lane & 15, quad = lane >> 4;
  int rl8 = lane >> 3, c8 = lane & 7;   // staging: 8 rows/call, 8 chunks/row
  floatx4 acc[4][4] = {};

  { // zero-init so skipped boundary rows read as 0
    uint4 z4 = {0, 0, 0, 0};
    uint4* a4 = (uint4*)&As[0][0];
    uint4* b4 = (uint4*)&Bs[0][0];
    for (int z = tid; z < 1024; z += 256) { a4[z] = z4; b4[z] = z4; }
  }
  __syncthreads();

  for (int k0 = 0; k0 < p.K; k0 += 64) {
    int rb = wave * 32;
    #pragma unroll
    for (int c = 0; c < 4; c++) {
      int r = rb + c * 8 + rl8;
      int gk = k0 + ((c8 ^ (r & 7)) * 8);   // chunk swizzle: slot s holds logical chunk s^(r&7)
      if (m0 + r < p.M) gll16(Ab + (size_t)(m0 + r) * p.K + gk, &As[rb + c * 8][0]);
      gll16(p.B + (size_t)(n0 + r) * p.K + gk, &Bs[rb + c * 8][0]);  // N=1024 always full
    }
    __syncthreads();
    #pragma unroll
    for (int s = 0; s < 2; s++) {
      short8 a[4], b[4];
      #pragma unroll
      for (int mi = 0; mi < 4; mi++) {
        int r = wm + mi * 16 + col;
        a[mi] = *(const short8*)&As[r][(((s * 4 + quad) ^ (r & 7)) * 8)];
      }
      #pragma unroll
      for (int ni = 0; ni < 4; ni++) {
        int r = wn + ni * 16 + col;
        b[ni] = *(const short8*)&Bs[r][(((s * 4 + quad) ^ (r & 7)) * 8)];
      }
      #pragma unroll
      for (int mi = 0; mi < 4; mi++)
        #pragma unroll
        for (int ni = 0; ni < 4; ni++)
          acc[mi][ni] = __builtin_amdgcn_mfma_f32_16x16x32_bf16(a[mi], b[ni], acc[mi][ni], 0, 0, 0);
    }
    __syncthreads();
  }

  if (p.epi == FCE_SELFMAX) {
    // masked rows contribute 0 (safe: final max >= 0 since relu >= 0 and >=1 valid row/item)
    #pragma unroll
    for (int ni = 0; ni < 4; ni++) {
      int n = n0 + wn + ni * 16 + col;
      float bn = p.bias[n];
      float mloc = 0.f;
      #pragma unroll
      for (int mi = 0; mi < 4; mi++)
        #pragma unroll
        for (int r = 0; r < 4; r++) {
          int m = m0 + wm + mi * 16 + quad * 4 + r;
          float vv = fmaxf(acc[mi][ni][r] + bn, 0.f);
          if (m < p.M && p.optm[inst * LOv + m]) mloc = fmaxf(mloc, vv);
        }
      mloc = fmaxf(mloc, __shfl_xor(mloc, 16, 64));
      mloc = fmaxf(mloc, __shfl_xor(mloc, 32, 64));
      if (quad == 0)
        atomicMax((unsigned int*)(p.outmax + (size_t)inst * Hv + n), __float_as_uint(mloc));
    }
    return;
  }
  #pragma unroll
  for (int mi = 0; mi < 4; mi++) {
    #pragma unroll
    for (int ni = 0; ni < 4; ni++) {
      int n = n0 + wn + ni * 16 + col;
      #pragma unroll
      for (int r = 0; r < 4; r++) {
        int m = m0 + wm + mi * 16 + quad * 4 + r;
        if (m >= p.M) continue;
        float v = acc[mi][ni][r] + p.bias[n];
        float* cp = p.C + (size_t)inst * p.sC + (size_t)m * Hv + n;
        if (p.epi == FCE_TANH) {
          *cp = tanhf(v);
        } else {  // FCE_GATE
          float gg = 1.f / (1.f + __expf(-v));
          float xv = opt_view_f(p.ll, p.fp, inst, m, n);
          float yv = p.Yv[(size_t)inst * p.sC + (size_t)m * Hv + n];
          *cp = xv * gg + yv * (1.f - gg);
        }
      }
    }
  }
}

// ======================= helpers =======================
__global__ __launch_bounds__(256) void init_masks(const int* fp_in, const int* am, int* fp,
                                                  unsigned char* optm, unsigned char* docm) {
  int item = blockIdx.x;
  int f = fp_in[item];
  if (threadIdx.x == 0) fp[item] = f;
  for (int t = threadIdx.x; t < LDv; t += blockDim.x) {
    docm[item * LDv + t] = (t < f && t < Sv && am[item * Sv + t] > 0) ? 1 : 0;
    if (t < LOv) {
      int idx = f + t;
      optm[item * LOv + t] = (idx < Sv && am[item * Sv + idx] > 0) ? 1 : 0;
    }
  }
}

__global__ __launch_bounds__(256) void convf2b(const float* src, u16* dst, int n) {
  int i = blockIdx.x * 256 + threadIdx.x;
  int stride = gridDim.x * 256;
  for (; i < n; i += stride) dst[i] = f2b(src[i]);
}

// opt view -> compA block0 (ld 7H) + (opt*w3)
__global__ __launch_bounds__(256) void build_opt(const float* ll, const int* fp, const float* w3,
                                                 u16* compA0, u16* optw3B) {
  int t = blockIdx.x, item = blockIdx.y;
  int idx = fp[item] + t;
  bool v = idx < Sv;
  const float* src = ll + ((size_t)item * Sv + (v ? idx : 0)) * Hv;
  u16* d0 = compA0 + ((size_t)item * LOv + t) * (7 * Hv);
  u16* d1 = optw3B + ((size_t)item * LOv + t) * Hv;
  for (int h = threadIdx.x; h < Hv; h += 256) {
    float x = v ? src[h] : 0.f;
    d0[h] = f2b(x);
    d1[h] = f2b(x * w3[h]);
  }
}

__global__ __launch_bounds__(256) void build_doc(const float* ll, const unsigned char* docm, u16* docB) {
  int t = blockIdx.x, item = blockIdx.y;
  bool v = docm[item * LDv + t] != 0;
  const float* src = ll + ((size_t)item * Sv + (t < Sv ? t : 0)) * Hv;
  size_t o = ((size_t)item * LDv + t) * Hv;
  for (int h = threadIdx.x; h < Hv; h += 256) docB[o + h] = v ? f2b(src[h]) : (u16)0;
}

__global__ __launch_bounds__(256) void transpose_b(const float* src, long long sS,
                                                   const float* ll, const int* fp, const unsigned char* docm,
                                                   int mode, int Lt, u16* out) {
  __shared__ float tile[32][33];
  int t0 = blockIdx.x * 32, h0 = blockIdx.y * 32, item = blockIdx.z;
  int tx = threadIdx.x & 31, ty0 = threadIdx.x >> 5;
  for (int yy = ty0; yy < 32; yy += 8) {
    int t = t0 + yy, h = h0 + tx;
    float v = 0.f;
    if (t < Lt) {
      if (mode == 0)      v = src[(size_t)item * sS + (size_t)t * Hv + h];
      else if (mode == 1) { int idx = fp[item] + t; if (idx < Sv) v = ll[((size_t)item * Sv + idx) * Hv + h]; }
      else                { if (docm[item * LDv + t]) v = ll[((size_t)item * Sv + t) * Hv + h]; }
    }
    tile[yy][tx] = v;
  }
  __syncthreads();
  for (int yy = ty0; yy < 32; yy += 8) {
    int h = h0 + yy, t = t0 + tx;
    if (t < Lt) out[((size_t)item * Hv + h) * (size_t)Lt + t] = f2b(tile[tx][yy]);
  }
}

__global__ __launch_bounds__(256) void build_gateA(const float* ll, const int* fp, const float* corr, u16* gateA) {
  int t = blockIdx.x, item = blockIdx.y;
  int idx = fp[item] + t;
  bool v = idx < Sv;
  const float* src = ll + ((size_t)item * Sv + (v ? idx : 0)) * Hv;
  u16* dst = gateA + ((size_t)item * LOv + t) * (2 * Hv);
  const float* cr = corr + ((size_t)item * LOv + t) * Hv;
  for (int h = threadIdx.x; h < Hv; h += 256) {
    dst[h] = f2b(v ? src[h] : 0.f);
    dst[Hv + h] = f2b(cr[h]);
  }
}

__global__ __launch_bounds__(256) void conv_act(const float* src, const float* w3,
                                                u16* dst1, int ld1, u16* dstw3) {
  int t = blockIdx.x, item = blockIdx.y;
  const float* s = src + ((size_t)item * LOv + t) * Hv;
  u16* d1 = dst1 + ((size_t)item * LOv + t) * ld1;
  u16* d2 = dstw3 + ((size_t)item * LOv + t) * Hv;
  for (int h = threadIdx.x; h < Hv; h += 256) {
    float x = s[h];
    d1[h] = f2b(x);
    d2[h] = f2b(x * w3[h]);
  }
}

__global__ __launch_bounds__(256) void build_selfA23(u16* selfA) {
  int t = blockIdx.x, item = blockIdx.y;
  u16* row = selfA + ((size_t)item * LOv + t) * (4 * Hv);
  for (int h = threadIdx.x; h < Hv; h += 256) {
    float f = b2f(row[h]), a = b2f(row[Hv + h]);
    row[2 * Hv + h] = f2b(f * a);
    row[3 * Hv + h] = f2b(f - a);
  }
}

__global__ __launch_bounds__(256) void dot_rows(const float* src, long long sS,
                                                const float* ll, const int* fp, const unsigned char* docm,
                                                const float* w, float* outv, int ldo, int mode) {
  int t = blockIdx.x, item = blockIdx.y;
  int tid = threadIdx.x;
  float s = 0.f;
  for (int h = tid; h < Hv; h += 256) {
    float v;
    if (mode == 0)      v = src[(size_t)item * sS + (size_t)t * Hv + h];
    else if (mode == 1) v = opt_view_f(ll, fp, item, t, h);
    else                v = docm[item * LDv + t] ? ll[((size_t)item * Sv + t) * Hv + h] : 0.f;
    s += v * w[h];
  }
  __shared__ float red[4];
  for (int o = 32; o > 0; o >>= 1) s += __shfl_down(s, o, 64);
  int lane = tid & 63, wv = tid >> 6;
  if (lane == 0) red[wv] = s;
  __syncthreads();
  if (tid == 0) outv[(size_t)item * ldo + t] = red[0] + red[1] + red[2] + red[3];
}

__global__ __launch_bounds__(256) void row_softmax(const float* src, u16* dst, int Lk, int ldl, long long sL) {
  int m = blockIdx.x, inst = blockIdx.y;
  const float* row = src + (size_t)inst * sL + (size_t)m * ldl;
  u16* orow = dst + (size_t)inst * sL + (size_t)m * ldl;
  int tid = threadIdx.x;
  float mx = -INFINITY;
  for (int t = tid; t < Lk; t += 256) mx = fmaxf(mx, row[t]);
  __shared__ float sm[4]; __shared__ float ss[4];
  for (int o = 32; o > 0; o >>= 1) mx = fmaxf(mx, __shfl_down(mx, o, 64));
  int lane = tid & 63, wv = tid >> 6;
  if (lane == 0) sm[wv] = mx;
  __syncthreads();
  mx = fmaxf(fmaxf(sm[0], sm[1]), fmaxf(sm[2], sm[3]));
  float sum = 0.f;
  for (int t = tid; t < Lk; t += 256) sum += __expf(row[t] - mx);
  for (int o = 32; o > 0; o >>= 1) sum += __shfl_down(sum, o, 64);
  if (lane == 0) ss[wv] = sum;
  __syncthreads();
  sum = ss[0] + ss[1] + ss[2] + ss[3];
  float inv = 1.f / sum;
  for (int t = tid; t < Lk; t += 256) {
    float x = row[t];
    orow[t] = (x < VTHR) ? (u16)0 : f2b(__expf(x - mx) * inv);
  }
}

__global__ __launch_bounds__(256) void col_softmax(const float* src, u16* dst, int Mr, int ldl, long long sL) {
  int c = blockIdx.x, inst = blockIdx.y;
  const float* base = src + (size_t)inst * sL + c;
  u16* ob = dst + (size_t)inst * sL + c;
  int tid = threadIdx.x;
  float mx = -INFINITY;
  for (int t = tid; t < Mr; t += 256) mx = fmaxf(mx, base[(size_t)t * ldl]);
  __shared__ float sm[4]; __shared__ float ss[4];
  for (int o = 32; o > 0; o >>= 1) mx = fmaxf(mx, __shfl_down(mx, o, 64));
  int lane = tid & 63, wv = tid >> 6;
  if (lane == 0) sm[wv] = mx;
  __syncthreads();
  mx = fmaxf(fmaxf(sm[0], sm[1]), fmaxf(sm[2], sm[3]));
  float sum = 0.f;
  for (int t = tid; t < Mr; t += 256) sum += __expf(base[(size_t)t * ldl] - mx);
  for (int o = 32; o > 0; o >>= 1) sum += __shfl_down(sum, o, 64);
  if (lane == 0) ss[wv] = sum;
  __syncthreads();
  sum = ss[0] + ss[1] + ss[2] + ss[3];
  float inv = 1.f / sum;
  for (int t = tid; t < Mr; t += 256) {
    float x = base[(size_t)t * ldl];
    ob[(size_t)t * ldl] = (x < VTHR) ? (u16)0 : f2b(__expf(x - mx) * inv);
  }
}

// ======================= launch =======================
extern "C" void kernel_launch(void* const* d_in, const int* in_sizes, int n_in,
                              void* d_out, int out_size, void* d_ws, size_t ws_size,
                              hipStream_t stream) {
  const float* ll        = (const float*)d_in[0];
  const int* am          = (const int*)d_in[1];
  const int* fp_in       = (const int*)d_in[2];   // harness delivers int64 ref input as int32
  const float* attn_w1   = (const float*)d_in[4];
  const float* attn_w2   = (const float*)d_in[5];
  const float* attn_w3   = (const float*)d_in[6];
  const float* opt_w1    = (const float*)d_in[7];
  const float* opt_w2    = (const float*)d_in[8];
  const float* opt_w3    = (const float*)d_in[9];
  const float* self_w1   = (const float*)d_in[10];
  const float* self_w2   = (const float*)d_in[11];
  const float* self_w3   = (const float*)d_in[12];
  const float* attn_fc_w = (const float*)d_in[13];
  const float* attn_fc_b = (const float*)d_in[14];
  const float* comp_fc_w = (const float*)d_in[15];
  const float* comp_fc_b = (const float*)d_in[16];
  const float* gate_fc_w = (const float*)d_in[17];
  const float* gate_fc_b = (const float*)d_in[18];
  const float* self_fc_w = (const float*)d_in[19];
  const float* self_fc_b = (const float*)d_in[20];
  float* out = (float*)d_out;

  // ---- arena ----
  const size_t BIGF = (size_t)NITEM * LOv * Hv;          // 14,680,064
  float* optcorrF = (float*)d_ws;                        // later aliased as fusion
  float* optionF  = optcorrF + BIGF;
  float* logitF   = optionF + BIGF;
  float* qlog     = logitF + BIGF;
  float* klog     = qlog + (size_t)NITEM * LOv;
  float* optq     = klog + (size_t)NITEM * LDv;
  float* optk     = optq + (size_t)NITEM * LOv;
  u16* wcomp = (u16*)(optk + (size_t)NITEM * LOv);       // 1024*7168
  u16* wgate = wcomp + (size_t)Hv * 7 * Hv;
  u16* wattn = wgate + (size_t)Hv * 2 * Hv;
  u16* wself = wattn + (size_t)Hv * 3 * Hv;
  u16* kqB   = wself + (size_t)Hv * 4 * Hv;              // 64*224*480
  u16* awbB  = kqB + (size_t)NITEM * LOv * LDv;
  u16* cowB  = awbB + (size_t)NITEM * LOv * LDv;
  unsigned char* optm = (unsigned char*)(cowB + (size_t)NITEM * LOv * LOv);
  unsigned char* docm = optm + (size_t)NITEM * LOv;
  int* fp = (int*)(docm + (size_t)NITEM * LDv);
  u16* U = (u16*)(fp + NITEM + 32);
  const size_t E_OPT = (size_t)NITEM * LOv * Hv;
  const size_t E_DOC = (size_t)NITEM * LDv * Hv;
  // P1: compA [64][224][7168]; block0 doubles as opt_enc bf16
  u16* optw3B = U;
  u16* optTB  = U + E_OPT;
  u16* aw1B   = U + 2 * E_OPT;                           // 192*224*224
  u16* compA  = aw1B + (size_t)12 * BSZ * LOv * LOv;     // 64*224*7168
  // P2
  u16* gateA  = U;                                       // 64*224*2048
  // P3
  u16* docB   = U;
  u16* docTB  = U + E_DOC;
  u16* optw3C = U + 2 * E_DOC;
  u16* optTC  = optw3C + E_OPT;
  u16* attnA  = optTC + E_OPT;                           // 64*224*3072
  // P4
  u16* selfA  = U;                                       // 64*224*4096
  u16* fusw3  = U + (size_t)NITEM * LOv * 4 * Hv;
  u16* fusTB  = fusw3 + E_OPT;
  float* fusionF = optcorrF;

  const long long sOH = (long long)LOv * Hv;
  const long long sLL = (long long)LOv * LOv;
  const long long sLD = (long long)LOv * LDv;
  const long long sC7 = (long long)LOv * 7 * Hv;

  (void)hipMemsetAsync(d_out, 0, (size_t)NITEM * Hv * sizeof(float), stream);
  init_masks<<<NITEM, 256, 0, stream>>>(fp_in, am, fp, optm, docm);
  convf2b<<<1024, 256, 0, stream>>>(comp_fc_w, wcomp, Hv * 7 * Hv);
  convf2b<<<1024, 256, 0, stream>>>(gate_fc_w, wgate, Hv * 2 * Hv);
  convf2b<<<1024, 256, 0, stream>>>(attn_fc_w, wattn, Hv * 3 * Hv);
  convf2b<<<1024, 256, 0, stream>>>(self_fc_w, wself, Hv * 4 * Hv);
  build_opt<<<dim3(LOv, NITEM), 256, 0, stream>>>(ll, fp, opt_w3, compA, optw3B);
  transpose_b<<<dim3(LOv / 32, Hv / 32, NITEM), 256, 0, stream>>>(nullptr, 0, ll, fp, docm, 1, LOv, optTB);
  dot_rows<<<dim3(LOv, NITEM), 256, 0, stream>>>(nullptr, 0, ll, fp, docm, opt_w1, optq, LOv, 1);
  dot_rows<<<dim3(LOv, NITEM), 256, 0, stream>>>(nullptr, 0, ll, fp, docm, opt_w2, optk, LOv, 1);

  // ========== Phase 1: all 12 pairwise logits -> softmax -> a_s (fused into compA) ==========
  { // logits for all (i,j) pairs: z = pair*16 + b ; B = compA block0 (opt_enc)
    MG p = {};
    p.A = optw3B; p.sA = sOH; p.lda = Hv; p.aidx = IX_ITQ;
    p.B = compA;  p.sB = sC7; p.ldb = 7 * Hv; p.bidx = IX_ITK;
    p.C = logitF; p.sC = sLL; p.ldc = LOv; p.cidx = IX_INST;
    p.qmask = optm; p.ldqm = LOv; p.kmask = optm; p.ldkm = LOv;
    p.qlogv = optq; p.ldql = LOv; p.klogv = optk; p.ldkl = LOv;
    p.M = LOv; p.N = LOv; p.K = Hv; p.epi = EP_LOGIT; p.pm = 1;
    mgemm<<<dim3(2, 2, 12 * BSZ), 256, 0, stream>>>(p);
  }
  row_softmax<<<dim3(LOv, 12 * BSZ), 256, 0, stream>>>(logitF, aw1B, LOv, LOv, sLL);
  { // a_s = aw @ opt_enc[j]; epilogue writes cur*a, cur-a into compA blocks (1+2s, 2+2s)
    MG p = {};
    p.A = aw1B; p.sA = sLL; p.lda = LOv; p.aidx = IX_INST;
    p.B = optTB; p.sB = (long long)Hv * LOv; p.ldb = LOv; p.bidx = IX_ITK;
    p.Cb = compA; p.sC = sC7; p.ldc = 7 * Hv; p.cidx = IX_ITQ;
    p.M = LOv; p.N = Hv; p.K = LOv; p.epi = EP_AS; p.pm = 1;
    mgemm<<<dim3(8, 2, 12 * BSZ), 256, 0, stream>>>(p);
  }
  { // opt_corr = tanh(compA @ comp_w^T + b), all 64 insts in one launch
    MF p = {};
    p.A = compA; p.sA = sC7; p.B = wcomp;
    p.C = optcorrF; p.sC = sOH; p.bias = comp_fc_b;
    p.M = LOv; p.K = 7 * Hv; p.epi = FCE_TANH;
    mgemm_fc<<<1024, 256, 0, stream>>>(p);
  }

  // ========== Phase 2: gate FC + blend ==========
  build_gateA<<<dim3(LOv, NITEM), 256, 0, stream>>>(ll, fp, optcorrF, gateA);
  {
    MF p = {};
    p.A = gateA; p.sA = (long long)LOv * 2 * Hv; p.B = wgate;
    p.C = optionF; p.sC = sOH; p.bias = gate_fc_b;
    p.ll = ll; p.fp = fp; p.Yv = optcorrF;
    p.M = LOv; p.K = 2 * Hv; p.epi = FCE_GATE;
    mgemm_fc<<<1024, 256, 0, stream>>>(p);
  }

  // ========== Phase 3: doc attention + co-attention + attn FC ==========
  build_doc<<<dim3(LDv, NITEM), 256, 0, stream>>>(ll, docm, docB);
  transpose_b<<<dim3(LDv / 32, Hv / 32, NITEM), 256, 0, stream>>>(nullptr, 0, ll, fp, docm, 2, LDv, docTB);
  conv_act<<<dim3(LOv, NITEM), 256, 0, stream>>>(optionF, attn_w3, attnA, 3 * Hv, optw3C);
  transpose_b<<<dim3(LOv / 32, Hv / 32, NITEM), 256, 0, stream>>>(optionF, sOH, ll, fp, docm, 0, LOv, optTC);
  dot_rows<<<dim3(LOv, NITEM), 256, 0, stream>>>(optionF, sOH, ll, fp, docm, attn_w1, qlog, LOv, 0);
  dot_rows<<<dim3(LDv, NITEM), 256, 0, stream>>>(nullptr, 0, ll, fp, docm, attn_w2, klog, LDv, 2);
  { // logit [224,480]
    MG p = {};
    p.A = optw3C; p.sA = sOH; p.lda = Hv; p.aidx = IX_INST;
    p.B = docB; p.sB = (long long)LDv * Hv; p.ldb = Hv; p.bidx = IX_INST;
    p.C = logitF; p.sC = sLD; p.ldc = LDv; p.cidx = IX_INST;
    p.qmask = optm; p.ldqm = LOv; p.kmask = docm; p.ldkm = LDv;
    p.qlogv = qlog; p.ldql = LOv; p.klogv = klog; p.ldkl = LDv;
    p.M = LOv; p.N = LDv; p.K = Hv; p.qi = -1; p.kj = -1; p.epi = EP_LOGIT;
    mgemm<<<dim3(4, 2, NITEM), 256, 0, stream>>>(p);
  }
  row_softmax<<<dim3(LOv, NITEM), 256, 0, stream>>>(logitF, awbB, LDv, LDv, sLD);
  col_softmax<<<dim3(LDv, NITEM), 256, 0, stream>>>(logitF, kqB, LOv, LDv, sLD);
  { // attn = aw @ doc -> attnA block 1
    MG p = {};
    p.A = awbB; p.sA = sLD; p.lda = LDv; p.aidx = IX_INST;
    p.B = docTB; p.sB = (long long)Hv * LDv; p.ldb = LDv; p.bidx = IX_INST;
    p.Cb = attnA + Hv; p.sC = (long long)LOv * 3 * Hv; p.ldc = 3 * Hv; p.cidx = IX_INST;
    p.M = LOv; p.N = Hv; p.K = LDv; p.qi = -1; p.kj = -1; p.epi = EP_BF16;
    mgemm<<<dim3(8, 2, NITEM), 256, 0, stream>>>(p);
  }
  { // co_w = aw @ kq^T
    MG p = {};
    p.A = awbB; p.sA = sLD; p.lda = LDv; p.aidx = IX_INST;
    p.B = kqB; p.sB = sLD; p.ldb = LDv; p.bidx = IX_INST;
    p.Cb = cowB; p.sC = sLL; p.ldc = LOv; p.cidx = IX_INST;
    p.M = LOv; p.N = LOv; p.K = LDv; p.qi = -1; p.kj = -1; p.epi = EP_BF16;
    mgemm<<<dim3(2, 2, NITEM), 256, 0, stream>>>(p);
  }
  { // coattn = co_w @ option -> attnA block 2
    MG p = {};
    p.A = cowB; p.sA = sLL; p.lda = LOv; p.aidx = IX_INST;
    p.B = optTC; p.sB = (long long)Hv * LOv; p.ldb = LOv; p.bidx = IX_INST;
    p.Cb = attnA + 2 * Hv; p.sC = (long long)LOv * 3 * Hv; p.ldc = 3 * Hv; p.cidx = IX_INST;
    p.M = LOv; p.N = Hv; p.K = LOv; p.qi = -1; p.kj = -1; p.epi = EP_BF16;
    mgemm<<<dim3(8, 2, NITEM), 256, 0, stream>>>(p);
  }
  { // fusion = tanh(attnA @ attn_w^T + b)
    MF p = {};
    p.A = attnA; p.sA = (long long)LOv * 3 * Hv; p.B = wattn;
    p.C = fusionF; p.sC = sOH; p.bias = attn_fc_b;
    p.M = LOv; p.K = 3 * Hv; p.epi = FCE_TANH;
    mgemm_fc<<<1024, 256, 0, stream>>>(p);
  }

  // ========== Phase 4: self attention + self FC + masked max ==========
  conv_act<<<dim3(LOv, NITEM), 256, 0, stream>>>(fusionF, self_w3, selfA, 4 * Hv, fusw3);
  transpose_b<<<dim3(LOv / 32, Hv / 32, NITEM), 256, 0, stream>>>(fusionF, sOH, ll, fp, docm, 0, LOv, fusTB);
  dot_rows<<<dim3(LOv, NITEM), 256, 0, stream>>>(fusionF, sOH, ll, fp, docm, self_w1, qlog, LOv, 0);
  dot_rows<<<dim3(LOv, NITEM), 256, 0, stream>>>(fusionF, sOH, ll, fp, docm, self_w2, klog, LOv, 0);
  { // self logit (B = selfA block 0 = fusion bf16, ldb=4096)
    MG p = {};
    p.A = fusw3; p.sA = sOH; p.lda = Hv; p.aidx = IX_INST;
    p.B = selfA; p.sB = (long long)LOv * 4 * Hv; p.ldb = 4 * Hv; p.bidx = IX_INST;
    p.C = logitF; p.sC = sLL; p.ldc = LOv; p.cidx = IX_INST;
    p.qmask = optm; p.ldqm = LOv; p.kmask = optm; p.ldkm = LOv;
    p.qlogv = qlog; p.ldql = LOv; p.klogv = klog; p.ldkl = LOv;
    p.M = LOv; p.N = LOv; p.K = Hv; p.qi = -1; p.kj = -1; p.epi = EP_LOGIT;
    mgemm<<<dim3(2, 2, NITEM), 256, 0, stream>>>(p);
  }
  row_softmax<<<dim3(LOv, NITEM), 256, 0, stream>>>(logitF, awbB, LOv, LOv, sLL);
  { // attn2 = aw @ fusion -> selfA block 1
    MG p = {};
    p.A = awbB; p.sA = sLL; p.lda = LOv; p.aidx = IX_INST;
    p.B = fusTB; p.sB = (long long)Hv * LOv; p.ldb = LOv; p.bidx = IX_INST;
    p.Cb = selfA + Hv; p.sC = (long long)LOv * 4 * Hv; p.ldc = 4 * Hv; p.cidx = IX_INST;
    p.M = LOv; p.N = Hv; p.K = LOv; p.qi = -1; p.kj = -1; p.epi = EP_BF16;
    mgemm<<<dim3(8, 2, NITEM), 256, 0, stream>>>(p);
  }
  build_selfA23<<<dim3(LOv, NITEM), 256, 0, stream>>>(selfA);
  { // out[item,h] = max over valid t of relu(selfA @ self_w^T + b)
    MF p = {};
    p.A = selfA; p.sA = (long long)LOv * 4 * Hv; p.B = wself;
    p.bias = self_fc_b; p.optm = optm; p.outmax = out;
    p.M = LOv; p.K = 4 * Hv; p.epi = FCE_SELFMAX;
    mgemm_fc<<<1024, 256, 0, stream>>>(p);
  }
}